// Round 6
// baseline (429.022 us; speedup 1.0000x reference)
//
#include <hip/hip_runtime.h>
#include <hip/hip_fp16.h>

// MRI adjoint: masked centered 2D IFFT per (coil,frame) -> conj(smaps) combine
// -> bilinear warp-adjoint scatter -> sum over frames. Nx=Ny=320, Nc=16, Nt=25.
//
// FFT: 320 = 5*64; one wave per transform (6-stage radix-2 across lanes via
// shfl_xor + per-lane twiddled radix-5). Centered: out[n]=(-1)^n IFFT[(-1)^k x].
// Complex values carried as ext_vector float2 -> v_pk_{add,mul,fma}_f32.
// tmp (x-IFFT result) fp16 half2, natural x order.
// pass2: 16-wide nx tiles (64B global fragments, matches HBM burst; round-5's
// 8-wide tiles caused 2x over-fetch).
// Scatter: LDS-privatized row bands via unsafeAtomicAdd (native ds_add_f32;
// plain f32 atomicAdd is a CAS loop on AMD -- the round-2..4 bottleneck).

#define NX 320
#define NT 25
#define NC 16
#define BR 32
#define WH 16
static const float INV320 = 1.0f / 320.0f;

typedef float v2f __attribute__((ext_vector_type(2)));

__device__ __forceinline__ int rev6(int l) {
  return ((l & 1) << 5) | ((l & 2) << 3) | ((l & 4) << 1) |
         ((l & 8) >> 1) | ((l & 16) >> 3) | ((l & 32) >> 5);
}

struct Tw {
  float c[6], s[6];
  float c1, s1, c2, s2, c3, s3, c4, s4;
};

__device__ __forceinline__ void make_tw(int lane, Tw& tw) {
#pragma unroll
  for (int st = 0; st < 6; ++st) {
    int m = 32 >> st;
    int j = lane & (m - 1);
    float ang = 3.14159265358979323846f * (float)j / (float)m;
    __sincosf(ang, &tw.s[st], &tw.c[st]);
  }
  int k1 = rev6(lane);
  float b = (6.283185307179586f / 320.0f) * (float)k1;
  __sincosf(b, &tw.s1, &tw.c1);
  tw.c2 = tw.c1 * tw.c1 - tw.s1 * tw.s1;
  tw.s2 = 2.f * tw.c1 * tw.s1;
  tw.c3 = tw.c2 * tw.c1 - tw.s2 * tw.s1;
  tw.s3 = tw.c2 * tw.s1 + tw.s2 * tw.c1;
  tw.c4 = tw.c2 * tw.c2 - tw.s2 * tw.s2;
  tw.s4 = 2.f * tw.c2 * tw.s2;
}

__device__ __forceinline__ v2f shfl_xor_v2(v2f z, int m) {
  v2f r;
  r.x = __shfl_xor(z.x, m);
  r.y = __shfl_xor(z.y, m);
  return r;
}

// (z.x + i z.y) * (c + i s)
__device__ __forceinline__ v2f cmul(v2f z, float c, float s) {
  v2f sw = {-z.y, z.x};
  return c * z + s * sw;
}

// Unnormalized inverse 320-pt DFT: lane l enters with x[5l+q] in z[q];
// exits with X[rev6(l) + 64*q].
__device__ __forceinline__ void fft320p(v2f z[5], int lane, const Tw& tw) {
#pragma unroll
  for (int st = 0; st < 6; ++st) {
    int m = 32 >> st;
    float c = tw.c[st], s = tw.s[st];
    bool bot = (lane & m) != 0;
#pragma unroll
    for (int q = 0; q < 5; ++q) {
      v2f o = shfl_xor_v2(z[q], m);
      v2f sum = z[q] + o;
      v2f dif = o - z[q];
      v2f tv = cmul(dif, c, s);
      z[q] = bot ? tv : sum;
    }
  }
  v2f t0 = z[0];
  v2f t1 = cmul(z[1], tw.c1, tw.s1);
  v2f t2 = cmul(z[2], tw.c2, tw.s2);
  v2f t3 = cmul(z[3], tw.c3, tw.s3);
  v2f t4 = cmul(z[4], tw.c4, tw.s4);
  const float C1 = 0.30901699437494742f, S1 = 0.95105651629515357f;
  const float C2 = -0.80901699437494742f, S2 = 0.58778525229247312f;
  v2f a1 = t1 + t4, b1 = t1 - t4;
  v2f a2 = t2 + t3, b2 = t2 - t3;
  z[0] = t0 + a1 + a2;
  v2f p = t0 + C1 * a1 + C2 * a2;
  v2f q_ = S1 * b1 + S2 * b2;
  v2f r = t0 + C2 * a1 + C1 * a2;
  v2f u = S2 * b1 - S1 * b2;
  v2f qi = {-q_.y, q_.x};
  v2f ui = {-u.y, u.x};
  z[1] = p + qi;
  z[4] = p - qi;
  z[2] = r + ui;
  z[3] = r - ui;
}

// mask [x][y][c][t] f32 -> bit-packed mp[c][y][x]
__global__ __launch_bounds__(256) void pack_mask_k(
    const float* __restrict__ mask, unsigned int* __restrict__ mp) {
  int xt = blockIdx.x, y = blockIdx.y, tid = threadIdx.x;
  int xx = tid >> 4, c = tid & 15;
  int x = xt * 16 + xx;
  const float* src = mask + (size_t)(x * NX + y) * (NC * NT) + c * NT;
  unsigned int bits = 0;
#pragma unroll
  for (int t = 0; t < NT; ++t) bits |= (src[t] != 0.f) ? (1u << t) : 0u;
  __shared__ unsigned int tile[16][17];
  tile[xx][c] = bits;
  __syncthreads();
  int c2 = tid >> 4, xx2 = tid & 15;
  mp[((size_t)(c2 * NX + y)) * NX + xt * 16 + xx2] = tile[xx2][c2];
}

// (ar,ai) [x][y][c] -> dst[c][y][x] float2   (kspace)
__global__ __launch_bounds__(256) void tr_cplx_k(
    const float* __restrict__ ar, const float* __restrict__ ai,
    float2* __restrict__ dst) {
  int xt = blockIdx.x, y = blockIdx.y, tid = threadIdx.x;
  int xx = tid >> 4, c = tid & 15;
  size_t si = (size_t)((xt * 16 + xx) * NX + y) * NC + c;
  __shared__ float2 tile[16][17];
  tile[xx][c] = make_float2(ar[si], ai[si]);
  __syncthreads();
  int c2 = tid >> 4, xx2 = tid & 15;
  dst[((size_t)(c2 * NX + y)) * NX + xt * 16 + xx2] = tile[xx2][c2];
}

// (ar,ai) [x][y][c] -> dst[c][x][y] float2   (smaps)
__global__ __launch_bounds__(256) void tr_cplx_cxy_k(
    const float* __restrict__ ar, const float* __restrict__ ai,
    float2* __restrict__ dst) {
  int yt = blockIdx.x, x = blockIdx.y, tid = threadIdx.x;
  int yy = tid >> 4, c = tid & 15;
  size_t si = (size_t)(x * NX + yt * 16 + yy) * NC + c;
  __shared__ float2 tile[16][17];
  tile[yy][c] = make_float2(ar[si], ai[si]);
  __syncthreads();
  int c2 = tid >> 4, yy2 = tid & 15;
  dst[((size_t)(c2 * NX + x)) * NX + yt * 16 + yy2] = tile[yy2][c2];
}

// flow [nx][ny][2][t] -> fs[t][nx][ny] float2 (natural order)
__global__ __launch_bounds__(256) void tr_flow_k(
    const float* __restrict__ fl, float2* __restrict__ dst) {
  int nyt = blockIdx.x, nx = blockIdx.y, tid = threadIdx.x;
  __shared__ float buf[1600];
  size_t base = (size_t)(nx * NX + nyt * 32) * (2 * NT);
  for (int f = tid; f < 1600; f += 256) buf[f] = fl[base + f];
  __syncthreads();
  for (int f = tid; f < 1600; f += 256) {
    int t = f / 64;
    int k = f % 64;
    int nyl = k >> 1, d = k & 1;
    size_t di = ((size_t)(t * NX + nx) * NX + nyt * 32 + nyl) * 2 + d;
    ((float*)dst)[di] = buf[(nyl * 2 + d) * NT + t];
  }
}

// Pass 1: x-axis IFFT for coil chunk [c0, c0+G). Writes tmp[cg][t][y][nx] fp16.
__global__ __launch_bounds__(256) void pass1_k(
    const float2* __restrict__ kT, const unsigned int* __restrict__ mp,
    __half2* __restrict__ tmp, int c0) {
  int y = blockIdx.x, cg = blockIdx.y, c = c0 + cg;
  int tid = threadIdx.x, lane = tid & 63, w = tid >> 6;
  v2f v[5];
  unsigned int mb[5];
  size_t rowbase = ((size_t)c * NX + y) * NX;
#pragma unroll
  for (int q = 0; q < 5; ++q) {
    int x = 5 * lane + q;
    float2 kv = kT[rowbase + x];
    float sg = ((lane + q) & 1) ? -INV320 : INV320;  // (-1)^x / 320
    v[q].x = kv.x * sg;
    v[q].y = kv.y * sg;
    mb[q] = mp[rowbase + x];
  }
  Tw tw;
  make_tw(lane, tw);
  int r6 = rev6(lane);
  float osg = (lane & 32) ? -1.f : 1.f;  // (-1)^nx
  for (int t = w; t < NT; t += 4) {
    v2f z[5];
#pragma unroll
    for (int q = 0; q < 5; ++q) {
      float m = ((mb[q] >> t) & 1u) ? 1.f : 0.f;
      z[q] = v[q] * m;
    }
    fft320p(z, lane, tw);
    __half2* dst = tmp + ((size_t)(cg * NT + t) * NX + y) * NX;
#pragma unroll
    for (int k2 = 0; k2 < 5; ++k2)
      dst[r6 + 64 * k2] = __floats2half2_rn(z[k2].x * osg, z[k2].y * osg);
  }
}

// Pass 2: y-axis IFFT + conj(smaps) combine -> im_aux[t][nx][ny] (natural).
// 1024 threads; block = (nx-tile of 16, t); wave j owns nx = nxt*16+j.
__global__ __launch_bounds__(1024) void pass2_k(
    const __half2* __restrict__ tmp, const float2* __restrict__ sT,
    float2* __restrict__ im_aux, int c0, int G, int first) {
  int nxt = blockIdx.x, t = blockIdx.y;
  int tid = threadIdx.x, lane = tid & 63, j = tid >> 6;
  int nx = nxt * 16 + j;
  int k1 = rev6(lane);
  Tw tw;
  make_tw(lane, tw);
  __shared__ __half2 tile[NX][17];  // 21.76 KB
  v2f acc[5] = {{0, 0}, {0, 0}, {0, 0}, {0, 0}, {0, 0}};
  for (int cg = 0; cg < G; ++cg) {
    __syncthreads();
    const __half2* src = tmp + ((size_t)(cg * NT + t) * NX) * NX + nxt * 16;
#pragma unroll
    for (int q = 0; q < 5; ++q) {
      int f = tid + q * 1024;
      int y = f >> 4, jj = f & 15;
      tile[y][jj] = src[(size_t)y * NX + jj];
    }
    __syncthreads();
    v2f z[5];
#pragma unroll
    for (int q = 0; q < 5; ++q) {
      float2 v = __half22float2(tile[5 * lane + q][j]);
      float sg = ((lane + q) & 1) ? -1.f : 1.f;  // (-1)^y
      z[q].x = v.x * sg;
      z[q].y = v.y * sg;
    }
    fft320p(z, lane, tw);
    const float2* srow = sT + ((size_t)(c0 + cg) * NX + nx) * NX;
#pragma unroll
    for (int k2 = 0; k2 < 5; ++k2) {
      int ny = k1 + 64 * k2;
      float2 sm = srow[ny];
      v2f zc = {z[k2].y, -z[k2].x};  // conj-MAC helper
      acc[k2] += sm.x * z[k2] + sm.y * zc;
    }
  }
  float osg = (lane & 32) ? -1.f : 1.f;  // (-1)^ny
  float2* dst = im_aux + ((size_t)t * NX + nx) * NX;
#pragma unroll
  for (int k2 = 0; k2 < 5; ++k2) {
    int ny = k1 + 64 * k2;
    float2 nv = make_float2(acc[k2].x * osg, acc[k2].y * osg);
    if (!first) {
      float2 old = dst[ny];
      nv.x += old.x;
      nv.y += old.y;
    }
    dst[ny] = nv;
  }
}

// Scatter: block (band b, seg, frame t). LDS-privatized 32-row band.
__global__ __launch_bounds__(1024) void scatter_k(
    const float2* __restrict__ im, const float2* __restrict__ fs,
    float* __restrict__ out_p, float* __restrict__ out_f, int nseg) {
  int b = blockIdx.x, seg = blockIdx.y, t = blockIdx.z;
  int r0 = b * BR;
  int tid = threadIdx.x, lane = tid & 63, w = tid >> 6;
  __shared__ float acc[BR * NX * 2];  // 80 KB
  for (int i = tid; i < BR * NX * 2; i += 1024) acc[i] = 0.f;
  __syncthreads();
  int lo = max(r0 - WH, 0), hi = min(r0 + BR + WH, NX);
  int stride = 16 * nseg;
  for (int nx = lo + seg * 16 + w; nx < hi; nx += stride) {
    bool own = (nx >= r0) && (nx < r0 + BR);
    const float2* imrow = im + ((size_t)t * NX + nx) * NX;
    const float2* frow = fs + ((size_t)t * NX + nx) * NX;
#pragma unroll
    for (int q = 0; q < 5; ++q) {
      int ny = lane + 64 * q;
      float2 v = imrow[ny];
      float2 fl = frow[ny];
      float px = fminf(fmaxf((float)nx + fl.x, 0.f), 319.f);
      float py = fminf(fmaxf((float)ny + fl.y, 0.f), 319.f);
      int x0 = (int)floorf(px), y0 = (int)floorf(py);
      int x1 = min(x0 + 1, NX - 1), y1 = min(y0 + 1, NX - 1);
      float wx = px - (float)x0, wy = py - (float)y0;
      float w00 = (1.f - wx) * (1.f - wy), w01 = (1.f - wx) * wy;
      float w10 = wx * (1.f - wy), w11 = wx * wy;
#pragma unroll
      for (int half = 0; half < 2; ++half) {
        int r = half ? x1 : x0;
        float wa = half ? w10 : w00;
        float wb = half ? w11 : w01;
        if (r >= r0 && r < r0 + BR) {
          float* p0 = &acc[((r - r0) * NX + y0) * 2];
          float* p1 = &acc[((r - r0) * NX + y1) * 2];
          unsafeAtomicAdd(p0, wa * v.x);
          unsafeAtomicAdd(p0 + 1, wa * v.y);
          unsafeAtomicAdd(p1, wb * v.x);
          unsafeAtomicAdd(p1 + 1, wb * v.y);
        } else if (own) {
          int rb = (r / BR) * BR;
          if (nx < rb - WH || nx >= rb + BR + WH) {  // no band reads nx
            unsafeAtomicAdd(&out_f[((size_t)r * NX + y0) * 2], wa * v.x);
            unsafeAtomicAdd(&out_f[((size_t)r * NX + y0) * 2 + 1], wa * v.y);
            unsafeAtomicAdd(&out_f[((size_t)r * NX + y1) * 2], wb * v.x);
            unsafeAtomicAdd(&out_f[((size_t)r * NX + y1) * 2 + 1], wb * v.y);
          }
        }
      }
    }
  }
  __syncthreads();
  float* dst = out_p + ((size_t)(seg * NT + t) * NX + r0) * NX * 2;
  for (int i = tid; i < BR * NX * 2; i += 1024) dst[i] = acc[i];
}

// out = out_f + sum_{seg,t} out_p
__global__ __launch_bounds__(256) void reduce_k(
    const float* __restrict__ out_p, const float* __restrict__ out_f,
    float* __restrict__ out, int nslice) {
  const int n4 = NX * NX * 2 / 4;
  int i = blockIdx.x * 256 + threadIdx.x;
  if (i >= n4) return;
  float4 s = ((const float4*)out_f)[i];
  for (int k = 0; k < nslice; ++k) {
    float4 v = ((const float4*)out_p)[(size_t)k * n4 + i];
    s.x += v.x; s.y += v.y; s.z += v.z; s.w += v.w;
  }
  ((float4*)out)[i] = s;
}

extern "C" void kernel_launch(void* const* d_in, const int* in_sizes, int n_in,
                              void* d_out, int out_size, void* d_ws,
                              size_t ws_size, hipStream_t stream) {
  const float* kr = (const float*)d_in[0];
  const float* ki = (const float*)d_in[1];
  const float* mask = (const float*)d_in[2];
  const float* sr = (const float*)d_in[3];
  const float* si = (const float*)d_in[4];
  const float* fl = (const float*)d_in[5];
  float* out = (float*)d_out;

  const size_t tmp1 = (size_t)NT * NX * NX * 4;      // fp16 complex, per coil
  const size_t kT_b = (size_t)NC * NX * NX * 8;
  const size_t sT_b = kT_b;
  const size_t fs_b = (size_t)NT * NX * NX * 8;
  const size_t mp_b = (size_t)NC * NX * NX * 4;
  const size_t ia_b = (size_t)NT * NX * NX * 8;
  const size_t of_b = (size_t)NX * NX * 8;
  const size_t op1 = (size_t)NT * NX * NX * 8;       // per scatter segment

  int NSEG = 2, G = 16;
  for (;;) {
    size_t fixed = kT_b + sT_b + fs_b + mp_b + ia_b + of_b + NSEG * op1;
    if (ws_size >= fixed + (size_t)G * tmp1) break;
    if (G > 1) { G >>= 1; continue; }
    if (NSEG > 1) { NSEG >>= 1; G = 16; continue; }
    break;  // minimal config; assume it fits
  }

  char* w = (char*)d_ws;
  __half2* tmp = (__half2*)w;   w += (size_t)G * tmp1;
  float2* kT = (float2*)w;      w += kT_b;
  float2* sT = (float2*)w;      w += sT_b;
  float2* fs = (float2*)w;      w += fs_b;
  float2* im_aux = (float2*)w;  w += ia_b;
  float* out_p = (float*)w;     w += (size_t)NSEG * op1;
  float* out_f = (float*)w;     w += of_b;
  unsigned int* mp = (unsigned int*)w;

  pack_mask_k<<<dim3(NX / 16, NX), 256, 0, stream>>>(mask, mp);
  tr_cplx_k<<<dim3(NX / 16, NX), 256, 0, stream>>>(kr, ki, kT);
  tr_cplx_cxy_k<<<dim3(NX / 16, NX), 256, 0, stream>>>(sr, si, sT);
  tr_flow_k<<<dim3(NX / 32, NX), 256, 0, stream>>>(fl, fs);
  hipMemsetAsync(out_f, 0, of_b, stream);

  for (int c0 = 0; c0 < NC; c0 += G) {
    pass1_k<<<dim3(NX, G), 256, 0, stream>>>(kT, mp, tmp, c0);
    pass2_k<<<dim3(NX / 16, NT), 1024, 0, stream>>>(tmp, sT, im_aux, c0, G,
                                                    c0 == 0 ? 1 : 0);
  }
  scatter_k<<<dim3(NX / BR, NSEG, NT), 1024, 0, stream>>>(im_aux, fs, out_p,
                                                          out_f, NSEG);
  reduce_k<<<200, 256, 0, stream>>>(out_p, out_f, out, NSEG * NT);
}

// Round 7
// 415.501 us; speedup vs baseline: 1.0325x; 1.0325x over previous
//
#include <hip/hip_runtime.h>
#include <hip/hip_fp16.h>

// MRI adjoint: masked centered 2D IFFT per (coil,frame) -> conj(smaps) combine
// -> bilinear warp-adjoint scatter -> sum over frames. Nx=Ny=320, Nc=16, Nt=25.
//
// FFT: 320 = 5*64; one wave per transform (6-stage radix-2 across lanes via
// shfl_xor + per-lane twiddled radix-5). Centered: out[n]=(-1)^n IFFT[(-1)^k x].
// Complex values carried as ext_vector float2 -> v_pk_{add,mul,fma}_f32.
// tmp (x-IFFT result) fp16 half2, natural x order.
// pass2 (round-7): coil loop software-pipelined -- double-buffered LDS tile
// (one barrier/iter) + 1-deep register prefetch of the next coil's tile +
// early smaps loads. Round 6 showed it latency-bound (VALU+DS work sums to
// ~half the measured time; the rest was barrier-serialized staging latency).
// Scatter: LDS-privatized row bands via unsafeAtomicAdd (native ds_add_f32;
// plain f32 atomicAdd is a CAS loop on AMD -- the round-2..4 bottleneck).

#define NX 320
#define NT 25
#define NC 16
#define BR 32
#define WH 16
static const float INV320 = 1.0f / 320.0f;

typedef float v2f __attribute__((ext_vector_type(2)));

__device__ __forceinline__ int rev6(int l) {
  return ((l & 1) << 5) | ((l & 2) << 3) | ((l & 4) << 1) |
         ((l & 8) >> 1) | ((l & 16) >> 3) | ((l & 32) >> 5);
}

struct Tw {
  float c[6], s[6];
  float c1, s1, c2, s2, c3, s3, c4, s4;
};

__device__ __forceinline__ void make_tw(int lane, Tw& tw) {
#pragma unroll
  for (int st = 0; st < 6; ++st) {
    int m = 32 >> st;
    int j = lane & (m - 1);
    float ang = 3.14159265358979323846f * (float)j / (float)m;
    __sincosf(ang, &tw.s[st], &tw.c[st]);
  }
  int k1 = rev6(lane);
  float b = (6.283185307179586f / 320.0f) * (float)k1;
  __sincosf(b, &tw.s1, &tw.c1);
  tw.c2 = tw.c1 * tw.c1 - tw.s1 * tw.s1;
  tw.s2 = 2.f * tw.c1 * tw.s1;
  tw.c3 = tw.c2 * tw.c1 - tw.s2 * tw.s1;
  tw.s3 = tw.c2 * tw.s1 + tw.s2 * tw.c1;
  tw.c4 = tw.c2 * tw.c2 - tw.s2 * tw.s2;
  tw.s4 = 2.f * tw.c2 * tw.s2;
}

__device__ __forceinline__ v2f shfl_xor_v2(v2f z, int m) {
  v2f r;
  r.x = __shfl_xor(z.x, m);
  r.y = __shfl_xor(z.y, m);
  return r;
}

// (z.x + i z.y) * (c + i s)
__device__ __forceinline__ v2f cmul(v2f z, float c, float s) {
  v2f sw = {-z.y, z.x};
  return c * z + s * sw;
}

// Unnormalized inverse 320-pt DFT: lane l enters with x[5l+q] in z[q];
// exits with X[rev6(l) + 64*q].
__device__ __forceinline__ void fft320p(v2f z[5], int lane, const Tw& tw) {
#pragma unroll
  for (int st = 0; st < 6; ++st) {
    int m = 32 >> st;
    float c = tw.c[st], s = tw.s[st];
    bool bot = (lane & m) != 0;
#pragma unroll
    for (int q = 0; q < 5; ++q) {
      v2f o = shfl_xor_v2(z[q], m);
      v2f sum = z[q] + o;
      v2f dif = o - z[q];
      v2f tv = cmul(dif, c, s);
      z[q] = bot ? tv : sum;
    }
  }
  v2f t0 = z[0];
  v2f t1 = cmul(z[1], tw.c1, tw.s1);
  v2f t2 = cmul(z[2], tw.c2, tw.s2);
  v2f t3 = cmul(z[3], tw.c3, tw.s3);
  v2f t4 = cmul(z[4], tw.c4, tw.s4);
  const float C1 = 0.30901699437494742f, S1 = 0.95105651629515357f;
  const float C2 = -0.80901699437494742f, S2 = 0.58778525229247312f;
  v2f a1 = t1 + t4, b1 = t1 - t4;
  v2f a2 = t2 + t3, b2 = t2 - t3;
  z[0] = t0 + a1 + a2;
  v2f p = t0 + C1 * a1 + C2 * a2;
  v2f q_ = S1 * b1 + S2 * b2;
  v2f r = t0 + C2 * a1 + C1 * a2;
  v2f u = S2 * b1 - S1 * b2;
  v2f qi = {-q_.y, q_.x};
  v2f ui = {-u.y, u.x};
  z[1] = p + qi;
  z[4] = p - qi;
  z[2] = r + ui;
  z[3] = r - ui;
}

// mask [x][y][c][t] f32 -> bit-packed mp[c][y][x]
__global__ __launch_bounds__(256) void pack_mask_k(
    const float* __restrict__ mask, unsigned int* __restrict__ mp) {
  int xt = blockIdx.x, y = blockIdx.y, tid = threadIdx.x;
  int xx = tid >> 4, c = tid & 15;
  int x = xt * 16 + xx;
  const float* src = mask + (size_t)(x * NX + y) * (NC * NT) + c * NT;
  unsigned int bits = 0;
#pragma unroll
  for (int t = 0; t < NT; ++t) bits |= (src[t] != 0.f) ? (1u << t) : 0u;
  __shared__ unsigned int tile[16][17];
  tile[xx][c] = bits;
  __syncthreads();
  int c2 = tid >> 4, xx2 = tid & 15;
  mp[((size_t)(c2 * NX + y)) * NX + xt * 16 + xx2] = tile[xx2][c2];
}

// (ar,ai) [x][y][c] -> dst[c][y][x] float2   (kspace)
__global__ __launch_bounds__(256) void tr_cplx_k(
    const float* __restrict__ ar, const float* __restrict__ ai,
    float2* __restrict__ dst) {
  int xt = blockIdx.x, y = blockIdx.y, tid = threadIdx.x;
  int xx = tid >> 4, c = tid & 15;
  size_t si = (size_t)((xt * 16 + xx) * NX + y) * NC + c;
  __shared__ float2 tile[16][17];
  tile[xx][c] = make_float2(ar[si], ai[si]);
  __syncthreads();
  int c2 = tid >> 4, xx2 = tid & 15;
  dst[((size_t)(c2 * NX + y)) * NX + xt * 16 + xx2] = tile[xx2][c2];
}

// (ar,ai) [x][y][c] -> dst[c][x][y] float2   (smaps)
__global__ __launch_bounds__(256) void tr_cplx_cxy_k(
    const float* __restrict__ ar, const float* __restrict__ ai,
    float2* __restrict__ dst) {
  int yt = blockIdx.x, x = blockIdx.y, tid = threadIdx.x;
  int yy = tid >> 4, c = tid & 15;
  size_t si = (size_t)(x * NX + yt * 16 + yy) * NC + c;
  __shared__ float2 tile[16][17];
  tile[yy][c] = make_float2(ar[si], ai[si]);
  __syncthreads();
  int c2 = tid >> 4, yy2 = tid & 15;
  dst[((size_t)(c2 * NX + x)) * NX + yt * 16 + yy2] = tile[yy2][c2];
}

// flow [nx][ny][2][t] -> fs[t][nx][ny] float2 (natural order)
__global__ __launch_bounds__(256) void tr_flow_k(
    const float* __restrict__ fl, float2* __restrict__ dst) {
  int nyt = blockIdx.x, nx = blockIdx.y, tid = threadIdx.x;
  __shared__ float buf[1600];
  size_t base = (size_t)(nx * NX + nyt * 32) * (2 * NT);
  for (int f = tid; f < 1600; f += 256) buf[f] = fl[base + f];
  __syncthreads();
  for (int f = tid; f < 1600; f += 256) {
    int t = f / 64;
    int k = f % 64;
    int nyl = k >> 1, d = k & 1;
    size_t di = ((size_t)(t * NX + nx) * NX + nyt * 32 + nyl) * 2 + d;
    ((float*)dst)[di] = buf[(nyl * 2 + d) * NT + t];
  }
}

// Pass 1: x-axis IFFT for coil chunk [c0, c0+G). Writes tmp[cg][t][y][nx] fp16.
__global__ __launch_bounds__(256) void pass1_k(
    const float2* __restrict__ kT, const unsigned int* __restrict__ mp,
    __half2* __restrict__ tmp, int c0) {
  int y = blockIdx.x, cg = blockIdx.y, c = c0 + cg;
  int tid = threadIdx.x, lane = tid & 63, w = tid >> 6;
  v2f v[5];
  unsigned int mb[5];
  size_t rowbase = ((size_t)c * NX + y) * NX;
#pragma unroll
  for (int q = 0; q < 5; ++q) {
    int x = 5 * lane + q;
    float2 kv = kT[rowbase + x];
    float sg = ((lane + q) & 1) ? -INV320 : INV320;  // (-1)^x / 320
    v[q].x = kv.x * sg;
    v[q].y = kv.y * sg;
    mb[q] = mp[rowbase + x];
  }
  Tw tw;
  make_tw(lane, tw);
  int r6 = rev6(lane);
  float osg = (lane & 32) ? -1.f : 1.f;  // (-1)^nx
  for (int t = w; t < NT; t += 4) {
    v2f z[5];
#pragma unroll
    for (int q = 0; q < 5; ++q) {
      float m = ((mb[q] >> t) & 1u) ? 1.f : 0.f;
      z[q] = v[q] * m;
    }
    fft320p(z, lane, tw);
    __half2* dst = tmp + ((size_t)(cg * NT + t) * NX + y) * NX;
#pragma unroll
    for (int k2 = 0; k2 < 5; ++k2)
      dst[r6 + 64 * k2] = __floats2half2_rn(z[k2].x * osg, z[k2].y * osg);
  }
}

// Pass 2: y-axis IFFT + conj(smaps) combine -> im_aux[t][nx][ny] (natural).
// 1024 threads; block = (nx-tile of 16, t); wave j owns nx = nxt*16+j.
// Software-pipelined coil loop: double-buffered LDS tile (1 barrier/iter),
// 1-deep register prefetch of coil cg+1 while computing cg.
__global__ __launch_bounds__(1024) void pass2_k(
    const __half2* __restrict__ tmp, const float2* __restrict__ sT,
    float2* __restrict__ im_aux, int c0, int G, int first) {
  int nxt_ = blockIdx.x, t = blockIdx.y;
  int tid = threadIdx.x, lane = tid & 63, j = tid >> 6;
  int nx = nxt_ * 16 + j;
  int k1 = rev6(lane);
  Tw tw;
  make_tw(lane, tw);
  __shared__ __half2 tile[2][NX][17];  // 43.5 KB
  v2f acc[5] = {{0, 0}, {0, 0}, {0, 0}, {0, 0}, {0, 0}};

  // loop-invariant per-thread offsets
  int off[5], lw[5];
#pragma unroll
  for (int q = 0; q < 5; ++q) {
    int f = tid + q * 1024;
    off[q] = (f >> 4) * NX + (f & 15);     // global element offset in plane
    lw[q] = (f >> 4) * 17 + (f & 15);      // LDS word offset
  }
  const size_t pstride = (size_t)NT * NX * NX;  // per-coil plane stride
  const __half2* sbase = tmp + (size_t)t * NX * NX + nxt_ * 16;
  __half2* lds = &tile[0][0][0];

  __half2 nb[5];
#pragma unroll
  for (int q = 0; q < 5; ++q) nb[q] = sbase[off[q]];

  for (int cg = 0; cg < G; ++cg) {
    __half2 cb[5];
#pragma unroll
    for (int q = 0; q < 5; ++q) cb[q] = nb[q];  // waits on cg's loads
    if (cg + 1 < G) {
      const __half2* s = sbase + (size_t)(cg + 1) * pstride;
#pragma unroll
      for (int q = 0; q < 5; ++q) nb[q] = s[off[q]];  // in flight across iter
    }
    __half2* buf = lds + (cg & 1) * (NX * 17);
#pragma unroll
    for (int q = 0; q < 5; ++q) buf[lw[q]] = cb[q];
    __syncthreads();
    const float2* srow = sT + ((size_t)(c0 + cg) * NX + nx) * NX;
    float2 sm[5];
#pragma unroll
    for (int k2 = 0; k2 < 5; ++k2) sm[k2] = srow[k1 + 64 * k2];
    v2f z[5];
#pragma unroll
    for (int q = 0; q < 5; ++q) {
      float2 v = __half22float2(buf[(5 * lane + q) * 17 + j]);
      float sg = ((lane + q) & 1) ? -1.f : 1.f;  // (-1)^y
      z[q].x = v.x * sg;
      z[q].y = v.y * sg;
    }
    fft320p(z, lane, tw);
#pragma unroll
    for (int k2 = 0; k2 < 5; ++k2) {
      v2f zc = {z[k2].y, -z[k2].x};  // conj-MAC helper
      acc[k2] += sm[k2].x * z[k2] + sm[k2].y * zc;
    }
  }
  float osg = (lane & 32) ? -1.f : 1.f;  // (-1)^ny
  float2* dst = im_aux + ((size_t)t * NX + nx) * NX;
#pragma unroll
  for (int k2 = 0; k2 < 5; ++k2) {
    int ny = k1 + 64 * k2;
    float2 nv = make_float2(acc[k2].x * osg, acc[k2].y * osg);
    if (!first) {
      float2 old = dst[ny];
      nv.x += old.x;
      nv.y += old.y;
    }
    dst[ny] = nv;
  }
}

// Scatter: block (band b, seg, frame t). LDS-privatized 32-row band.
__global__ __launch_bounds__(1024) void scatter_k(
    const float2* __restrict__ im, const float2* __restrict__ fs,
    float* __restrict__ out_p, float* __restrict__ out_f, int nseg) {
  int b = blockIdx.x, seg = blockIdx.y, t = blockIdx.z;
  int r0 = b * BR;
  int tid = threadIdx.x, lane = tid & 63, w = tid >> 6;
  __shared__ float acc[BR * NX * 2];  // 80 KB
  for (int i = tid; i < BR * NX * 2; i += 1024) acc[i] = 0.f;
  __syncthreads();
  int lo = max(r0 - WH, 0), hi = min(r0 + BR + WH, NX);
  int stride = 16 * nseg;
  for (int nx = lo + seg * 16 + w; nx < hi; nx += stride) {
    bool own = (nx >= r0) && (nx < r0 + BR);
    const float2* imrow = im + ((size_t)t * NX + nx) * NX;
    const float2* frow = fs + ((size_t)t * NX + nx) * NX;
#pragma unroll
    for (int q = 0; q < 5; ++q) {
      int ny = lane + 64 * q;
      float2 v = imrow[ny];
      float2 fl = frow[ny];
      float px = fminf(fmaxf((float)nx + fl.x, 0.f), 319.f);
      float py = fminf(fmaxf((float)ny + fl.y, 0.f), 319.f);
      int x0 = (int)floorf(px), y0 = (int)floorf(py);
      int x1 = min(x0 + 1, NX - 1), y1 = min(y0 + 1, NX - 1);
      float wx = px - (float)x0, wy = py - (float)y0;
      float w00 = (1.f - wx) * (1.f - wy), w01 = (1.f - wx) * wy;
      float w10 = wx * (1.f - wy), w11 = wx * wy;
#pragma unroll
      for (int half = 0; half < 2; ++half) {
        int r = half ? x1 : x0;
        float wa = half ? w10 : w00;
        float wb = half ? w11 : w01;
        if (r >= r0 && r < r0 + BR) {
          float* p0 = &acc[((r - r0) * NX + y0) * 2];
          float* p1 = &acc[((r - r0) * NX + y1) * 2];
          unsafeAtomicAdd(p0, wa * v.x);
          unsafeAtomicAdd(p0 + 1, wa * v.y);
          unsafeAtomicAdd(p1, wb * v.x);
          unsafeAtomicAdd(p1 + 1, wb * v.y);
        } else if (own) {
          int rb = (r / BR) * BR;
          if (nx < rb - WH || nx >= rb + BR + WH) {  // no band reads nx
            unsafeAtomicAdd(&out_f[((size_t)r * NX + y0) * 2], wa * v.x);
            unsafeAtomicAdd(&out_f[((size_t)r * NX + y0) * 2 + 1], wa * v.y);
            unsafeAtomicAdd(&out_f[((size_t)r * NX + y1) * 2], wb * v.x);
            unsafeAtomicAdd(&out_f[((size_t)r * NX + y1) * 2 + 1], wb * v.y);
          }
        }
      }
    }
  }
  __syncthreads();
  float* dst = out_p + ((size_t)(seg * NT + t) * NX + r0) * NX * 2;
  for (int i = tid; i < BR * NX * 2; i += 1024) dst[i] = acc[i];
}

// out = out_f + sum_{seg,t} out_p
__global__ __launch_bounds__(256) void reduce_k(
    const float* __restrict__ out_p, const float* __restrict__ out_f,
    float* __restrict__ out, int nslice) {
  const int n4 = NX * NX * 2 / 4;
  int i = blockIdx.x * 256 + threadIdx.x;
  if (i >= n4) return;
  float4 s = ((const float4*)out_f)[i];
  for (int k = 0; k < nslice; ++k) {
    float4 v = ((const float4*)out_p)[(size_t)k * n4 + i];
    s.x += v.x; s.y += v.y; s.z += v.z; s.w += v.w;
  }
  ((float4*)out)[i] = s;
}

extern "C" void kernel_launch(void* const* d_in, const int* in_sizes, int n_in,
                              void* d_out, int out_size, void* d_ws,
                              size_t ws_size, hipStream_t stream) {
  const float* kr = (const float*)d_in[0];
  const float* ki = (const float*)d_in[1];
  const float* mask = (const float*)d_in[2];
  const float* sr = (const float*)d_in[3];
  const float* si = (const float*)d_in[4];
  const float* fl = (const float*)d_in[5];
  float* out = (float*)d_out;

  const size_t tmp1 = (size_t)NT * NX * NX * 4;      // fp16 complex, per coil
  const size_t kT_b = (size_t)NC * NX * NX * 8;
  const size_t sT_b = kT_b;
  const size_t fs_b = (size_t)NT * NX * NX * 8;
  const size_t mp_b = (size_t)NC * NX * NX * 4;
  const size_t ia_b = (size_t)NT * NX * NX * 8;
  const size_t of_b = (size_t)NX * NX * 8;
  const size_t op1 = (size_t)NT * NX * NX * 8;       // per scatter segment

  int NSEG = 2, G = 16;
  for (;;) {
    size_t fixed = kT_b + sT_b + fs_b + mp_b + ia_b + of_b + NSEG * op1;
    if (ws_size >= fixed + (size_t)G * tmp1) break;
    if (G > 1) { G >>= 1; continue; }
    if (NSEG > 1) { NSEG >>= 1; G = 16; continue; }
    break;  // minimal config; assume it fits
  }

  char* w = (char*)d_ws;
  __half2* tmp = (__half2*)w;   w += (size_t)G * tmp1;
  float2* kT = (float2*)w;      w += kT_b;
  float2* sT = (float2*)w;      w += sT_b;
  float2* fs = (float2*)w;      w += fs_b;
  float2* im_aux = (float2*)w;  w += ia_b;
  float* out_p = (float*)w;     w += (size_t)NSEG * op1;
  float* out_f = (float*)w;     w += of_b;
  unsigned int* mp = (unsigned int*)w;

  pack_mask_k<<<dim3(NX / 16, NX), 256, 0, stream>>>(mask, mp);
  tr_cplx_k<<<dim3(NX / 16, NX), 256, 0, stream>>>(kr, ki, kT);
  tr_cplx_cxy_k<<<dim3(NX / 16, NX), 256, 0, stream>>>(sr, si, sT);
  tr_flow_k<<<dim3(NX / 32, NX), 256, 0, stream>>>(fl, fs);
  hipMemsetAsync(out_f, 0, of_b, stream);

  for (int c0 = 0; c0 < NC; c0 += G) {
    pass1_k<<<dim3(NX, G), 256, 0, stream>>>(kT, mp, tmp, c0);
    pass2_k<<<dim3(NX / 16, NT), 1024, 0, stream>>>(tmp, sT, im_aux, c0, G,
                                                    c0 == 0 ? 1 : 0);
  }
  scatter_k<<<dim3(NX / BR, NSEG, NT), 1024, 0, stream>>>(im_aux, fs, out_p,
                                                          out_f, NSEG);
  reduce_k<<<200, 256, 0, stream>>>(out_p, out_f, out, NSEG * NT);
}

// Round 8
// 385.769 us; speedup vs baseline: 1.1121x; 1.0771x over previous
//
#include <hip/hip_runtime.h>
#include <hip/hip_fp16.h>

// MRI adjoint: masked centered 2D IFFT per (coil,frame) -> conj(smaps) combine
// -> bilinear warp-adjoint scatter -> sum over frames. Nx=Ny=320, Nc=16, Nt=25.
//
// FFT: 320 = 5*64; one wave per transform (6-stage radix-2 across lanes via
// shfl_xor + per-lane twiddled radix-5). Centered: out[n]=(-1)^n IFFT[(-1)^k x].
// Complex carried as ext_vector float2 -> v_pk_{add,mul,fma}_f32.
// tmp (x-IFFT result) fp16 half2 [c][t][y][nx]; smaps + im_aux fp16 too.
// pass2 (round-8): 8-wave blocks, nx-tile 8, grid 1000 (3.9/CU), dbuf LDS
// (1 barrier/iter, 8-wave barriers), reg prefetch, XCD pair-swizzle on nxt.
// prep_k: all input-permute passes + out_f zero merged into one launch.
// Scatter: LDS-privatized row bands via unsafeAtomicAdd (native ds_add_f32;
// plain f32 atomicAdd is a CAS loop on AMD -- the round-2..4 bottleneck).

#define NX 320
#define NT 25
#define NC 16
#define BR 32
#define WH 16
static const float INV320 = 1.0f / 320.0f;

typedef float v2f __attribute__((ext_vector_type(2)));

__device__ __forceinline__ int rev6(int l) {
  return ((l & 1) << 5) | ((l & 2) << 3) | ((l & 4) << 1) |
         ((l & 8) >> 1) | ((l & 16) >> 3) | ((l & 32) >> 5);
}

struct Tw {
  float c[6], s[6];
  float c1, s1, c2, s2, c3, s3, c4, s4;
};

__device__ __forceinline__ void make_tw(int lane, Tw& tw) {
#pragma unroll
  for (int st = 0; st < 6; ++st) {
    int m = 32 >> st;
    int j = lane & (m - 1);
    float ang = 3.14159265358979323846f * (float)j / (float)m;
    __sincosf(ang, &tw.s[st], &tw.c[st]);
  }
  int k1 = rev6(lane);
  float b = (6.283185307179586f / 320.0f) * (float)k1;
  __sincosf(b, &tw.s1, &tw.c1);
  tw.c2 = tw.c1 * tw.c1 - tw.s1 * tw.s1;
  tw.s2 = 2.f * tw.c1 * tw.s1;
  tw.c3 = tw.c2 * tw.c1 - tw.s2 * tw.s1;
  tw.s3 = tw.c2 * tw.s1 + tw.s2 * tw.c1;
  tw.c4 = tw.c2 * tw.c2 - tw.s2 * tw.s2;
  tw.s4 = 2.f * tw.c2 * tw.s2;
}

__device__ __forceinline__ v2f shfl_xor_v2(v2f z, int m) {
  v2f r;
  r.x = __shfl_xor(z.x, m);
  r.y = __shfl_xor(z.y, m);
  return r;
}

// (z.x + i z.y) * (c + i s)
__device__ __forceinline__ v2f cmul(v2f z, float c, float s) {
  v2f sw = {-z.y, z.x};
  return c * z + s * sw;
}

// Unnormalized inverse 320-pt DFT: lane l enters with x[5l+q] in z[q];
// exits with X[rev6(l) + 64*q].
__device__ __forceinline__ void fft320p(v2f z[5], int lane, const Tw& tw) {
#pragma unroll
  for (int st = 0; st < 6; ++st) {
    int m = 32 >> st;
    float c = tw.c[st], s = tw.s[st];
    bool bot = (lane & m) != 0;
#pragma unroll
    for (int q = 0; q < 5; ++q) {
      v2f o = shfl_xor_v2(z[q], m);
      v2f sum = z[q] + o;
      v2f dif = o - z[q];
      v2f tv = cmul(dif, c, s);
      z[q] = bot ? tv : sum;
    }
  }
  v2f t0 = z[0];
  v2f t1 = cmul(z[1], tw.c1, tw.s1);
  v2f t2 = cmul(z[2], tw.c2, tw.s2);
  v2f t3 = cmul(z[3], tw.c3, tw.s3);
  v2f t4 = cmul(z[4], tw.c4, tw.s4);
  const float C1 = 0.30901699437494742f, S1 = 0.95105651629515357f;
  const float C2 = -0.80901699437494742f, S2 = 0.58778525229247312f;
  v2f a1 = t1 + t4, b1 = t1 - t4;
  v2f a2 = t2 + t3, b2 = t2 - t3;
  z[0] = t0 + a1 + a2;
  v2f p = t0 + C1 * a1 + C2 * a2;
  v2f q_ = S1 * b1 + S2 * b2;
  v2f r = t0 + C2 * a1 + C1 * a2;
  v2f u = S2 * b1 - S1 * b2;
  v2f qi = {-q_.y, q_.x};
  v2f ui = {-u.y, u.x};
  z[1] = p + qi;
  z[4] = p - qi;
  z[2] = r + ui;
  z[3] = r - ui;
}

// Merged pre-pass: role-switched on blockIdx.x.
//  [0,6400)    mask [x][y][c][t] -> bit-packed mp[c][y][x]
//  [6400,12800)  kspace [x][y][c] -> kT[c][y][x] float2
//  [12800,19200) smaps [x][y][c] -> sT[c][x][y] half2
//  [19200,22400) flow [nx][ny][2][t] -> fs[t][nx][ny] float2
//  [22400,22600) zero out_f
__global__ __launch_bounds__(256) void prep_k(
    const float* __restrict__ mask, const float* __restrict__ kr,
    const float* __restrict__ ki, const float* __restrict__ sr,
    const float* __restrict__ si, const float* __restrict__ fl,
    unsigned int* __restrict__ mp, float2* __restrict__ kT,
    __half2* __restrict__ sT, float2* __restrict__ fs,
    float* __restrict__ out_f) {
  int bid = blockIdx.x, tid = threadIdx.x;
  if (bid < 6400) {
    int xt = bid % 20, y = bid / 20;
    int xx = tid >> 4, c = tid & 15;
    int x = xt * 16 + xx;
    const float* src = mask + (size_t)(x * NX + y) * (NC * NT) + c * NT;
    unsigned int bits = 0;
#pragma unroll
    for (int t = 0; t < NT; ++t) bits |= (src[t] != 0.f) ? (1u << t) : 0u;
    __shared__ unsigned int tileu[16][17];
    tileu[xx][c] = bits;
    __syncthreads();
    int c2 = tid >> 4, xx2 = tid & 15;
    mp[((size_t)(c2 * NX + y)) * NX + xt * 16 + xx2] = tileu[xx2][c2];
  } else if (bid < 12800) {
    int r = bid - 6400;
    int xt = r % 20, y = r / 20;
    int xx = tid >> 4, c = tid & 15;
    size_t si_ = (size_t)((xt * 16 + xx) * NX + y) * NC + c;
    __shared__ float2 tilef[16][17];
    tilef[xx][c] = make_float2(kr[si_], ki[si_]);
    __syncthreads();
    int c2 = tid >> 4, xx2 = tid & 15;
    kT[((size_t)(c2 * NX + y)) * NX + xt * 16 + xx2] = tilef[xx2][c2];
  } else if (bid < 19200) {
    int r = bid - 12800;
    int yt = r % 20, x = r / 20;
    int yy = tid >> 4, c = tid & 15;
    size_t si_ = (size_t)(x * NX + yt * 16 + yy) * NC + c;
    __shared__ float2 tilef[16][17];
    tilef[yy][c] = make_float2(sr[si_], si[si_]);
    __syncthreads();
    int c2 = tid >> 4, yy2 = tid & 15;
    float2 v = tilef[yy2][c2];
    sT[((size_t)(c2 * NX + x)) * NX + yt * 16 + yy2] = __floats2half2_rn(v.x, v.y);
  } else if (bid < 22400) {
    int r = bid - 19200;
    int nyt = r % 10, nx = r / 10;
    __shared__ float buf[1600];
    size_t base = (size_t)(nx * NX + nyt * 32) * (2 * NT);
    for (int f = tid; f < 1600; f += 256) buf[f] = fl[base + f];
    __syncthreads();
    for (int f = tid; f < 1600; f += 256) {
      int t = f / 64;
      int k = f % 64;
      int nyl = k >> 1, d = k & 1;
      size_t di = ((size_t)(t * NX + nx) * NX + nyt * 32 + nyl) * 2 + d;
      ((float*)fs)[di] = buf[(nyl * 2 + d) * NT + t];
    }
  } else {
    int idx = (bid - 22400) * 256 + tid;  // 51200 float4
    ((float4*)out_f)[idx] = make_float4(0.f, 0.f, 0.f, 0.f);
  }
}

// Pass 1: x-axis IFFT for coil chunk [c0, c0+G). Writes tmp[cg][t][y][nx] fp16.
__global__ __launch_bounds__(256) void pass1_k(
    const float2* __restrict__ kT, const unsigned int* __restrict__ mp,
    __half2* __restrict__ tmp, int c0) {
  int y = blockIdx.x, cg = blockIdx.y, c = c0 + cg;
  int tid = threadIdx.x, lane = tid & 63, w = tid >> 6;
  v2f v[5];
  unsigned int mb[5];
  size_t rowbase = ((size_t)c * NX + y) * NX;
#pragma unroll
  for (int q = 0; q < 5; ++q) {
    int x = 5 * lane + q;
    float2 kv = kT[rowbase + x];
    float sg = ((lane + q) & 1) ? -INV320 : INV320;  // (-1)^x / 320
    v[q].x = kv.x * sg;
    v[q].y = kv.y * sg;
    mb[q] = mp[rowbase + x];
  }
  Tw tw;
  make_tw(lane, tw);
  int r6 = rev6(lane);
  float osg = (lane & 32) ? -1.f : 1.f;  // (-1)^nx
  for (int t = w; t < NT; t += 4) {
    v2f z[5];
#pragma unroll
    for (int q = 0; q < 5; ++q) {
      float m = ((mb[q] >> t) & 1u) ? 1.f : 0.f;
      z[q] = v[q] * m;
    }
    fft320p(z, lane, tw);
    __half2* dst = tmp + ((size_t)(cg * NT + t) * NX + y) * NX;
#pragma unroll
    for (int k2 = 0; k2 < 5; ++k2)
      dst[r6 + 64 * k2] = __floats2half2_rn(z[k2].x * osg, z[k2].y * osg);
  }
}

// Pass 2: y-axis IFFT + conj(smaps) combine -> im_aux[t][nx][ny] fp16.
// 512 threads = 8 waves; block = (nx-tile of 8, t); wave j owns nx.
// Double-buffered LDS tile (1 barrier/iter) + 1-deep register prefetch.
// nxt swizzled so partner tiles (sharing 64B lines) land on the same XCD.
__global__ __launch_bounds__(512) void pass2_k(
    const __half2* __restrict__ tmp, const __half2* __restrict__ sT,
    __half2* __restrict__ im_aux, int c0, int G, int first) {
  int bx = blockIdx.x, t = blockIdx.y;
  int nxt_ = (bx & 7) * 5 + (bx >> 3);  // 40 = 8*5, bijective
  int tid = threadIdx.x, lane = tid & 63, j = tid >> 6;
  int nx = nxt_ * 8 + j;
  int k1 = rev6(lane);
  Tw tw;
  make_tw(lane, tw);
  __shared__ __half2 tile[2][NX][9];  // 23 KB
  v2f acc[5] = {{0, 0}, {0, 0}, {0, 0}, {0, 0}, {0, 0}};

  int off[5], lw[5];
#pragma unroll
  for (int q = 0; q < 5; ++q) {
    int f = tid + q * 512;
    off[q] = (f >> 3) * NX + (f & 7);
    lw[q] = (f >> 3) * 9 + (f & 7);
  }
  const size_t pstride = (size_t)NT * NX * NX;
  const __half2* sbase = tmp + (size_t)t * NX * NX + nxt_ * 8;
  __half2* lds = &tile[0][0][0];

  __half2 nb[5];
#pragma unroll
  for (int q = 0; q < 5; ++q) nb[q] = sbase[off[q]];

  for (int cg = 0; cg < G; ++cg) {
    __half2 cb[5];
#pragma unroll
    for (int q = 0; q < 5; ++q) cb[q] = nb[q];
    if (cg + 1 < G) {
      const __half2* s = sbase + (size_t)(cg + 1) * pstride;
#pragma unroll
      for (int q = 0; q < 5; ++q) nb[q] = s[off[q]];  // in flight across iter
    }
    __half2* buf = lds + (cg & 1) * (NX * 9);
#pragma unroll
    for (int q = 0; q < 5; ++q) buf[lw[q]] = cb[q];
    // smaps row loads issue before the barrier (independent of tile)
    const __half2* srow = sT + ((size_t)(c0 + cg) * NX + nx) * NX;
    __half2 smh[5];
#pragma unroll
    for (int k2 = 0; k2 < 5; ++k2) smh[k2] = srow[k1 + 64 * k2];
    __syncthreads();
    v2f z[5];
#pragma unroll
    for (int q = 0; q < 5; ++q) {
      float2 v = __half22float2(buf[(5 * lane + q) * 9 + j]);
      float sg = ((lane + q) & 1) ? -1.f : 1.f;  // (-1)^y
      z[q].x = v.x * sg;
      z[q].y = v.y * sg;
    }
    fft320p(z, lane, tw);
#pragma unroll
    for (int k2 = 0; k2 < 5; ++k2) {
      float2 sm = __half22float2(smh[k2]);
      v2f zc = {z[k2].y, -z[k2].x};  // conj-MAC helper
      acc[k2] += sm.x * z[k2] + sm.y * zc;
    }
  }
  float osg = (lane & 32) ? -1.f : 1.f;  // (-1)^ny
  __half2* dst = im_aux + ((size_t)t * NX + nx) * NX;
#pragma unroll
  for (int k2 = 0; k2 < 5; ++k2) {
    int ny = k1 + 64 * k2;
    v2f nv = {acc[k2].x * osg, acc[k2].y * osg};
    if (!first) {
      float2 old = __half22float2(dst[ny]);
      nv.x += old.x;
      nv.y += old.y;
    }
    dst[ny] = __floats2half2_rn(nv.x, nv.y);
  }
}

// Scatter: block (band b, seg, frame t). LDS-privatized 32-row band.
__global__ __launch_bounds__(1024) void scatter_k(
    const __half2* __restrict__ im, const float2* __restrict__ fs,
    float* __restrict__ out_p, float* __restrict__ out_f, int nseg) {
  int b = blockIdx.x, seg = blockIdx.y, t = blockIdx.z;
  int r0 = b * BR;
  int tid = threadIdx.x, lane = tid & 63, w = tid >> 6;
  __shared__ float acc[BR * NX * 2];  // 80 KB
  for (int i = tid; i < BR * NX * 2; i += 1024) acc[i] = 0.f;
  __syncthreads();
  int lo = max(r0 - WH, 0), hi = min(r0 + BR + WH, NX);
  int stride = 16 * nseg;
  for (int nx = lo + seg * 16 + w; nx < hi; nx += stride) {
    bool own = (nx >= r0) && (nx < r0 + BR);
    const __half2* imrow = im + ((size_t)t * NX + nx) * NX;
    const float2* frow = fs + ((size_t)t * NX + nx) * NX;
#pragma unroll
    for (int q = 0; q < 5; ++q) {
      int ny = lane + 64 * q;
      float2 v = __half22float2(imrow[ny]);
      float2 fl = frow[ny];
      float px = fminf(fmaxf((float)nx + fl.x, 0.f), 319.f);
      float py = fminf(fmaxf((float)ny + fl.y, 0.f), 319.f);
      int x0 = (int)floorf(px), y0 = (int)floorf(py);
      int x1 = min(x0 + 1, NX - 1), y1 = min(y0 + 1, NX - 1);
      float wx = px - (float)x0, wy = py - (float)y0;
      float w00 = (1.f - wx) * (1.f - wy), w01 = (1.f - wx) * wy;
      float w10 = wx * (1.f - wy), w11 = wx * wy;
#pragma unroll
      for (int half = 0; half < 2; ++half) {
        int r = half ? x1 : x0;
        float wa = half ? w10 : w00;
        float wb = half ? w11 : w01;
        if (r >= r0 && r < r0 + BR) {
          float* p0 = &acc[((r - r0) * NX + y0) * 2];
          float* p1 = &acc[((r - r0) * NX + y1) * 2];
          unsafeAtomicAdd(p0, wa * v.x);
          unsafeAtomicAdd(p0 + 1, wa * v.y);
          unsafeAtomicAdd(p1, wb * v.x);
          unsafeAtomicAdd(p1 + 1, wb * v.y);
        } else if (own) {
          int rb = (r / BR) * BR;
          if (nx < rb - WH || nx >= rb + BR + WH) {  // no band reads nx
            unsafeAtomicAdd(&out_f[((size_t)r * NX + y0) * 2], wa * v.x);
            unsafeAtomicAdd(&out_f[((size_t)r * NX + y0) * 2 + 1], wa * v.y);
            unsafeAtomicAdd(&out_f[((size_t)r * NX + y1) * 2], wb * v.x);
            unsafeAtomicAdd(&out_f[((size_t)r * NX + y1) * 2 + 1], wb * v.y);
          }
        }
      }
    }
  }
  __syncthreads();
  float* dst = out_p + ((size_t)(seg * NT + t) * NX + r0) * NX * 2;
  for (int i = tid; i < BR * NX * 2; i += 1024) dst[i] = acc[i];
}

// out = out_f + sum_{seg,t} out_p
__global__ __launch_bounds__(256) void reduce_k(
    const float* __restrict__ out_p, const float* __restrict__ out_f,
    float* __restrict__ out, int nslice) {
  const int n4 = NX * NX * 2 / 4;
  int i = blockIdx.x * 256 + threadIdx.x;
  if (i >= n4) return;
  float4 s = ((const float4*)out_f)[i];
  for (int k = 0; k < nslice; ++k) {
    float4 v = ((const float4*)out_p)[(size_t)k * n4 + i];
    s.x += v.x; s.y += v.y; s.z += v.z; s.w += v.w;
  }
  ((float4*)out)[i] = s;
}

extern "C" void kernel_launch(void* const* d_in, const int* in_sizes, int n_in,
                              void* d_out, int out_size, void* d_ws,
                              size_t ws_size, hipStream_t stream) {
  const float* kr = (const float*)d_in[0];
  const float* ki = (const float*)d_in[1];
  const float* mask = (const float*)d_in[2];
  const float* sr = (const float*)d_in[3];
  const float* si = (const float*)d_in[4];
  const float* fl = (const float*)d_in[5];
  float* out = (float*)d_out;

  const size_t tmp1 = (size_t)NT * NX * NX * 4;      // fp16 complex, per coil
  const size_t kT_b = (size_t)NC * NX * NX * 8;
  const size_t sT_b = (size_t)NC * NX * NX * 4;      // half2
  const size_t fs_b = (size_t)NT * NX * NX * 8;
  const size_t mp_b = (size_t)NC * NX * NX * 4;
  const size_t ia_b = (size_t)NT * NX * NX * 4;      // half2
  const size_t of_b = (size_t)NX * NX * 8;
  const size_t op1 = (size_t)NT * NX * NX * 8;       // per scatter segment

  int NSEG = 2, G = 16;
  for (;;) {
    size_t fixed = kT_b + sT_b + fs_b + mp_b + ia_b + of_b + NSEG * op1;
    if (ws_size >= fixed + (size_t)G * tmp1) break;
    if (G > 1) { G >>= 1; continue; }
    if (NSEG > 1) { NSEG >>= 1; G = 16; continue; }
    break;  // minimal config; assume it fits
  }

  char* w = (char*)d_ws;
  __half2* tmp = (__half2*)w;   w += (size_t)G * tmp1;
  float2* kT = (float2*)w;      w += kT_b;
  __half2* sT = (__half2*)w;    w += sT_b;
  float2* fs = (float2*)w;      w += fs_b;
  __half2* im_aux = (__half2*)w; w += ia_b;
  float* out_p = (float*)w;     w += (size_t)NSEG * op1;
  float* out_f = (float*)w;     w += of_b;
  unsigned int* mp = (unsigned int*)w;

  prep_k<<<22600, 256, 0, stream>>>(mask, kr, ki, sr, si, fl, mp, kT, sT, fs,
                                    out_f);

  for (int c0 = 0; c0 < NC; c0 += G) {
    pass1_k<<<dim3(NX, G), 256, 0, stream>>>(kT, mp, tmp, c0);
    pass2_k<<<dim3(40, NT), 512, 0, stream>>>(tmp, sT, im_aux, c0, G,
                                              c0 == 0 ? 1 : 0);
  }
  scatter_k<<<dim3(NX / BR, NSEG, NT), 1024, 0, stream>>>(im_aux, fs, out_p,
                                                          out_f, NSEG);
  reduce_k<<<200, 256, 0, stream>>>(out_p, out_f, out, NSEG * NT);
}

// Round 9
// 380.903 us; speedup vs baseline: 1.1263x; 1.0128x over previous
//
#include <hip/hip_runtime.h>
#include <hip/hip_fp16.h>

// MRI adjoint: masked centered 2D IFFT per (coil,frame) -> conj(smaps) combine
// -> bilinear warp-adjoint scatter -> sum over frames. Nx=Ny=320, Nc=16, Nt=25.
//
// FFT: 320 = 5*64; one wave per transform (6-stage radix-2 across lanes +
// per-lane twiddled radix-5). Cross-lane via immediate ds_swizzle (m<=16) and
// shfl_xor (m=32) -- kills bpermute address-setup VALU.
// Centered: (-1)^kx/(-1)^ky input signs and (-1)^nx/(-1)^ky output signs all
// folded into pass1; (-1)^ny folded into pre-signed smaps (prep).
// tmp fp16 half2 [c][t][ky][nx]; smaps/im_aux fp16.
// pass2: nx-tile 4, 256-thr blocks, grid 80x25, XCD swizzle keeps the 16 nx
// sharing a 64B line on one XCD (L2 absorbs fragment partners, round-8-proven).
// Scatter: LDS-privatized row bands via unsafeAtomicAdd (native ds_add_f32;
// plain f32 atomicAdd is a CAS loop on AMD -- the round-2..4 bottleneck).

#define NX 320
#define NT 25
#define NC 16
#define BR 32
#define WH 16
static const float INV320 = 1.0f / 320.0f;

typedef float v2f __attribute__((ext_vector_type(2)));

__device__ __forceinline__ int rev6(int l) {
  return ((l & 1) << 5) | ((l & 2) << 3) | ((l & 4) << 1) |
         ((l & 8) >> 1) | ((l & 16) >> 3) | ((l & 32) >> 5);
}

struct Tw {
  float c[6], s[6];
  float c1, s1, c2, s2, c3, s3, c4, s4;
};

__device__ __forceinline__ void make_tw(int lane, Tw& tw) {
#pragma unroll
  for (int st = 0; st < 6; ++st) {
    int m = 32 >> st;
    int j = lane & (m - 1);
    float ang = 3.14159265358979323846f * (float)j / (float)m;
    __sincosf(ang, &tw.s[st], &tw.c[st]);
  }
  int k1 = rev6(lane);
  float b = (6.283185307179586f / 320.0f) * (float)k1;
  __sincosf(b, &tw.s1, &tw.c1);
  tw.c2 = tw.c1 * tw.c1 - tw.s1 * tw.s1;
  tw.s2 = 2.f * tw.c1 * tw.s1;
  tw.c3 = tw.c2 * tw.c1 - tw.s2 * tw.s1;
  tw.s3 = tw.c2 * tw.s1 + tw.s2 * tw.c1;
  tw.c4 = tw.c2 * tw.c2 - tw.s2 * tw.s2;
  tw.s4 = 2.f * tw.c2 * tw.s2;
}

template <int M>
__device__ __forceinline__ float lxor(float x) {
  if constexpr (M == 32) {
    return __shfl_xor(x, 32);
  } else {
    constexpr int pat = (M << 10) | 0x1F;  // BitMode: xor=M, and=0x1F
    return __int_as_float(__builtin_amdgcn_ds_swizzle(__float_as_int(x), pat));
  }
}

// (z.x + i z.y) * (c + i s)
__device__ __forceinline__ v2f cmul(v2f z, float c, float s) {
  v2f sw = {-z.y, z.x};
  return c * z + s * sw;
}

template <int M>
__device__ __forceinline__ void bfly(v2f z[5], int lane, float c, float s) {
  bool bot = (lane & M) != 0;
#pragma unroll
  for (int q = 0; q < 5; ++q) {
    v2f o;
    o.x = lxor<M>(z[q].x);
    o.y = lxor<M>(z[q].y);
    v2f sum = z[q] + o;
    v2f dif = o - z[q];
    v2f tv = cmul(dif, c, s);
    z[q] = bot ? tv : sum;
  }
}

// Unnormalized inverse 320-pt DFT: lane l enters with x[5l+q] in z[q];
// exits with X[rev6(l) + 64*q].
__device__ __forceinline__ void fft320p(v2f z[5], int lane, const Tw& tw) {
  bfly<32>(z, lane, tw.c[0], tw.s[0]);
  bfly<16>(z, lane, tw.c[1], tw.s[1]);
  bfly<8>(z, lane, tw.c[2], tw.s[2]);
  bfly<4>(z, lane, tw.c[3], tw.s[3]);
  bfly<2>(z, lane, tw.c[4], tw.s[4]);
  bfly<1>(z, lane, tw.c[5], tw.s[5]);
  v2f t0 = z[0];
  v2f t1 = cmul(z[1], tw.c1, tw.s1);
  v2f t2 = cmul(z[2], tw.c2, tw.s2);
  v2f t3 = cmul(z[3], tw.c3, tw.s3);
  v2f t4 = cmul(z[4], tw.c4, tw.s4);
  const float C1 = 0.30901699437494742f, S1 = 0.95105651629515357f;
  const float C2 = -0.80901699437494742f, S2 = 0.58778525229247312f;
  v2f a1 = t1 + t4, b1 = t1 - t4;
  v2f a2 = t2 + t3, b2 = t2 - t3;
  z[0] = t0 + a1 + a2;
  v2f p = t0 + C1 * a1 + C2 * a2;
  v2f q_ = S1 * b1 + S2 * b2;
  v2f r = t0 + C2 * a1 + C1 * a2;
  v2f u = S2 * b1 - S1 * b2;
  v2f qi = {-q_.y, q_.x};
  v2f ui = {-u.y, u.x};
  z[1] = p + qi;
  z[4] = p - qi;
  z[2] = r + ui;
  z[3] = r - ui;
}

// Merged pre-pass: role-switched on blockIdx.x.
//  [0,6400)      mask [x][y][c][t] -> bit-packed mp[c][y][x] (float4-staged)
//  [6400,12800)  kspace [x][y][c] -> kT[c][y][x] float2
//  [12800,19200) smaps [x][y][c] -> sT[c][x][y] half2, pre-signed by (-1)^y
//  [19200,22400) flow [nx][ny][2][t] -> fs[t][nx][ny] float2
//  [22400,22600) zero out_f
__global__ __launch_bounds__(256) void prep_k(
    const float* __restrict__ mask, const float* __restrict__ kr,
    const float* __restrict__ ki, const float* __restrict__ sr,
    const float* __restrict__ si, const float* __restrict__ fl,
    unsigned int* __restrict__ mp, float2* __restrict__ kT,
    __half2* __restrict__ sT, float2* __restrict__ fs,
    float* __restrict__ out_f) {
  int bid = blockIdx.x, tid = threadIdx.x;
  if (bid < 6400) {
    int xt = bid % 20, y = bid / 20;
    __shared__ float4 mrow4[16][101];  // [xx][(c*25+t)/4]
    const float* mbase = mask + ((size_t)(xt * 16) * NX + y) * (NC * NT);
    for (int k = tid; k < 1600; k += 256) {
      int xx = k / 100, f4 = k % 100;
      const float4* p =
          (const float4*)(mbase + (size_t)xx * NX * (NC * NT));
      mrow4[xx][f4] = p[f4];
    }
    __shared__ unsigned int tileu[16][17];
    __syncthreads();
    int xx = tid >> 4, c = tid & 15;
    const float* row = (const float*)&mrow4[xx][0];
    unsigned int bits = 0;
#pragma unroll
    for (int t = 0; t < NT; ++t)
      bits |= (row[c * NT + t] != 0.f) ? (1u << t) : 0u;
    tileu[xx][c] = bits;
    __syncthreads();
    int c2 = tid >> 4, xx2 = tid & 15;
    mp[((size_t)(c2 * NX + y)) * NX + xt * 16 + xx2] = tileu[xx2][c2];
  } else if (bid < 12800) {
    int r = bid - 6400;
    int xt = r % 20, y = r / 20;
    int xx = tid >> 4, c = tid & 15;
    size_t si_ = (size_t)((xt * 16 + xx) * NX + y) * NC + c;
    __shared__ float2 tilef[16][17];
    tilef[xx][c] = make_float2(kr[si_], ki[si_]);
    __syncthreads();
    int c2 = tid >> 4, xx2 = tid & 15;
    kT[((size_t)(c2 * NX + y)) * NX + xt * 16 + xx2] = tilef[xx2][c2];
  } else if (bid < 19200) {
    int r = bid - 12800;
    int yt = r % 20, x = r / 20;
    int yy = tid >> 4, c = tid & 15;
    size_t si_ = (size_t)(x * NX + yt * 16 + yy) * NC + c;
    __shared__ float2 tiles[16][17];
    tiles[yy][c] = make_float2(sr[si_], si[si_]);
    __syncthreads();
    int c2 = tid >> 4, yy2 = tid & 15;
    float2 v = tiles[yy2][c2];
    float sg = (yy2 & 1) ? -1.f : 1.f;  // (-1)^ny pre-sign
    sT[((size_t)(c2 * NX + x)) * NX + yt * 16 + yy2] =
        __floats2half2_rn(v.x * sg, v.y * sg);
  } else if (bid < 22400) {
    int r = bid - 19200;
    int nyt = r % 10, nx = r / 10;
    __shared__ float buf[1600];
    size_t base = (size_t)(nx * NX + nyt * 32) * (2 * NT);
    for (int f = tid; f < 1600; f += 256) buf[f] = fl[base + f];
    __syncthreads();
    for (int f = tid; f < 1600; f += 256) {
      int t = f / 64;
      int k = f % 64;
      int nyl = k >> 1, d = k & 1;
      size_t di = ((size_t)(t * NX + nx) * NX + nyt * 32 + nyl) * 2 + d;
      ((float*)fs)[di] = buf[(nyl * 2 + d) * NT + t];
    }
  } else {
    int idx = (bid - 22400) * 256 + tid;  // 51200 float4
    ((float4*)out_f)[idx] = make_float4(0.f, 0.f, 0.f, 0.f);
  }
}

// Pass 1: x-axis IFFT for coil chunk [c0, c0+G). Writes tmp[cg][t][ky][nx]
// fp16, pre-signed by (-1)^nx * (-1)^ky (both centered-transform signs).
__global__ __launch_bounds__(256) void pass1_k(
    const float2* __restrict__ kT, const unsigned int* __restrict__ mp,
    __half2* __restrict__ tmp, int c0) {
  int y = blockIdx.x, cg = blockIdx.y, c = c0 + cg;
  int tid = threadIdx.x, lane = tid & 63, w = tid >> 6;
  v2f v[5];
  unsigned int mb[5];
  size_t rowbase = ((size_t)c * NX + y) * NX;
#pragma unroll
  for (int q = 0; q < 5; ++q) {
    int x = 5 * lane + q;
    float2 kv = kT[rowbase + x];
    float sg = ((lane + q) & 1) ? -INV320 : INV320;  // (-1)^x / 320
    v[q].x = kv.x * sg;
    v[q].y = kv.y * sg;
    mb[q] = mp[rowbase + x];
  }
  Tw tw;
  make_tw(lane, tw);
  int r6 = rev6(lane);
  // (-1)^nx (nx=rev6+64k2, flips on lane bit 5) times (-1)^ky (block-uniform)
  float osg = ((lane & 32) ? -1.f : 1.f) * ((y & 1) ? -1.f : 1.f);
  for (int t = w; t < NT; t += 4) {
    v2f z[5];
#pragma unroll
    for (int q = 0; q < 5; ++q) {
      float m = ((mb[q] >> t) & 1u) ? 1.f : 0.f;
      z[q] = v[q] * m;
    }
    fft320p(z, lane, tw);
    __half2* dst = tmp + ((size_t)(cg * NT + t) * NX + y) * NX;
#pragma unroll
    for (int k2 = 0; k2 < 5; ++k2)
      dst[r6 + 64 * k2] = __floats2half2_rn(z[k2].x * osg, z[k2].y * osg);
  }
}

// Pass 2: y-axis IFFT + conj(smaps) combine -> im_aux[t][nx][ny] fp16.
// 256 threads = 4 waves; block = (nx-tile of 4, t); wave j owns nx.
// Double-buffered LDS tile (1 barrier/iter) + 1-deep register prefetch.
// bx->nxt swizzle: nx in [40p,40p+40) all map to XCD p, so the 4 blocks
// sharing each 64B tmp line are co-resident on one XCD's L2.
__global__ __launch_bounds__(256) void pass2_k(
    const __half2* __restrict__ tmp, const __half2* __restrict__ sT,
    __half2* __restrict__ im_aux, int c0, int G, int first) {
  int bx = blockIdx.x, t = blockIdx.y;
  int nxt_ = (bx >> 3) + 10 * (bx & 7);  // bijective on [0,80)
  int tid = threadIdx.x, lane = tid & 63, j = tid >> 6;
  int nx = nxt_ * 4 + j;
  int k1 = rev6(lane);
  Tw tw;
  make_tw(lane, tw);
  __shared__ __half2 tile[2][NX][5];  // 12.8 KB
  v2f acc[5] = {{0, 0}, {0, 0}, {0, 0}, {0, 0}, {0, 0}};

  int off[5], lw[5];
#pragma unroll
  for (int q = 0; q < 5; ++q) {
    int f = tid + q * 256;
    off[q] = (f >> 2) * NX + (f & 3);
    lw[q] = (f >> 2) * 5 + (f & 3);
  }
  const size_t pstride = (size_t)NT * NX * NX;
  const __half2* sbase = tmp + (size_t)t * NX * NX + nxt_ * 4;
  __half2* lds = &tile[0][0][0];

  __half2 nb[5];
#pragma unroll
  for (int q = 0; q < 5; ++q) nb[q] = sbase[off[q]];

  for (int cg = 0; cg < G; ++cg) {
    __half2 cb[5];
#pragma unroll
    for (int q = 0; q < 5; ++q) cb[q] = nb[q];
    if (cg + 1 < G) {
      const __half2* s = sbase + (size_t)(cg + 1) * pstride;
#pragma unroll
      for (int q = 0; q < 5; ++q) nb[q] = s[off[q]];  // in flight across iter
    }
    __half2* buf = lds + (cg & 1) * (NX * 5);
#pragma unroll
    for (int q = 0; q < 5; ++q) buf[lw[q]] = cb[q];
    // smaps row loads issue before the barrier (independent of tile)
    const __half2* srow = sT + ((size_t)(c0 + cg) * NX + nx) * NX;
    __half2 smh[5];
#pragma unroll
    for (int k2 = 0; k2 < 5; ++k2) smh[k2] = srow[k1 + 64 * k2];
    __syncthreads();
    v2f z[5];
#pragma unroll
    for (int q = 0; q < 5; ++q) {
      float2 v = __half22float2(buf[(5 * lane + q) * 5 + j]);
      z[q].x = v.x;  // signs pre-folded in pass1
      z[q].y = v.y;
    }
    fft320p(z, lane, tw);
#pragma unroll
    for (int k2 = 0; k2 < 5; ++k2) {
      float2 sm = __half22float2(smh[k2]);
      v2f zc = {z[k2].y, -z[k2].x};  // conj-MAC helper
      acc[k2] += sm.x * z[k2] + sm.y * zc;
    }
  }
  __half2* dst = im_aux + ((size_t)t * NX + nx) * NX;
#pragma unroll
  for (int k2 = 0; k2 < 5; ++k2) {
    int ny = k1 + 64 * k2;
    v2f nv = acc[k2];  // (-1)^ny folded into sT
    if (!first) {
      float2 old = __half22float2(dst[ny]);
      nv.x += old.x;
      nv.y += old.y;
    }
    dst[ny] = __floats2half2_rn(nv.x, nv.y);
  }
}

// Scatter: block (band b, seg, frame t). LDS-privatized 32-row band.
__global__ __launch_bounds__(1024) void scatter_k(
    const __half2* __restrict__ im, const float2* __restrict__ fs,
    float* __restrict__ out_p, float* __restrict__ out_f, int nseg) {
  int b = blockIdx.x, seg = blockIdx.y, t = blockIdx.z;
  int r0 = b * BR;
  int tid = threadIdx.x, lane = tid & 63, w = tid >> 6;
  __shared__ float acc[BR * NX * 2];  // 80 KB
  for (int i = tid; i < BR * NX * 2; i += 1024) acc[i] = 0.f;
  __syncthreads();
  int lo = max(r0 - WH, 0), hi = min(r0 + BR + WH, NX);
  int stride = 16 * nseg;
  for (int nx = lo + seg * 16 + w; nx < hi; nx += stride) {
    bool own = (nx >= r0) && (nx < r0 + BR);
    const __half2* imrow = im + ((size_t)t * NX + nx) * NX;
    const float2* frow = fs + ((size_t)t * NX + nx) * NX;
#pragma unroll
    for (int q = 0; q < 5; ++q) {
      int ny = lane + 64 * q;
      float2 v = __half22float2(imrow[ny]);
      float2 fl = frow[ny];
      float px = fminf(fmaxf((float)nx + fl.x, 0.f), 319.f);
      float py = fminf(fmaxf((float)ny + fl.y, 0.f), 319.f);
      int x0 = (int)floorf(px), y0 = (int)floorf(py);
      int x1 = min(x0 + 1, NX - 1), y1 = min(y0 + 1, NX - 1);
      float wx = px - (float)x0, wy = py - (float)y0;
      float w00 = (1.f - wx) * (1.f - wy), w01 = (1.f - wx) * wy;
      float w10 = wx * (1.f - wy), w11 = wx * wy;
#pragma unroll
      for (int half = 0; half < 2; ++half) {
        int r = half ? x1 : x0;
        float wa = half ? w10 : w00;
        float wb = half ? w11 : w01;
        if (r >= r0 && r < r0 + BR) {
          float* p0 = &acc[((r - r0) * NX + y0) * 2];
          float* p1 = &acc[((r - r0) * NX + y1) * 2];
          unsafeAtomicAdd(p0, wa * v.x);
          unsafeAtomicAdd(p0 + 1, wa * v.y);
          unsafeAtomicAdd(p1, wb * v.x);
          unsafeAtomicAdd(p1 + 1, wb * v.y);
        } else if (own) {
          int rb = (r / BR) * BR;
          if (nx < rb - WH || nx >= rb + BR + WH) {  // no band reads nx
            unsafeAtomicAdd(&out_f[((size_t)r * NX + y0) * 2], wa * v.x);
            unsafeAtomicAdd(&out_f[((size_t)r * NX + y0) * 2 + 1], wa * v.y);
            unsafeAtomicAdd(&out_f[((size_t)r * NX + y1) * 2], wb * v.x);
            unsafeAtomicAdd(&out_f[((size_t)r * NX + y1) * 2 + 1], wb * v.y);
          }
        }
      }
    }
  }
  __syncthreads();
  float* dst = out_p + ((size_t)(seg * NT + t) * NX + r0) * NX * 2;
  for (int i = tid; i < BR * NX * 2; i += 1024) dst[i] = acc[i];
}

// out = out_f + sum_{seg,t} out_p
__global__ __launch_bounds__(256) void reduce_k(
    const float* __restrict__ out_p, const float* __restrict__ out_f,
    float* __restrict__ out, int nslice) {
  const int n4 = NX * NX * 2 / 4;
  int i = blockIdx.x * 256 + threadIdx.x;
  if (i >= n4) return;
  float4 s = ((const float4*)out_f)[i];
  for (int k = 0; k < nslice; ++k) {
    float4 v = ((const float4*)out_p)[(size_t)k * n4 + i];
    s.x += v.x; s.y += v.y; s.z += v.z; s.w += v.w;
  }
  ((float4*)out)[i] = s;
}

extern "C" void kernel_launch(void* const* d_in, const int* in_sizes, int n_in,
                              void* d_out, int out_size, void* d_ws,
                              size_t ws_size, hipStream_t stream) {
  const float* kr = (const float*)d_in[0];
  const float* ki = (const float*)d_in[1];
  const float* mask = (const float*)d_in[2];
  const float* sr = (const float*)d_in[3];
  const float* si = (const float*)d_in[4];
  const float* fl = (const float*)d_in[5];
  float* out = (float*)d_out;

  const size_t tmp1 = (size_t)NT * NX * NX * 4;      // fp16 complex, per coil
  const size_t kT_b = (size_t)NC * NX * NX * 8;
  const size_t sT_b = (size_t)NC * NX * NX * 4;      // half2
  const size_t fs_b = (size_t)NT * NX * NX * 8;
  const size_t mp_b = (size_t)NC * NX * NX * 4;
  const size_t ia_b = (size_t)NT * NX * NX * 4;      // half2
  const size_t of_b = (size_t)NX * NX * 8;
  const size_t op1 = (size_t)NT * NX * NX * 8;       // per scatter segment

  int NSEG = 2, G = 16;
  for (;;) {
    size_t fixed = kT_b + sT_b + fs_b + mp_b + ia_b + of_b + NSEG * op1;
    if (ws_size >= fixed + (size_t)G * tmp1) break;
    if (G > 1) { G >>= 1; continue; }
    if (NSEG > 1) { NSEG >>= 1; G = 16; continue; }
    break;  // minimal config; assume it fits
  }

  char* w = (char*)d_ws;
  __half2* tmp = (__half2*)w;   w += (size_t)G * tmp1;
  float2* kT = (float2*)w;      w += kT_b;
  __half2* sT = (__half2*)w;    w += sT_b;
  float2* fs = (float2*)w;      w += fs_b;
  __half2* im_aux = (__half2*)w; w += ia_b;
  float* out_p = (float*)w;     w += (size_t)NSEG * op1;
  float* out_f = (float*)w;     w += of_b;
  unsigned int* mp = (unsigned int*)w;

  prep_k<<<22600, 256, 0, stream>>>(mask, kr, ki, sr, si, fl, mp, kT, sT, fs,
                                    out_f);

  for (int c0 = 0; c0 < NC; c0 += G) {
    pass1_k<<<dim3(NX, G), 256, 0, stream>>>(kT, mp, tmp, c0);
    pass2_k<<<dim3(80, NT), 256, 0, stream>>>(tmp, sT, im_aux, c0, G,
                                              c0 == 0 ? 1 : 0);
  }
  scatter_k<<<dim3(NX / BR, NSEG, NT), 1024, 0, stream>>>(im_aux, fs, out_p,
                                                          out_f, NSEG);
  reduce_k<<<200, 256, 0, stream>>>(out_p, out_f, out, NSEG * NT);
}

// Round 10
// 327.229 us; speedup vs baseline: 1.3111x; 1.1640x over previous
//
#include <hip/hip_runtime.h>
#include <hip/hip_fp16.h>

// MRI adjoint: masked centered 2D IFFT per (coil,frame) -> conj(smaps) combine
// -> bilinear warp-adjoint scatter -> sum over frames. Nx=Ny=320, Nc=16, Nt=25.
//
// FFT: 320 = 5*64; one wave per transform (6-stage radix-2 across lanes +
// per-lane twiddled radix-5). Cross-lane via immediate ds_swizzle (m<=16) and
// shfl_xor (m=32). Centered-transform signs folded into pass1 & pre-signed
// smaps. tmp fp16 half2 [c][t][ky][nx]; smaps/im_aux fp16.
// Scatter (round-10): LDS accumulator is __half2 (re,im) and taps use
// ds_pk_add_f16 (unsafeAtomicAdd on __half2) -- LDS atomics are ~lane-
// serialized (round-9 evidence: 117us invariant across CAS/native/WH/NSEG,
// all pipes <8% busy), so halving lane-atomic count is the lever.
// 8 f32 atomics/element -> 4 pk16 atomics. LDS 80->40KB, out_p half2.

#define NX 320
#define NT 25
#define NC 16
#define BR 32
#define WH 16
static const float INV320 = 1.0f / 320.0f;

typedef float v2f __attribute__((ext_vector_type(2)));

__device__ __forceinline__ int rev6(int l) {
  return ((l & 1) << 5) | ((l & 2) << 3) | ((l & 4) << 1) |
         ((l & 8) >> 1) | ((l & 16) >> 3) | ((l & 32) >> 5);
}

struct Tw {
  float c[6], s[6];
  float c1, s1, c2, s2, c3, s3, c4, s4;
};

__device__ __forceinline__ void make_tw(int lane, Tw& tw) {
#pragma unroll
  for (int st = 0; st < 6; ++st) {
    int m = 32 >> st;
    int j = lane & (m - 1);
    float ang = 3.14159265358979323846f * (float)j / (float)m;
    __sincosf(ang, &tw.s[st], &tw.c[st]);
  }
  int k1 = rev6(lane);
  float b = (6.283185307179586f / 320.0f) * (float)k1;
  __sincosf(b, &tw.s1, &tw.c1);
  tw.c2 = tw.c1 * tw.c1 - tw.s1 * tw.s1;
  tw.s2 = 2.f * tw.c1 * tw.s1;
  tw.c3 = tw.c2 * tw.c1 - tw.s2 * tw.s1;
  tw.s3 = tw.c2 * tw.s1 + tw.s2 * tw.c1;
  tw.c4 = tw.c2 * tw.c2 - tw.s2 * tw.s2;
  tw.s4 = 2.f * tw.c2 * tw.s2;
}

template <int M>
__device__ __forceinline__ float lxor(float x) {
  if constexpr (M == 32) {
    return __shfl_xor(x, 32);
  } else {
    constexpr int pat = (M << 10) | 0x1F;  // BitMode: xor=M, and=0x1F
    return __int_as_float(__builtin_amdgcn_ds_swizzle(__float_as_int(x), pat));
  }
}

// (z.x + i z.y) * (c + i s)
__device__ __forceinline__ v2f cmul(v2f z, float c, float s) {
  v2f sw = {-z.y, z.x};
  return c * z + s * sw;
}

template <int M>
__device__ __forceinline__ void bfly(v2f z[5], int lane, float c, float s) {
  bool bot = (lane & M) != 0;
#pragma unroll
  for (int q = 0; q < 5; ++q) {
    v2f o;
    o.x = lxor<M>(z[q].x);
    o.y = lxor<M>(z[q].y);
    v2f sum = z[q] + o;
    v2f dif = o - z[q];
    v2f tv = cmul(dif, c, s);
    z[q] = bot ? tv : sum;
  }
}

// Unnormalized inverse 320-pt DFT: lane l enters with x[5l+q] in z[q];
// exits with X[rev6(l) + 64*q].
__device__ __forceinline__ void fft320p(v2f z[5], int lane, const Tw& tw) {
  bfly<32>(z, lane, tw.c[0], tw.s[0]);
  bfly<16>(z, lane, tw.c[1], tw.s[1]);
  bfly<8>(z, lane, tw.c[2], tw.s[2]);
  bfly<4>(z, lane, tw.c[3], tw.s[3]);
  bfly<2>(z, lane, tw.c[4], tw.s[4]);
  bfly<1>(z, lane, tw.c[5], tw.s[5]);
  v2f t0 = z[0];
  v2f t1 = cmul(z[1], tw.c1, tw.s1);
  v2f t2 = cmul(z[2], tw.c2, tw.s2);
  v2f t3 = cmul(z[3], tw.c3, tw.s3);
  v2f t4 = cmul(z[4], tw.c4, tw.s4);
  const float C1 = 0.30901699437494742f, S1 = 0.95105651629515357f;
  const float C2 = -0.80901699437494742f, S2 = 0.58778525229247312f;
  v2f a1 = t1 + t4, b1 = t1 - t4;
  v2f a2 = t2 + t3, b2 = t2 - t3;
  z[0] = t0 + a1 + a2;
  v2f p = t0 + C1 * a1 + C2 * a2;
  v2f q_ = S1 * b1 + S2 * b2;
  v2f r = t0 + C2 * a1 + C1 * a2;
  v2f u = S2 * b1 - S1 * b2;
  v2f qi = {-q_.y, q_.x};
  v2f ui = {-u.y, u.x};
  z[1] = p + qi;
  z[4] = p - qi;
  z[2] = r + ui;
  z[3] = r - ui;
}

// Merged pre-pass: role-switched on blockIdx.x.
//  [0,6400)      mask [x][y][c][t] -> bit-packed mp[c][y][x] (float4-staged)
//  [6400,12800)  kspace [x][y][c] -> kT[c][y][x] float2
//  [12800,19200) smaps [x][y][c] -> sT[c][x][y] half2, pre-signed by (-1)^y
//  [19200,22400) flow [nx][ny][2][t] -> fs[t][nx][ny] float2
//  [22400,22600) zero out_f
__global__ __launch_bounds__(256) void prep_k(
    const float* __restrict__ mask, const float* __restrict__ kr,
    const float* __restrict__ ki, const float* __restrict__ sr,
    const float* __restrict__ si, const float* __restrict__ fl,
    unsigned int* __restrict__ mp, float2* __restrict__ kT,
    __half2* __restrict__ sT, float2* __restrict__ fs,
    float* __restrict__ out_f) {
  int bid = blockIdx.x, tid = threadIdx.x;
  if (bid < 6400) {
    int xt = bid % 20, y = bid / 20;
    __shared__ float4 mrow4[16][101];  // [xx][(c*25+t)/4]
    const float* mbase = mask + ((size_t)(xt * 16) * NX + y) * (NC * NT);
    for (int k = tid; k < 1600; k += 256) {
      int xx = k / 100, f4 = k % 100;
      const float4* p =
          (const float4*)(mbase + (size_t)xx * NX * (NC * NT));
      mrow4[xx][f4] = p[f4];
    }
    __shared__ unsigned int tileu[16][17];
    __syncthreads();
    int xx = tid >> 4, c = tid & 15;
    const float* row = (const float*)&mrow4[xx][0];
    unsigned int bits = 0;
#pragma unroll
    for (int t = 0; t < NT; ++t)
      bits |= (row[c * NT + t] != 0.f) ? (1u << t) : 0u;
    tileu[xx][c] = bits;
    __syncthreads();
    int c2 = tid >> 4, xx2 = tid & 15;
    mp[((size_t)(c2 * NX + y)) * NX + xt * 16 + xx2] = tileu[xx2][c2];
  } else if (bid < 12800) {
    int r = bid - 6400;
    int xt = r % 20, y = r / 20;
    int xx = tid >> 4, c = tid & 15;
    size_t si_ = (size_t)((xt * 16 + xx) * NX + y) * NC + c;
    __shared__ float2 tilef[16][17];
    tilef[xx][c] = make_float2(kr[si_], ki[si_]);
    __syncthreads();
    int c2 = tid >> 4, xx2 = tid & 15;
    kT[((size_t)(c2 * NX + y)) * NX + xt * 16 + xx2] = tilef[xx2][c2];
  } else if (bid < 19200) {
    int r = bid - 12800;
    int yt = r % 20, x = r / 20;
    int yy = tid >> 4, c = tid & 15;
    size_t si_ = (size_t)(x * NX + yt * 16 + yy) * NC + c;
    __shared__ float2 tiles[16][17];
    tiles[yy][c] = make_float2(sr[si_], si[si_]);
    __syncthreads();
    int c2 = tid >> 4, yy2 = tid & 15;
    float2 v = tiles[yy2][c2];
    float sg = (yy2 & 1) ? -1.f : 1.f;  // (-1)^ny pre-sign
    sT[((size_t)(c2 * NX + x)) * NX + yt * 16 + yy2] =
        __floats2half2_rn(v.x * sg, v.y * sg);
  } else if (bid < 22400) {
    int r = bid - 19200;
    int nyt = r % 10, nx = r / 10;
    __shared__ float buf[1600];
    size_t base = (size_t)(nx * NX + nyt * 32) * (2 * NT);
    for (int f = tid; f < 1600; f += 256) buf[f] = fl[base + f];
    __syncthreads();
    for (int f = tid; f < 1600; f += 256) {
      int t = f / 64;
      int k = f % 64;
      int nyl = k >> 1, d = k & 1;
      size_t di = ((size_t)(t * NX + nx) * NX + nyt * 32 + nyl) * 2 + d;
      ((float*)fs)[di] = buf[(nyl * 2 + d) * NT + t];
    }
  } else {
    int idx = (bid - 22400) * 256 + tid;  // 51200 float4
    ((float4*)out_f)[idx] = make_float4(0.f, 0.f, 0.f, 0.f);
  }
}

// Pass 1: x-axis IFFT for coil chunk [c0, c0+G). Writes tmp[cg][t][ky][nx]
// fp16, pre-signed by (-1)^nx * (-1)^ky.
__global__ __launch_bounds__(256) void pass1_k(
    const float2* __restrict__ kT, const unsigned int* __restrict__ mp,
    __half2* __restrict__ tmp, int c0) {
  int y = blockIdx.x, cg = blockIdx.y, c = c0 + cg;
  int tid = threadIdx.x, lane = tid & 63, w = tid >> 6;
  v2f v[5];
  unsigned int mb[5];
  size_t rowbase = ((size_t)c * NX + y) * NX;
#pragma unroll
  for (int q = 0; q < 5; ++q) {
    int x = 5 * lane + q;
    float2 kv = kT[rowbase + x];
    float sg = ((lane + q) & 1) ? -INV320 : INV320;  // (-1)^x / 320
    v[q].x = kv.x * sg;
    v[q].y = kv.y * sg;
    mb[q] = mp[rowbase + x];
  }
  Tw tw;
  make_tw(lane, tw);
  int r6 = rev6(lane);
  float osg = ((lane & 32) ? -1.f : 1.f) * ((y & 1) ? -1.f : 1.f);
  for (int t = w; t < NT; t += 4) {
    v2f z[5];
#pragma unroll
    for (int q = 0; q < 5; ++q) {
      float m = ((mb[q] >> t) & 1u) ? 1.f : 0.f;
      z[q] = v[q] * m;
    }
    fft320p(z, lane, tw);
    __half2* dst = tmp + ((size_t)(cg * NT + t) * NX + y) * NX;
#pragma unroll
    for (int k2 = 0; k2 < 5; ++k2)
      dst[r6 + 64 * k2] = __floats2half2_rn(z[k2].x * osg, z[k2].y * osg);
  }
}

// Pass 2: y-axis IFFT + conj(smaps) combine -> im_aux[t][nx][ny] fp16.
// 256 threads = 4 waves; block = (nx-tile of 4, t); wave j owns nx.
__global__ __launch_bounds__(256) void pass2_k(
    const __half2* __restrict__ tmp, const __half2* __restrict__ sT,
    __half2* __restrict__ im_aux, int c0, int G, int first) {
  int bx = blockIdx.x, t = blockIdx.y;
  int nxt_ = (bx >> 3) + 10 * (bx & 7);  // bijective on [0,80)
  int tid = threadIdx.x, lane = tid & 63, j = tid >> 6;
  int nx = nxt_ * 4 + j;
  int k1 = rev6(lane);
  Tw tw;
  make_tw(lane, tw);
  __shared__ __half2 tile[2][NX][5];  // 12.8 KB
  v2f acc[5] = {{0, 0}, {0, 0}, {0, 0}, {0, 0}, {0, 0}};

  int off[5], lw[5];
#pragma unroll
  for (int q = 0; q < 5; ++q) {
    int f = tid + q * 256;
    off[q] = (f >> 2) * NX + (f & 3);
    lw[q] = (f >> 2) * 5 + (f & 3);
  }
  const size_t pstride = (size_t)NT * NX * NX;
  const __half2* sbase = tmp + (size_t)t * NX * NX + nxt_ * 4;
  __half2* lds = &tile[0][0][0];

  __half2 nb[5];
#pragma unroll
  for (int q = 0; q < 5; ++q) nb[q] = sbase[off[q]];

  for (int cg = 0; cg < G; ++cg) {
    __half2 cb[5];
#pragma unroll
    for (int q = 0; q < 5; ++q) cb[q] = nb[q];
    if (cg + 1 < G) {
      const __half2* s = sbase + (size_t)(cg + 1) * pstride;
#pragma unroll
      for (int q = 0; q < 5; ++q) nb[q] = s[off[q]];  // in flight across iter
    }
    __half2* buf = lds + (cg & 1) * (NX * 5);
#pragma unroll
    for (int q = 0; q < 5; ++q) buf[lw[q]] = cb[q];
    const __half2* srow = sT + ((size_t)(c0 + cg) * NX + nx) * NX;
    __half2 smh[5];
#pragma unroll
    for (int k2 = 0; k2 < 5; ++k2) smh[k2] = srow[k1 + 64 * k2];
    __syncthreads();
    v2f z[5];
#pragma unroll
    for (int q = 0; q < 5; ++q) {
      float2 v = __half22float2(buf[(5 * lane + q) * 5 + j]);
      z[q].x = v.x;  // signs pre-folded in pass1
      z[q].y = v.y;
    }
    fft320p(z, lane, tw);
#pragma unroll
    for (int k2 = 0; k2 < 5; ++k2) {
      float2 sm = __half22float2(smh[k2]);
      v2f zc = {z[k2].y, -z[k2].x};  // conj-MAC helper
      acc[k2] += sm.x * z[k2] + sm.y * zc;
    }
  }
  __half2* dst = im_aux + ((size_t)t * NX + nx) * NX;
#pragma unroll
  for (int k2 = 0; k2 < 5; ++k2) {
    int ny = k1 + 64 * k2;
    v2f nv = acc[k2];  // (-1)^ny folded into sT
    if (!first) {
      float2 old = __half22float2(dst[ny]);
      nv.x += old.x;
      nv.y += old.y;
    }
    dst[ny] = __floats2half2_rn(nv.x, nv.y);
  }
}

// Scatter: block (band b, seg, frame t). LDS-privatized 32-row band of
// __half2 (re,im) cells; taps via ds_pk_add_f16 (4 lane-atomics/element).
__global__ __launch_bounds__(1024) void scatter_k(
    const __half2* __restrict__ im, const float2* __restrict__ fs,
    __half2* __restrict__ out_p, float* __restrict__ out_f, int nseg) {
  int b = blockIdx.x, seg = blockIdx.y, t = blockIdx.z;
  int r0 = b * BR;
  int tid = threadIdx.x, lane = tid & 63, w = tid >> 6;
  __shared__ __half2 acc[BR * NX];  // 40 KB
  const __half2 h2z = __floats2half2_rn(0.f, 0.f);
  for (int i = tid; i < BR * NX; i += 1024) acc[i] = h2z;
  __syncthreads();
  int lo = max(r0 - WH, 0), hi = min(r0 + BR + WH, NX);
  int stride = 16 * nseg;
  for (int nx = lo + seg * 16 + w; nx < hi; nx += stride) {
    bool own = (nx >= r0) && (nx < r0 + BR);
    const __half2* imrow = im + ((size_t)t * NX + nx) * NX;
    const float2* frow = fs + ((size_t)t * NX + nx) * NX;
#pragma unroll
    for (int q = 0; q < 5; ++q) {
      int ny = lane + 64 * q;
      float2 v = __half22float2(imrow[ny]);
      float2 fl = frow[ny];
      float px = fminf(fmaxf((float)nx + fl.x, 0.f), 319.f);
      float py = fminf(fmaxf((float)ny + fl.y, 0.f), 319.f);
      int x0 = (int)floorf(px), y0 = (int)floorf(py);
      int x1 = min(x0 + 1, NX - 1), y1 = min(y0 + 1, NX - 1);
      float wx = px - (float)x0, wy = py - (float)y0;
      float w00 = (1.f - wx) * (1.f - wy), w01 = (1.f - wx) * wy;
      float w10 = wx * (1.f - wy), w11 = wx * wy;
#pragma unroll
      for (int half = 0; half < 2; ++half) {
        int r = half ? x1 : x0;
        float wa = half ? w10 : w00;
        float wb = half ? w11 : w01;
        if (r >= r0 && r < r0 + BR) {
          unsafeAtomicAdd(&acc[(r - r0) * NX + y0],
                          __floats2half2_rn(wa * v.x, wa * v.y));
          unsafeAtomicAdd(&acc[(r - r0) * NX + y1],
                          __floats2half2_rn(wb * v.x, wb * v.y));
        } else if (own) {
          int rb = (r / BR) * BR;
          if (nx < rb - WH || nx >= rb + BR + WH) {  // no band reads nx
            unsafeAtomicAdd(&out_f[((size_t)r * NX + y0) * 2], wa * v.x);
            unsafeAtomicAdd(&out_f[((size_t)r * NX + y0) * 2 + 1], wa * v.y);
            unsafeAtomicAdd(&out_f[((size_t)r * NX + y1) * 2], wb * v.x);
            unsafeAtomicAdd(&out_f[((size_t)r * NX + y1) * 2 + 1], wb * v.y);
          }
        }
      }
    }
  }
  __syncthreads();
  __half2* dst = out_p + (size_t)(seg * NT + t) * NX * NX + (size_t)r0 * NX;
  for (int i = tid; i < BR * NX; i += 1024) dst[i] = acc[i];
}

// out = out_f + sum_{seg,t} out_p (half2 slices)
__global__ __launch_bounds__(256) void reduce_k(
    const __half2* __restrict__ out_p, const float* __restrict__ out_f,
    float* __restrict__ out, int nslice) {
  const int n = NX * NX;  // 102400 cells
  int i = blockIdx.x * 256 + threadIdx.x;
  if (i >= n) return;
  float2 s = ((const float2*)out_f)[i];
  for (int k = 0; k < nslice; ++k) {
    float2 v = __half22float2(out_p[(size_t)k * n + i]);
    s.x += v.x;
    s.y += v.y;
  }
  ((float2*)out)[i] = s;
}

extern "C" void kernel_launch(void* const* d_in, const int* in_sizes, int n_in,
                              void* d_out, int out_size, void* d_ws,
                              size_t ws_size, hipStream_t stream) {
  const float* kr = (const float*)d_in[0];
  const float* ki = (const float*)d_in[1];
  const float* mask = (const float*)d_in[2];
  const float* sr = (const float*)d_in[3];
  const float* si = (const float*)d_in[4];
  const float* fl = (const float*)d_in[5];
  float* out = (float*)d_out;

  const size_t tmp1 = (size_t)NT * NX * NX * 4;      // fp16 complex, per coil
  const size_t kT_b = (size_t)NC * NX * NX * 8;
  const size_t sT_b = (size_t)NC * NX * NX * 4;      // half2
  const size_t fs_b = (size_t)NT * NX * NX * 8;
  const size_t mp_b = (size_t)NC * NX * NX * 4;
  const size_t ia_b = (size_t)NT * NX * NX * 4;      // half2
  const size_t of_b = (size_t)NX * NX * 8;
  const size_t op1 = (size_t)NT * NX * NX * 4;       // half2, per segment

  int NSEG = 2, G = 16;
  for (;;) {
    size_t fixed = kT_b + sT_b + fs_b + mp_b + ia_b + of_b + NSEG * op1;
    if (ws_size >= fixed + (size_t)G * tmp1) break;
    if (G > 1) { G >>= 1; continue; }
    if (NSEG > 1) { NSEG >>= 1; G = 16; continue; }
    break;  // minimal config; assume it fits
  }

  char* w = (char*)d_ws;
  __half2* tmp = (__half2*)w;    w += (size_t)G * tmp1;
  float2* kT = (float2*)w;       w += kT_b;
  __half2* sT = (__half2*)w;     w += sT_b;
  float2* fs = (float2*)w;       w += fs_b;
  __half2* im_aux = (__half2*)w; w += ia_b;
  __half2* out_p = (__half2*)w;  w += (size_t)NSEG * op1;
  float* out_f = (float*)w;      w += of_b;
  unsigned int* mp = (unsigned int*)w;

  prep_k<<<22600, 256, 0, stream>>>(mask, kr, ki, sr, si, fl, mp, kT, sT, fs,
                                    out_f);

  for (int c0 = 0; c0 < NC; c0 += G) {
    pass1_k<<<dim3(NX, G), 256, 0, stream>>>(kT, mp, tmp, c0);
    pass2_k<<<dim3(80, NT), 256, 0, stream>>>(tmp, sT, im_aux, c0, G,
                                              c0 == 0 ? 1 : 0);
  }
  scatter_k<<<dim3(NX / BR, NSEG, NT), 1024, 0, stream>>>(im_aux, fs, out_p,
                                                          out_f, NSEG);
  reduce_k<<<400, 256, 0, stream>>>(out_p, out_f, out, NSEG * NT);
}

// Round 11
// 297.187 us; speedup vs baseline: 1.4436x; 1.1011x over previous
//
#include <hip/hip_runtime.h>
#include <hip/hip_fp16.h>

// MRI adjoint: masked centered 2D IFFT per (coil,frame) -> conj(smaps) combine
// -> bilinear warp-adjoint scatter -> sum over frames. Nx=Ny=320, Nc=16, Nt=25.
//
// FFT: 320 = 5*64; one wave per transform. Round-11 butterfly: selection-free
// form z = cmul(o + sgn*z, w) with lane-resident sgn/twiddles (top lanes get
// w=(1,0)) -- 3 VALU/point vs 6. Stage m=1's twiddle is identically 1, so the
// radix-5 twiddles W320^(k1 q) are folded there (deletes 4 cmuls + old stage).
// Cross-lane via immediate ds_swizzle (m<=16) / shfl_xor (m=32).
// Centered-transform signs folded into pass1 output & pre-signed smaps.
// tmp fp16 half2 [c][t][ky][nx]; smaps/im_aux fp16.
// Scatter: LDS __half2 accumulator, ds_pk_add_f16 taps (LDS atomics are
// ~lane-serialized; halving lane-atomics was round-10's win). Spills to out_f.

#define NX 320
#define NT 25
#define NC 16
#define BR 32
#define WH 16
static const float INV320 = 1.0f / 320.0f;

typedef float v2f __attribute__((ext_vector_type(2)));

__device__ __forceinline__ int rev6(int l) {
  return ((l & 1) << 5) | ((l & 2) << 3) | ((l & 4) << 1) |
         ((l & 8) >> 1) | ((l & 16) >> 3) | ((l & 32) >> 5);
}

// Lane-resident twiddle state (computed once per thread).
// Stages st=0..4 (m=32,16,8,4,2): sg = bot?-1:+1, (cst,sst) = bot?(c,s):(1,0).
// Stage m=1: sg5 = bot?-1:+1; twiddle = W320^(k1*q) for all lanes (c5,s5).
struct Tw {
  float cst[5], sst[5], sg[5];
  float sg5;
  float c5[5], s5[5];
};

__device__ __forceinline__ void make_tw(int lane, Tw& tw) {
#pragma unroll
  for (int st = 0; st < 5; ++st) {
    int m = 32 >> st;
    bool bot = (lane & m) != 0;
    int j = lane & (m - 1);
    float ang = 3.14159265358979323846f * (float)j / (float)m;
    float s, c;
    __sincosf(ang, &s, &c);
    tw.sg[st] = bot ? -1.f : 1.f;
    tw.cst[st] = bot ? c : 1.f;
    tw.sst[st] = bot ? s : 0.f;
  }
  tw.sg5 = (lane & 1) ? -1.f : 1.f;
  int k1 = rev6(lane);
  float b = (6.283185307179586f / 320.0f) * (float)k1;
  float s1, c1;
  __sincosf(b, &s1, &c1);
  tw.c5[0] = 1.f;
  tw.s5[0] = 0.f;
  tw.c5[1] = c1;
  tw.s5[1] = s1;
  tw.c5[2] = c1 * c1 - s1 * s1;
  tw.s5[2] = 2.f * c1 * s1;
  tw.c5[3] = tw.c5[2] * c1 - tw.s5[2] * s1;
  tw.s5[3] = tw.c5[2] * s1 + tw.s5[2] * c1;
  tw.c5[4] = tw.c5[2] * tw.c5[2] - tw.s5[2] * tw.s5[2];
  tw.s5[4] = 2.f * tw.c5[2] * tw.s5[2];
}

template <int M>
__device__ __forceinline__ float lxor(float x) {
  if constexpr (M == 32) {
    return __shfl_xor(x, 32);
  } else {
    constexpr int pat = (M << 10) | 0x1F;  // BitMode: xor=M, and=0x1F
    return __int_as_float(__builtin_amdgcn_ds_swizzle(__float_as_int(x), pat));
  }
}

// (z.x + i z.y) * (c + i s)
__device__ __forceinline__ v2f cmul(v2f z, float c, float s) {
  v2f sw = {-z.y, z.x};
  return c * z + s * sw;
}

template <int M>
__device__ __forceinline__ void bstage(v2f z[5], float sg, float c, float s) {
#pragma unroll
  for (int q = 0; q < 5; ++q) {
    v2f o;
    o.x = lxor<M>(z[q].x);
    o.y = lxor<M>(z[q].y);
    v2f t = o + sg * z[q];
    z[q] = cmul(t, c, s);  // top lanes: (c,s)=(1,0) -> identity
  }
}

// Unnormalized inverse 320-pt DFT: lane l enters with x[5l+q] in z[q];
// exits with X[rev6(l) + 64*q].
__device__ __forceinline__ void fft320p(v2f z[5], const Tw& tw) {
  bstage<32>(z, tw.sg[0], tw.cst[0], tw.sst[0]);
  bstage<16>(z, tw.sg[1], tw.cst[1], tw.sst[1]);
  bstage<8>(z, tw.sg[2], tw.cst[2], tw.sst[2]);
  bstage<4>(z, tw.sg[3], tw.cst[3], tw.sst[3]);
  bstage<2>(z, tw.sg[4], tw.cst[4], tw.sst[4]);
  // stage m=1 with folded radix-5 twiddles (stage twiddle == 1 identically)
  {
    v2f o;
    o.x = lxor<1>(z[0].x);
    o.y = lxor<1>(z[0].y);
    z[0] = o + tw.sg5 * z[0];  // c5[0]=1: no cmul
#pragma unroll
    for (int q = 1; q < 5; ++q) {
      o.x = lxor<1>(z[q].x);
      o.y = lxor<1>(z[q].y);
      v2f t = o + tw.sg5 * z[q];
      z[q] = cmul(t, tw.c5[q], tw.s5[q]);
    }
  }
  v2f t0 = z[0], t1 = z[1], t2 = z[2], t3 = z[3], t4 = z[4];
  const float C1 = 0.30901699437494742f, S1 = 0.95105651629515357f;
  const float C2 = -0.80901699437494742f, S2 = 0.58778525229247312f;
  v2f a1 = t1 + t4, b1 = t1 - t4;
  v2f a2 = t2 + t3, b2 = t2 - t3;
  z[0] = t0 + a1 + a2;
  v2f p = t0 + C1 * a1 + C2 * a2;
  v2f q_ = S1 * b1 + S2 * b2;
  v2f r = t0 + C2 * a1 + C1 * a2;
  v2f u = S2 * b1 - S1 * b2;
  v2f qi = {-q_.y, q_.x};
  v2f ui = {-u.y, u.x};
  z[1] = p + qi;
  z[4] = p - qi;
  z[2] = r + ui;
  z[3] = r - ui;
}

// Merged pre-pass: role-switched on blockIdx.x.
//  [0,6400)      mask [x][y][c][t] -> bit-packed mp[c][y][x] (float4-staged)
//  [6400,12800)  kspace [x][y][c] -> kT[c][y][x] float2
//  [12800,19200) smaps [x][y][c] -> sT[c][x][y] half2, pre-signed by (-1)^y
//  [19200,22400) flow [nx][ny][2][t] -> fs[t][nx][ny] float2
//  [22400,22600) zero out_f
__global__ __launch_bounds__(256) void prep_k(
    const float* __restrict__ mask, const float* __restrict__ kr,
    const float* __restrict__ ki, const float* __restrict__ sr,
    const float* __restrict__ si, const float* __restrict__ fl,
    unsigned int* __restrict__ mp, float2* __restrict__ kT,
    __half2* __restrict__ sT, float2* __restrict__ fs,
    float* __restrict__ out_f) {
  int bid = blockIdx.x, tid = threadIdx.x;
  if (bid < 6400) {
    int xt = bid % 20, y = bid / 20;
    __shared__ float4 mrow4[16][101];  // [xx][(c*25+t)/4]
    const float* mbase = mask + ((size_t)(xt * 16) * NX + y) * (NC * NT);
    for (int k = tid; k < 1600; k += 256) {
      int xx = k / 100, f4 = k % 100;
      const float4* p =
          (const float4*)(mbase + (size_t)xx * NX * (NC * NT));
      mrow4[xx][f4] = p[f4];
    }
    __shared__ unsigned int tileu[16][17];
    __syncthreads();
    int xx = tid >> 4, c = tid & 15;
    const float* row = (const float*)&mrow4[xx][0];
    unsigned int bits = 0;
#pragma unroll
    for (int t = 0; t < NT; ++t)
      bits |= (row[c * NT + t] != 0.f) ? (1u << t) : 0u;
    tileu[xx][c] = bits;
    __syncthreads();
    int c2 = tid >> 4, xx2 = tid & 15;
    mp[((size_t)(c2 * NX + y)) * NX + xt * 16 + xx2] = tileu[xx2][c2];
  } else if (bid < 12800) {
    int r = bid - 6400;
    int xt = r % 20, y = r / 20;
    int xx = tid >> 4, c = tid & 15;
    size_t si_ = (size_t)((xt * 16 + xx) * NX + y) * NC + c;
    __shared__ float2 tilef[16][17];
    tilef[xx][c] = make_float2(kr[si_], ki[si_]);
    __syncthreads();
    int c2 = tid >> 4, xx2 = tid & 15;
    kT[((size_t)(c2 * NX + y)) * NX + xt * 16 + xx2] = tilef[xx2][c2];
  } else if (bid < 19200) {
    int r = bid - 12800;
    int yt = r % 20, x = r / 20;
    int yy = tid >> 4, c = tid & 15;
    size_t si_ = (size_t)(x * NX + yt * 16 + yy) * NC + c;
    __shared__ float2 tiles[16][17];
    tiles[yy][c] = make_float2(sr[si_], si[si_]);
    __syncthreads();
    int c2 = tid >> 4, yy2 = tid & 15;
    float2 v = tiles[yy2][c2];
    float sg = (yy2 & 1) ? -1.f : 1.f;  // (-1)^ny pre-sign
    sT[((size_t)(c2 * NX + x)) * NX + yt * 16 + yy2] =
        __floats2half2_rn(v.x * sg, v.y * sg);
  } else if (bid < 22400) {
    int r = bid - 19200;
    int nyt = r % 10, nx = r / 10;
    __shared__ float buf[1600];
    size_t base = (size_t)(nx * NX + nyt * 32) * (2 * NT);
    for (int f = tid; f < 1600; f += 256) buf[f] = fl[base + f];
    __syncthreads();
    for (int f = tid; f < 1600; f += 256) {
      int t = f / 64;
      int k = f % 64;
      int nyl = k >> 1, d = k & 1;
      size_t di = ((size_t)(t * NX + nx) * NX + nyt * 32 + nyl) * 2 + d;
      ((float*)fs)[di] = buf[(nyl * 2 + d) * NT + t];
    }
  } else {
    int idx = (bid - 22400) * 256 + tid;  // 51200 float4
    ((float4*)out_f)[idx] = make_float4(0.f, 0.f, 0.f, 0.f);
  }
}

// Pass 1: x-axis IFFT for coil chunk [c0, c0+G). Writes tmp[cg][t][ky][nx]
// fp16, pre-signed by (-1)^nx * (-1)^ky.
__global__ __launch_bounds__(256) void pass1_k(
    const float2* __restrict__ kT, const unsigned int* __restrict__ mp,
    __half2* __restrict__ tmp, int c0) {
  int y = blockIdx.x, cg = blockIdx.y, c = c0 + cg;
  int tid = threadIdx.x, lane = tid & 63, w = tid >> 6;
  v2f v[5];
  unsigned int mb[5];
  size_t rowbase = ((size_t)c * NX + y) * NX;
#pragma unroll
  for (int q = 0; q < 5; ++q) {
    int x = 5 * lane + q;
    float2 kv = kT[rowbase + x];
    float sg = ((lane + q) & 1) ? -INV320 : INV320;  // (-1)^x / 320
    v[q].x = kv.x * sg;
    v[q].y = kv.y * sg;
    mb[q] = mp[rowbase + x];
  }
  Tw tw;
  make_tw(lane, tw);
  int r6 = rev6(lane);
  float osg = ((lane & 32) ? -1.f : 1.f) * ((y & 1) ? -1.f : 1.f);
  for (int t = w; t < NT; t += 4) {
    v2f z[5];
#pragma unroll
    for (int q = 0; q < 5; ++q) {
      float m = ((mb[q] >> t) & 1u) ? 1.f : 0.f;
      z[q] = v[q] * m;
    }
    fft320p(z, tw);
    __half2* dst = tmp + ((size_t)(cg * NT + t) * NX + y) * NX;
#pragma unroll
    for (int k2 = 0; k2 < 5; ++k2)
      dst[r6 + 64 * k2] = __floats2half2_rn(z[k2].x * osg, z[k2].y * osg);
  }
}

// Pass 2: y-axis IFFT + conj(smaps) combine -> im_aux[t][nx][ny] fp16.
// 256 threads = 4 waves; block = (nx-tile of 4, t); wave j owns nx.
__global__ __launch_bounds__(256) void pass2_k(
    const __half2* __restrict__ tmp, const __half2* __restrict__ sT,
    __half2* __restrict__ im_aux, int c0, int G, int first) {
  int bx = blockIdx.x, t = blockIdx.y;
  int nxt_ = (bx >> 3) + 10 * (bx & 7);  // bijective on [0,80)
  int tid = threadIdx.x, lane = tid & 63, j = tid >> 6;
  int nx = nxt_ * 4 + j;
  int k1 = rev6(lane);
  Tw tw;
  make_tw(lane, tw);
  __shared__ __half2 tile[2][NX][5];  // 12.8 KB
  v2f acc[5] = {{0, 0}, {0, 0}, {0, 0}, {0, 0}, {0, 0}};

  int off[5], lw[5];
#pragma unroll
  for (int q = 0; q < 5; ++q) {
    int f = tid + q * 256;
    off[q] = (f >> 2) * NX + (f & 3);
    lw[q] = (f >> 2) * 5 + (f & 3);
  }
  const size_t pstride = (size_t)NT * NX * NX;
  const __half2* sbase = tmp + (size_t)t * NX * NX + nxt_ * 4;
  __half2* lds = &tile[0][0][0];

  __half2 nb[5];
#pragma unroll
  for (int q = 0; q < 5; ++q) nb[q] = sbase[off[q]];

  for (int cg = 0; cg < G; ++cg) {
    __half2 cb[5];
#pragma unroll
    for (int q = 0; q < 5; ++q) cb[q] = nb[q];
    if (cg + 1 < G) {
      const __half2* s = sbase + (size_t)(cg + 1) * pstride;
#pragma unroll
      for (int q = 0; q < 5; ++q) nb[q] = s[off[q]];  // in flight across iter
    }
    __half2* buf = lds + (cg & 1) * (NX * 5);
#pragma unroll
    for (int q = 0; q < 5; ++q) buf[lw[q]] = cb[q];
    const __half2* srow = sT + ((size_t)(c0 + cg) * NX + nx) * NX;
    __half2 smh[5];
#pragma unroll
    for (int k2 = 0; k2 < 5; ++k2) smh[k2] = srow[k1 + 64 * k2];
    __syncthreads();
    v2f z[5];
#pragma unroll
    for (int q = 0; q < 5; ++q) {
      float2 v = __half22float2(buf[(5 * lane + q) * 5 + j]);
      z[q].x = v.x;  // signs pre-folded in pass1
      z[q].y = v.y;
    }
    fft320p(z, tw);
#pragma unroll
    for (int k2 = 0; k2 < 5; ++k2) {
      float2 sm = __half22float2(smh[k2]);
      v2f zc = {z[k2].y, -z[k2].x};  // conj-MAC helper
      acc[k2] += sm.x * z[k2] + sm.y * zc;
    }
  }
  __half2* dst = im_aux + ((size_t)t * NX + nx) * NX;
#pragma unroll
  for (int k2 = 0; k2 < 5; ++k2) {
    int ny = k1 + 64 * k2;
    v2f nv = acc[k2];  // (-1)^ny folded into sT
    if (!first) {
      float2 old = __half22float2(dst[ny]);
      nv.x += old.x;
      nv.y += old.y;
    }
    dst[ny] = __floats2half2_rn(nv.x, nv.y);
  }
}

// Scatter: block (band b, seg, frame t). LDS-privatized 32-row band of
// __half2 (re,im) cells; taps via ds_pk_add_f16 (4 lane-atomics/element).
__global__ __launch_bounds__(1024) void scatter_k(
    const __half2* __restrict__ im, const float2* __restrict__ fs,
    __half2* __restrict__ out_p, float* __restrict__ out_f, int nseg) {
  int b = blockIdx.x, seg = blockIdx.y, t = blockIdx.z;
  int r0 = b * BR;
  int tid = threadIdx.x, lane = tid & 63, w = tid >> 6;
  __shared__ __half2 acc[BR * NX];  // 40 KB
  const __half2 h2z = __floats2half2_rn(0.f, 0.f);
  for (int i = tid; i < BR * NX; i += 1024) acc[i] = h2z;
  __syncthreads();
  int lo = max(r0 - WH, 0), hi = min(r0 + BR + WH, NX);
  int stride = 16 * nseg;
  for (int nx = lo + seg * 16 + w; nx < hi; nx += stride) {
    bool own = (nx >= r0) && (nx < r0 + BR);
    const __half2* imrow = im + ((size_t)t * NX + nx) * NX;
    const float2* frow = fs + ((size_t)t * NX + nx) * NX;
#pragma unroll
    for (int q = 0; q < 5; ++q) {
      int ny = lane + 64 * q;
      float2 v = __half22float2(imrow[ny]);
      float2 fl = frow[ny];
      float px = fminf(fmaxf((float)nx + fl.x, 0.f), 319.f);
      float py = fminf(fmaxf((float)ny + fl.y, 0.f), 319.f);
      int x0 = (int)floorf(px), y0 = (int)floorf(py);
      int x1 = min(x0 + 1, NX - 1), y1 = min(y0 + 1, NX - 1);
      float wx = px - (float)x0, wy = py - (float)y0;
      float w00 = (1.f - wx) * (1.f - wy), w01 = (1.f - wx) * wy;
      float w10 = wx * (1.f - wy), w11 = wx * wy;
#pragma unroll
      for (int half = 0; half < 2; ++half) {
        int r = half ? x1 : x0;
        float wa = half ? w10 : w00;
        float wb = half ? w11 : w01;
        if (r >= r0 && r < r0 + BR) {
          unsafeAtomicAdd(&acc[(r - r0) * NX + y0],
                          __floats2half2_rn(wa * v.x, wa * v.y));
          unsafeAtomicAdd(&acc[(r - r0) * NX + y1],
                          __floats2half2_rn(wb * v.x, wb * v.y));
        } else if (own) {
          int rb = (r / BR) * BR;
          if (nx < rb - WH || nx >= rb + BR + WH) {  // no band reads nx
            unsafeAtomicAdd(&out_f[((size_t)r * NX + y0) * 2], wa * v.x);
            unsafeAtomicAdd(&out_f[((size_t)r * NX + y0) * 2 + 1], wa * v.y);
            unsafeAtomicAdd(&out_f[((size_t)r * NX + y1) * 2], wb * v.x);
            unsafeAtomicAdd(&out_f[((size_t)r * NX + y1) * 2 + 1], wb * v.y);
          }
        }
      }
    }
  }
  __syncthreads();
  __half2* dst = out_p + (size_t)(seg * NT + t) * NX * NX + (size_t)r0 * NX;
  for (int i = tid; i < BR * NX; i += 1024) dst[i] = acc[i];
}

// out = out_f + sum_{seg,t} out_p (half2 slices)
__global__ __launch_bounds__(256) void reduce_k(
    const __half2* __restrict__ out_p, const float* __restrict__ out_f,
    float* __restrict__ out, int nslice) {
  const int n = NX * NX;  // 102400 cells
  int i = blockIdx.x * 256 + threadIdx.x;
  if (i >= n) return;
  float2 s = ((const float2*)out_f)[i];
  for (int k = 0; k < nslice; ++k) {
    float2 v = __half22float2(out_p[(size_t)k * n + i]);
    s.x += v.x;
    s.y += v.y;
  }
  ((float2*)out)[i] = s;
}

extern "C" void kernel_launch(void* const* d_in, const int* in_sizes, int n_in,
                              void* d_out, int out_size, void* d_ws,
                              size_t ws_size, hipStream_t stream) {
  const float* kr = (const float*)d_in[0];
  const float* ki = (const float*)d_in[1];
  const float* mask = (const float*)d_in[2];
  const float* sr = (const float*)d_in[3];
  const float* si = (const float*)d_in[4];
  const float* fl = (const float*)d_in[5];
  float* out = (float*)d_out;

  const size_t tmp1 = (size_t)NT * NX * NX * 4;      // fp16 complex, per coil
  const size_t kT_b = (size_t)NC * NX * NX * 8;
  const size_t sT_b = (size_t)NC * NX * NX * 4;      // half2
  const size_t fs_b = (size_t)NT * NX * NX * 8;
  const size_t mp_b = (size_t)NC * NX * NX * 4;
  const size_t ia_b = (size_t)NT * NX * NX * 4;      // half2
  const size_t of_b = (size_t)NX * NX * 8;
  const size_t op1 = (size_t)NT * NX * NX * 4;       // half2, per segment

  int NSEG = 2, G = 16;
  for (;;) {
    size_t fixed = kT_b + sT_b + fs_b + mp_b + ia_b + of_b + NSEG * op1;
    if (ws_size >= fixed + (size_t)G * tmp1) break;
    if (G > 1) { G >>= 1; continue; }
    if (NSEG > 1) { NSEG >>= 1; G = 16; continue; }
    break;  // minimal config; assume it fits
  }

  char* w = (char*)d_ws;
  __half2* tmp = (__half2*)w;    w += (size_t)G * tmp1;
  float2* kT = (float2*)w;       w += kT_b;
  __half2* sT = (__half2*)w;     w += sT_b;
  float2* fs = (float2*)w;       w += fs_b;
  __half2* im_aux = (__half2*)w; w += ia_b;
  __half2* out_p = (__half2*)w;  w += (size_t)NSEG * op1;
  float* out_f = (float*)w;      w += of_b;
  unsigned int* mp = (unsigned int*)w;

  prep_k<<<22600, 256, 0, stream>>>(mask, kr, ki, sr, si, fl, mp, kT, sT, fs,
                                    out_f);

  for (int c0 = 0; c0 < NC; c0 += G) {
    pass1_k<<<dim3(NX, G), 256, 0, stream>>>(kT, mp, tmp, c0);
    pass2_k<<<dim3(80, NT), 256, 0, stream>>>(tmp, sT, im_aux, c0, G,
                                              c0 == 0 ? 1 : 0);
  }
  scatter_k<<<dim3(NX / BR, NSEG, NT), 1024, 0, stream>>>(im_aux, fs, out_p,
                                                          out_f, NSEG);
  reduce_k<<<400, 256, 0, stream>>>(out_p, out_f, out, NSEG * NT);
}

// Round 12
// 281.561 us; speedup vs baseline: 1.5237x; 1.0555x over previous
//
#include <hip/hip_runtime.h>
#include <hip/hip_fp16.h>

// MRI adjoint: masked centered 2D IFFT per (coil,frame) -> conj(smaps) combine
// -> bilinear warp-adjoint scatter -> sum over frames. Nx=Ny=320, Nc=16, Nt=25.
//
// FFT: 320 = 5*64; one wave per transform. Selection-free butterfly
// z = cmul(o + sgn*z, w) with lane-resident twiddles; radix-5 twiddles folded
// into the (identity-twiddle) m=1 stage. ds_swizzle (m<=16) / shfl_xor (m=32).
// Centered-transform signs folded into pass1 output & pre-signed smaps.
// tmp fp16 half2 [c][t][ky][nx]; smaps/im_aux fp16.
// prep (round-12): all phases overlay ONE 7.5KB LDS buffer (round-11 had the
// per-phase __shared__ arrays SUMMED to 37.9KB -> 4 blocks/CU -> latency-bound
// at 1.5TB/s). Mask phase packs per-wave (1.6KB strips, no block barrier on
// the load path). Scatter: LDS __half2 accumulator + ds_pk_add_f16 taps.

#define NX 320
#define NT 25
#define NC 16
#define BR 32
#define WH 16
static const float INV320 = 1.0f / 320.0f;

typedef float v2f __attribute__((ext_vector_type(2)));

__device__ __forceinline__ int rev6(int l) {
  return ((l & 1) << 5) | ((l & 2) << 3) | ((l & 4) << 1) |
         ((l & 8) >> 1) | ((l & 16) >> 3) | ((l & 32) >> 5);
}

// Lane-resident twiddle state. Stages st=0..4 (m=32..2): sg=bot?-1:+1,
// (cst,sst)=bot?(c,s):(1,0). Stage m=1: sg5 plus folded radix-5 twiddles.
struct Tw {
  float cst[5], sst[5], sg[5];
  float sg5;
  float c5[5], s5[5];
};

__device__ __forceinline__ void make_tw(int lane, Tw& tw) {
#pragma unroll
  for (int st = 0; st < 5; ++st) {
    int m = 32 >> st;
    bool bot = (lane & m) != 0;
    int j = lane & (m - 1);
    float ang = 3.14159265358979323846f * (float)j / (float)m;
    float s, c;
    __sincosf(ang, &s, &c);
    tw.sg[st] = bot ? -1.f : 1.f;
    tw.cst[st] = bot ? c : 1.f;
    tw.sst[st] = bot ? s : 0.f;
  }
  tw.sg5 = (lane & 1) ? -1.f : 1.f;
  int k1 = rev6(lane);
  float b = (6.283185307179586f / 320.0f) * (float)k1;
  float s1, c1;
  __sincosf(b, &s1, &c1);
  tw.c5[0] = 1.f;
  tw.s5[0] = 0.f;
  tw.c5[1] = c1;
  tw.s5[1] = s1;
  tw.c5[2] = c1 * c1 - s1 * s1;
  tw.s5[2] = 2.f * c1 * s1;
  tw.c5[3] = tw.c5[2] * c1 - tw.s5[2] * s1;
  tw.s5[3] = tw.c5[2] * s1 + tw.s5[2] * c1;
  tw.c5[4] = tw.c5[2] * tw.c5[2] - tw.s5[2] * tw.s5[2];
  tw.s5[4] = 2.f * tw.c5[2] * tw.s5[2];
}

template <int M>
__device__ __forceinline__ float lxor(float x) {
  if constexpr (M == 32) {
    return __shfl_xor(x, 32);
  } else {
    constexpr int pat = (M << 10) | 0x1F;  // BitMode: xor=M, and=0x1F
    return __int_as_float(__builtin_amdgcn_ds_swizzle(__float_as_int(x), pat));
  }
}

// (z.x + i z.y) * (c + i s)
__device__ __forceinline__ v2f cmul(v2f z, float c, float s) {
  v2f sw = {-z.y, z.x};
  return c * z + s * sw;
}

template <int M>
__device__ __forceinline__ void bstage(v2f z[5], float sg, float c, float s) {
#pragma unroll
  for (int q = 0; q < 5; ++q) {
    v2f o;
    o.x = lxor<M>(z[q].x);
    o.y = lxor<M>(z[q].y);
    v2f t = o + sg * z[q];
    z[q] = cmul(t, c, s);  // top lanes: (c,s)=(1,0) -> identity
  }
}

// Unnormalized inverse 320-pt DFT: lane l enters with x[5l+q] in z[q];
// exits with X[rev6(l) + 64*q].
__device__ __forceinline__ void fft320p(v2f z[5], const Tw& tw) {
  bstage<32>(z, tw.sg[0], tw.cst[0], tw.sst[0]);
  bstage<16>(z, tw.sg[1], tw.cst[1], tw.sst[1]);
  bstage<8>(z, tw.sg[2], tw.cst[2], tw.sst[2]);
  bstage<4>(z, tw.sg[3], tw.cst[3], tw.sst[3]);
  bstage<2>(z, tw.sg[4], tw.cst[4], tw.sst[4]);
  {
    v2f o;
    o.x = lxor<1>(z[0].x);
    o.y = lxor<1>(z[0].y);
    z[0] = o + tw.sg5 * z[0];  // c5[0]=1: no cmul
#pragma unroll
    for (int q = 1; q < 5; ++q) {
      o.x = lxor<1>(z[q].x);
      o.y = lxor<1>(z[q].y);
      v2f t = o + tw.sg5 * z[q];
      z[q] = cmul(t, tw.c5[q], tw.s5[q]);
    }
  }
  v2f t0 = z[0], t1 = z[1], t2 = z[2], t3 = z[3], t4 = z[4];
  const float C1 = 0.30901699437494742f, S1 = 0.95105651629515357f;
  const float C2 = -0.80901699437494742f, S2 = 0.58778525229247312f;
  v2f a1 = t1 + t4, b1 = t1 - t4;
  v2f a2 = t2 + t3, b2 = t2 - t3;
  z[0] = t0 + a1 + a2;
  v2f p = t0 + C1 * a1 + C2 * a2;
  v2f q_ = S1 * b1 + S2 * b2;
  v2f r = t0 + C2 * a1 + C1 * a2;
  v2f u = S2 * b1 - S1 * b2;
  v2f qi = {-q_.y, q_.x};
  v2f ui = {-u.y, u.x};
  z[1] = p + qi;
  z[4] = p - qi;
  z[2] = r + ui;
  z[3] = r - ui;
}

// Merged pre-pass: role-switched on blockIdx.x. ONE overlaid LDS buffer.
//  [0,6400)      mask [x][y][c][t] -> bit-packed mp[c][y][x] (per-wave strips)
//  [6400,12800)  kspace [x][y][c] -> kT[c][y][x] float2
//  [12800,19200) smaps [x][y][c] -> sT[c][x][y] half2, pre-signed by (-1)^y
//  [19200,22400) flow [nx][ny][2][t] -> fs[t][nx][ny] float2
//  [22400,22600) zero out_f
__global__ __launch_bounds__(256) void prep_k(
    const float* __restrict__ mask, const float* __restrict__ kr,
    const float* __restrict__ ki, const float* __restrict__ sr,
    const float* __restrict__ si, const float* __restrict__ fl,
    unsigned int* __restrict__ mp, float2* __restrict__ kT,
    __half2* __restrict__ sT, float2* __restrict__ fs,
    float* __restrict__ out_f) {
  __shared__ __align__(16) char shmem[7552];  // overlaid by all phases
  int bid = blockIdx.x, tid = threadIdx.x;
  if (bid < 6400) {
    int xt = bid % 20, y = bid / 20;
    int w = tid >> 6, lane = tid & 63;
    float* stage = (float*)shmem;                          // [4][400]
    unsigned int* tileu = (unsigned int*)(shmem + 6400);   // [16][17]
    float* mystrip = stage + w * 400;
#pragma unroll
    for (int k = 0; k < 4; ++k) {
      int xx = w * 4 + k;
      const float* src = mask + ((size_t)((xt * 16 + xx) * NX) + y) * (NC * NT);
#pragma unroll
      for (int i = 0; i < 7; ++i) {
        int f = lane + 64 * i;
        if (f < NC * NT) mystrip[f] = src[f];
      }
      if (lane < 16) {
        const float* row = mystrip + lane * NT;
        unsigned int bits = 0;
#pragma unroll
        for (int t = 0; t < NT; ++t) bits |= (row[t] != 0.f) ? (1u << t) : 0u;
        tileu[xx * 17 + lane] = bits;
      }
    }
    __syncthreads();
    int c2 = tid >> 4, xx2 = tid & 15;
    mp[((size_t)(c2 * NX + y)) * NX + xt * 16 + xx2] = tileu[xx2 * 17 + c2];
  } else if (bid < 12800) {
    int r = bid - 6400;
    int xt = r % 20, y = r / 20;
    int xx = tid >> 4, c = tid & 15;
    float2* tilef = (float2*)shmem;  // [16][17]
    size_t si_ = (size_t)((xt * 16 + xx) * NX + y) * NC + c;
    tilef[xx * 17 + c] = make_float2(kr[si_], ki[si_]);
    __syncthreads();
    int c2 = tid >> 4, xx2 = tid & 15;
    kT[((size_t)(c2 * NX + y)) * NX + xt * 16 + xx2] = tilef[xx2 * 17 + c2];
  } else if (bid < 19200) {
    int r = bid - 12800;
    int yt = r % 20, x = r / 20;
    int yy = tid >> 4, c = tid & 15;
    float2* tiles = (float2*)shmem;  // [16][17]
    size_t si_ = (size_t)(x * NX + yt * 16 + yy) * NC + c;
    tiles[yy * 17 + c] = make_float2(sr[si_], si[si_]);
    __syncthreads();
    int c2 = tid >> 4, yy2 = tid & 15;
    float2 v = tiles[yy2 * 17 + c2];
    float sg = (yy2 & 1) ? -1.f : 1.f;  // (-1)^ny pre-sign
    sT[((size_t)(c2 * NX + x)) * NX + yt * 16 + yy2] =
        __floats2half2_rn(v.x * sg, v.y * sg);
  } else if (bid < 22400) {
    int r = bid - 19200;
    int nyt = r % 10, nx = r / 10;
    float* buf = (float*)shmem;  // [1600]
    size_t base = (size_t)(nx * NX + nyt * 32) * (2 * NT);
    for (int f = tid; f < 1600; f += 256) buf[f] = fl[base + f];
    __syncthreads();
    for (int f = tid; f < 1600; f += 256) {
      int t = f / 64;
      int k = f % 64;
      int nyl = k >> 1, d = k & 1;
      size_t di = ((size_t)(t * NX + nx) * NX + nyt * 32 + nyl) * 2 + d;
      ((float*)fs)[di] = buf[(nyl * 2 + d) * NT + t];
    }
  } else {
    int idx = (bid - 22400) * 256 + tid;  // 51200 float4
    ((float4*)out_f)[idx] = make_float4(0.f, 0.f, 0.f, 0.f);
  }
}

// Pass 1: x-axis IFFT for coil chunk [c0, c0+G). Writes tmp[cg][t][ky][nx]
// fp16, pre-signed by (-1)^nx * (-1)^ky.
__global__ __launch_bounds__(256) void pass1_k(
    const float2* __restrict__ kT, const unsigned int* __restrict__ mp,
    __half2* __restrict__ tmp, int c0) {
  int y = blockIdx.x, cg = blockIdx.y, c = c0 + cg;
  int tid = threadIdx.x, lane = tid & 63, w = tid >> 6;
  v2f v[5];
  unsigned int mb[5];
  size_t rowbase = ((size_t)c * NX + y) * NX;
#pragma unroll
  for (int q = 0; q < 5; ++q) {
    int x = 5 * lane + q;
    float2 kv = kT[rowbase + x];
    float sg = ((lane + q) & 1) ? -INV320 : INV320;  // (-1)^x / 320
    v[q].x = kv.x * sg;
    v[q].y = kv.y * sg;
    mb[q] = mp[rowbase + x];
  }
  Tw tw;
  make_tw(lane, tw);
  int r6 = rev6(lane);
  float osg = ((lane & 32) ? -1.f : 1.f) * ((y & 1) ? -1.f : 1.f);
  for (int t = w; t < NT; t += 4) {
    v2f z[5];
#pragma unroll
    for (int q = 0; q < 5; ++q) {
      float m = ((mb[q] >> t) & 1u) ? 1.f : 0.f;
      z[q] = v[q] * m;
    }
    fft320p(z, tw);
    __half2* dst = tmp + ((size_t)(cg * NT + t) * NX + y) * NX;
#pragma unroll
    for (int k2 = 0; k2 < 5; ++k2)
      dst[r6 + 64 * k2] = __floats2half2_rn(z[k2].x * osg, z[k2].y * osg);
  }
}

// Pass 2: y-axis IFFT + conj(smaps) combine -> im_aux[t][nx][ny] fp16.
// 256 threads = 4 waves; block = (nx-tile of 4, t); wave j owns nx.
__global__ __launch_bounds__(256) void pass2_k(
    const __half2* __restrict__ tmp, const __half2* __restrict__ sT,
    __half2* __restrict__ im_aux, int c0, int G, int first) {
  int bx = blockIdx.x, t = blockIdx.y;
  int nxt_ = (bx >> 3) + 10 * (bx & 7);  // bijective on [0,80)
  int tid = threadIdx.x, lane = tid & 63, j = tid >> 6;
  int nx = nxt_ * 4 + j;
  int k1 = rev6(lane);
  Tw tw;
  make_tw(lane, tw);
  __shared__ __half2 tile[2][NX][5];  // 12.8 KB
  v2f acc[5] = {{0, 0}, {0, 0}, {0, 0}, {0, 0}, {0, 0}};

  int off[5], lw[5];
#pragma unroll
  for (int q = 0; q < 5; ++q) {
    int f = tid + q * 256;
    off[q] = (f >> 2) * NX + (f & 3);
    lw[q] = (f >> 2) * 5 + (f & 3);
  }
  const size_t pstride = (size_t)NT * NX * NX;
  const __half2* sbase = tmp + (size_t)t * NX * NX + nxt_ * 4;
  __half2* lds = &tile[0][0][0];

  __half2 nb[5];
#pragma unroll
  for (int q = 0; q < 5; ++q) nb[q] = sbase[off[q]];

  for (int cg = 0; cg < G; ++cg) {
    __half2 cb[5];
#pragma unroll
    for (int q = 0; q < 5; ++q) cb[q] = nb[q];
    if (cg + 1 < G) {
      const __half2* s = sbase + (size_t)(cg + 1) * pstride;
#pragma unroll
      for (int q = 0; q < 5; ++q) nb[q] = s[off[q]];  // in flight across iter
    }
    __half2* buf = lds + (cg & 1) * (NX * 5);
#pragma unroll
    for (int q = 0; q < 5; ++q) buf[lw[q]] = cb[q];
    const __half2* srow = sT + ((size_t)(c0 + cg) * NX + nx) * NX;
    __half2 smh[5];
#pragma unroll
    for (int k2 = 0; k2 < 5; ++k2) smh[k2] = srow[k1 + 64 * k2];
    __syncthreads();
    v2f z[5];
#pragma unroll
    for (int q = 0; q < 5; ++q) {
      float2 v = __half22float2(buf[(5 * lane + q) * 5 + j]);
      z[q].x = v.x;  // signs pre-folded in pass1
      z[q].y = v.y;
    }
    fft320p(z, tw);
#pragma unroll
    for (int k2 = 0; k2 < 5; ++k2) {
      float2 sm = __half22float2(smh[k2]);
      v2f zc = {z[k2].y, -z[k2].x};  // conj-MAC helper
      acc[k2] += sm.x * z[k2] + sm.y * zc;
    }
  }
  __half2* dst = im_aux + ((size_t)t * NX + nx) * NX;
#pragma unroll
  for (int k2 = 0; k2 < 5; ++k2) {
    int ny = k1 + 64 * k2;
    v2f nv = acc[k2];  // (-1)^ny folded into sT
    if (!first) {
      float2 old = __half22float2(dst[ny]);
      nv.x += old.x;
      nv.y += old.y;
    }
    dst[ny] = __floats2half2_rn(nv.x, nv.y);
  }
}

// Scatter: block (band b, seg, frame t). LDS-privatized 32-row band of
// __half2 (re,im) cells; taps via ds_pk_add_f16 (4 lane-atomics/element).
__global__ __launch_bounds__(1024) void scatter_k(
    const __half2* __restrict__ im, const float2* __restrict__ fs,
    __half2* __restrict__ out_p, float* __restrict__ out_f, int nseg) {
  int b = blockIdx.x, seg = blockIdx.y, t = blockIdx.z;
  int r0 = b * BR;
  int tid = threadIdx.x, lane = tid & 63, w = tid >> 6;
  __shared__ __half2 acc[BR * NX];  // 40 KB
  const __half2 h2z = __floats2half2_rn(0.f, 0.f);
  for (int i = tid; i < BR * NX; i += 1024) acc[i] = h2z;
  __syncthreads();
  int lo = max(r0 - WH, 0), hi = min(r0 + BR + WH, NX);
  int stride = 16 * nseg;
  for (int nx = lo + seg * 16 + w; nx < hi; nx += stride) {
    bool own = (nx >= r0) && (nx < r0 + BR);
    const __half2* imrow = im + ((size_t)t * NX + nx) * NX;
    const float2* frow = fs + ((size_t)t * NX + nx) * NX;
#pragma unroll
    for (int q = 0; q < 5; ++q) {
      int ny = lane + 64 * q;
      float2 v = __half22float2(imrow[ny]);
      float2 fl = frow[ny];
      float px = fminf(fmaxf((float)nx + fl.x, 0.f), 319.f);
      float py = fminf(fmaxf((float)ny + fl.y, 0.f), 319.f);
      int x0 = (int)floorf(px), y0 = (int)floorf(py);
      int x1 = min(x0 + 1, NX - 1), y1 = min(y0 + 1, NX - 1);
      float wx = px - (float)x0, wy = py - (float)y0;
      float w00 = (1.f - wx) * (1.f - wy), w01 = (1.f - wx) * wy;
      float w10 = wx * (1.f - wy), w11 = wx * wy;
#pragma unroll
      for (int half = 0; half < 2; ++half) {
        int r = half ? x1 : x0;
        float wa = half ? w10 : w00;
        float wb = half ? w11 : w01;
        if (r >= r0 && r < r0 + BR) {
          unsafeAtomicAdd(&acc[(r - r0) * NX + y0],
                          __floats2half2_rn(wa * v.x, wa * v.y));
          unsafeAtomicAdd(&acc[(r - r0) * NX + y1],
                          __floats2half2_rn(wb * v.x, wb * v.y));
        } else if (own) {
          int rb = (r / BR) * BR;
          if (nx < rb - WH || nx >= rb + BR + WH) {  // no band reads nx
            unsafeAtomicAdd(&out_f[((size_t)r * NX + y0) * 2], wa * v.x);
            unsafeAtomicAdd(&out_f[((size_t)r * NX + y0) * 2 + 1], wa * v.y);
            unsafeAtomicAdd(&out_f[((size_t)r * NX + y1) * 2], wb * v.x);
            unsafeAtomicAdd(&out_f[((size_t)r * NX + y1) * 2 + 1], wb * v.y);
          }
        }
      }
    }
  }
  __syncthreads();
  __half2* dst = out_p + (size_t)(seg * NT + t) * NX * NX + (size_t)r0 * NX;
  for (int i = tid; i < BR * NX; i += 1024) dst[i] = acc[i];
}

// out = out_f + sum_{seg,t} out_p (half2 slices)
__global__ __launch_bounds__(256) void reduce_k(
    const __half2* __restrict__ out_p, const float* __restrict__ out_f,
    float* __restrict__ out, int nslice) {
  const int n = NX * NX;  // 102400 cells
  int i = blockIdx.x * 256 + threadIdx.x;
  if (i >= n) return;
  float2 s = ((const float2*)out_f)[i];
  for (int k = 0; k < nslice; ++k) {
    float2 v = __half22float2(out_p[(size_t)k * n + i]);
    s.x += v.x;
    s.y += v.y;
  }
  ((float2*)out)[i] = s;
}

extern "C" void kernel_launch(void* const* d_in, const int* in_sizes, int n_in,
                              void* d_out, int out_size, void* d_ws,
                              size_t ws_size, hipStream_t stream) {
  const float* kr = (const float*)d_in[0];
  const float* ki = (const float*)d_in[1];
  const float* mask = (const float*)d_in[2];
  const float* sr = (const float*)d_in[3];
  const float* si = (const float*)d_in[4];
  const float* fl = (const float*)d_in[5];
  float* out = (float*)d_out;

  const size_t tmp1 = (size_t)NT * NX * NX * 4;      // fp16 complex, per coil
  const size_t kT_b = (size_t)NC * NX * NX * 8;
  const size_t sT_b = (size_t)NC * NX * NX * 4;      // half2
  const size_t fs_b = (size_t)NT * NX * NX * 8;
  const size_t mp_b = (size_t)NC * NX * NX * 4;
  const size_t ia_b = (size_t)NT * NX * NX * 4;      // half2
  const size_t of_b = (size_t)NX * NX * 8;
  const size_t op1 = (size_t)NT * NX * NX * 4;       // half2, per segment

  int NSEG = 2, G = 16;
  for (;;) {
    size_t fixed = kT_b + sT_b + fs_b + mp_b + ia_b + of_b + NSEG * op1;
    if (ws_size >= fixed + (size_t)G * tmp1) break;
    if (G > 1) { G >>= 1; continue; }
    if (NSEG > 1) { NSEG >>= 1; G = 16; continue; }
    break;  // minimal config; assume it fits
  }

  char* w = (char*)d_ws;
  __half2* tmp = (__half2*)w;    w += (size_t)G * tmp1;
  float2* kT = (float2*)w;       w += kT_b;
  __half2* sT = (__half2*)w;     w += sT_b;
  float2* fs = (float2*)w;       w += fs_b;
  __half2* im_aux = (__half2*)w; w += ia_b;
  __half2* out_p = (__half2*)w;  w += (size_t)NSEG * op1;
  float* out_f = (float*)w;      w += of_b;
  unsigned int* mp = (unsigned int*)w;

  prep_k<<<22600, 256, 0, stream>>>(mask, kr, ki, sr, si, fl, mp, kT, sT, fs,
                                    out_f);

  for (int c0 = 0; c0 < NC; c0 += G) {
    pass1_k<<<dim3(NX, G), 256, 0, stream>>>(kT, mp, tmp, c0);
    pass2_k<<<dim3(80, NT), 256, 0, stream>>>(tmp, sT, im_aux, c0, G,
                                              c0 == 0 ? 1 : 0);
  }
  scatter_k<<<dim3(NX / BR, NSEG, NT), 1024, 0, stream>>>(im_aux, fs, out_p,
                                                          out_f, NSEG);
  reduce_k<<<400, 256, 0, stream>>>(out_p, out_f, out, NSEG * NT);
}

// Round 13
// 281.446 us; speedup vs baseline: 1.5243x; 1.0004x over previous
//
#include <hip/hip_runtime.h>
#include <hip/hip_fp16.h>

// MRI adjoint: masked centered 2D IFFT per (coil,frame) -> conj(smaps) combine
// -> bilinear warp-adjoint scatter -> sum over frames. Nx=Ny=320, Nc=16, Nt=25.
//
// FFT: 320 = 5*64; one wave per transform. Selection-free butterfly
// z = cmul(o + sgn*z, w) with lane-resident twiddles; radix-5 twiddles folded
// into the (identity-twiddle) m=1 stage. ds_swizzle (m<=16) / shfl_xor (m=32).
// Centered-transform signs folded into pass1 output & pre-signed smaps.
// tmp fp16 half2 [c][t][ky][nx]; smaps/im_aux fp16.
// prep (round-13): mask packing via __ballot -- coalesced 64-float wave loads
// compress to 64-bit scalars in one op; lanes extract their 25-bit window via
// static-unrolled select + funnel shift. No LDS data staging, no vmcnt drain.
// Scatter: LDS __half2 accumulator + ds_pk_add_f16 taps (LDS atomics are
// ~lane-serialized; halving lane-atomics was round-10's win).

#define NX 320
#define NT 25
#define NC 16
#define BR 32
#define WH 16
static const float INV320 = 1.0f / 320.0f;

typedef float v2f __attribute__((ext_vector_type(2)));

__device__ __forceinline__ int rev6(int l) {
  return ((l & 1) << 5) | ((l & 2) << 3) | ((l & 4) << 1) |
         ((l & 8) >> 1) | ((l & 16) >> 3) | ((l & 32) >> 5);
}

// Lane-resident twiddle state. Stages st=0..4 (m=32..2): sg=bot?-1:+1,
// (cst,sst)=bot?(c,s):(1,0). Stage m=1: sg5 plus folded radix-5 twiddles.
struct Tw {
  float cst[5], sst[5], sg[5];
  float sg5;
  float c5[5], s5[5];
};

__device__ __forceinline__ void make_tw(int lane, Tw& tw) {
#pragma unroll
  for (int st = 0; st < 5; ++st) {
    int m = 32 >> st;
    bool bot = (lane & m) != 0;
    int j = lane & (m - 1);
    float ang = 3.14159265358979323846f * (float)j / (float)m;
    float s, c;
    __sincosf(ang, &s, &c);
    tw.sg[st] = bot ? -1.f : 1.f;
    tw.cst[st] = bot ? c : 1.f;
    tw.sst[st] = bot ? s : 0.f;
  }
  tw.sg5 = (lane & 1) ? -1.f : 1.f;
  int k1 = rev6(lane);
  float b = (6.283185307179586f / 320.0f) * (float)k1;
  float s1, c1;
  __sincosf(b, &s1, &c1);
  tw.c5[0] = 1.f;
  tw.s5[0] = 0.f;
  tw.c5[1] = c1;
  tw.s5[1] = s1;
  tw.c5[2] = c1 * c1 - s1 * s1;
  tw.s5[2] = 2.f * c1 * s1;
  tw.c5[3] = tw.c5[2] * c1 - tw.s5[2] * s1;
  tw.s5[3] = tw.c5[2] * s1 + tw.s5[2] * c1;
  tw.c5[4] = tw.c5[2] * tw.c5[2] - tw.s5[2] * tw.s5[2];
  tw.s5[4] = 2.f * tw.c5[2] * tw.s5[2];
}

template <int M>
__device__ __forceinline__ float lxor(float x) {
  if constexpr (M == 32) {
    return __shfl_xor(x, 32);
  } else {
    constexpr int pat = (M << 10) | 0x1F;  // BitMode: xor=M, and=0x1F
    return __int_as_float(__builtin_amdgcn_ds_swizzle(__float_as_int(x), pat));
  }
}

// (z.x + i z.y) * (c + i s)
__device__ __forceinline__ v2f cmul(v2f z, float c, float s) {
  v2f sw = {-z.y, z.x};
  return c * z + s * sw;
}

template <int M>
__device__ __forceinline__ void bstage(v2f z[5], float sg, float c, float s) {
#pragma unroll
  for (int q = 0; q < 5; ++q) {
    v2f o;
    o.x = lxor<M>(z[q].x);
    o.y = lxor<M>(z[q].y);
    v2f t = o + sg * z[q];
    z[q] = cmul(t, c, s);  // top lanes: (c,s)=(1,0) -> identity
  }
}

// Unnormalized inverse 320-pt DFT: lane l enters with x[5l+q] in z[q];
// exits with X[rev6(l) + 64*q].
__device__ __forceinline__ void fft320p(v2f z[5], const Tw& tw) {
  bstage<32>(z, tw.sg[0], tw.cst[0], tw.sst[0]);
  bstage<16>(z, tw.sg[1], tw.cst[1], tw.sst[1]);
  bstage<8>(z, tw.sg[2], tw.cst[2], tw.sst[2]);
  bstage<4>(z, tw.sg[3], tw.cst[3], tw.sst[3]);
  bstage<2>(z, tw.sg[4], tw.cst[4], tw.sst[4]);
  {
    v2f o;
    o.x = lxor<1>(z[0].x);
    o.y = lxor<1>(z[0].y);
    z[0] = o + tw.sg5 * z[0];  // c5[0]=1: no cmul
#pragma unroll
    for (int q = 1; q < 5; ++q) {
      o.x = lxor<1>(z[q].x);
      o.y = lxor<1>(z[q].y);
      v2f t = o + tw.sg5 * z[q];
      z[q] = cmul(t, tw.c5[q], tw.s5[q]);
    }
  }
  v2f t0 = z[0], t1 = z[1], t2 = z[2], t3 = z[3], t4 = z[4];
  const float C1 = 0.30901699437494742f, S1 = 0.95105651629515357f;
  const float C2 = -0.80901699437494742f, S2 = 0.58778525229247312f;
  v2f a1 = t1 + t4, b1 = t1 - t4;
  v2f a2 = t2 + t3, b2 = t2 - t3;
  z[0] = t0 + a1 + a2;
  v2f p = t0 + C1 * a1 + C2 * a2;
  v2f q_ = S1 * b1 + S2 * b2;
  v2f r = t0 + C2 * a1 + C1 * a2;
  v2f u = S2 * b1 - S1 * b2;
  v2f qi = {-q_.y, q_.x};
  v2f ui = {-u.y, u.x};
  z[1] = p + qi;
  z[4] = p - qi;
  z[2] = r + ui;
  z[3] = r - ui;
}

// Merged pre-pass: role-switched on blockIdx.x. ONE overlaid LDS buffer.
//  [0,6400)      mask [x][y][c][t] -> bit-packed mp[c][y][x] (ballot pack)
//  [6400,12800)  kspace [x][y][c] -> kT[c][y][x] float2
//  [12800,19200) smaps [x][y][c] -> sT[c][x][y] half2, pre-signed by (-1)^y
//  [19200,22400) flow [nx][ny][2][t] -> fs[t][nx][ny] float2
//  [22400,22600) zero out_f
__global__ __launch_bounds__(256) void prep_k(
    const float* __restrict__ mask, const float* __restrict__ kr,
    const float* __restrict__ ki, const float* __restrict__ sr,
    const float* __restrict__ si, const float* __restrict__ fl,
    unsigned int* __restrict__ mp, float2* __restrict__ kT,
    __half2* __restrict__ sT, float2* __restrict__ fs,
    float* __restrict__ out_f) {
  __shared__ __align__(16) char shmem[7552];  // overlaid by all phases
  int bid = blockIdx.x, tid = threadIdx.x;
  if (bid < 6400) {
    int xt = bid % 20, y = bid / 20;
    int w = tid >> 6, lane = tid & 63;
    unsigned int* tileu = (unsigned int*)shmem;  // [16][17]
#pragma unroll
    for (int k = 0; k < 4; ++k) {
      int xx = w * 4 + k;
      const float* src = mask + ((size_t)((xt * 16 + xx) * NX) + y) * (NC * NT);
      unsigned long long B[7];
#pragma unroll
      for (int i = 0; i < 7; ++i) {
        int f = lane + 64 * i;
        float v = (f < NC * NT) ? src[f] : 0.f;
        B[i] = __ballot(v != 0.f);
      }
      if (lane < 16) {
        int lo = lane * 25;
        int idx = lo >> 6, sh = lo & 63;
        unsigned long long b0 = B[0], b1 = B[1];
        if (idx == 1) { b0 = B[1]; b1 = B[2]; }
        else if (idx == 2) { b0 = B[2]; b1 = B[3]; }
        else if (idx == 3) { b0 = B[3]; b1 = B[4]; }
        else if (idx == 4) { b0 = B[4]; b1 = B[5]; }
        else if (idx == 5) { b0 = B[5]; b1 = B[6]; }
        unsigned long long v = b0 >> sh;
        if (sh > 39) v |= b1 << (64 - sh);  // 25-bit window straddles words
        tileu[xx * 17 + lane] = (unsigned)(v & 0x1FFFFFFULL);
      }
    }
    __syncthreads();
    int c2 = tid >> 4, xx2 = tid & 15;
    mp[((size_t)(c2 * NX + y)) * NX + xt * 16 + xx2] = tileu[xx2 * 17 + c2];
  } else if (bid < 12800) {
    int r = bid - 6400;
    int xt = r % 20, y = r / 20;
    int xx = tid >> 4, c = tid & 15;
    float2* tilef = (float2*)shmem;  // [16][17]
    size_t si_ = (size_t)((xt * 16 + xx) * NX + y) * NC + c;
    tilef[xx * 17 + c] = make_float2(kr[si_], ki[si_]);
    __syncthreads();
    int c2 = tid >> 4, xx2 = tid & 15;
    kT[((size_t)(c2 * NX + y)) * NX + xt * 16 + xx2] = tilef[xx2 * 17 + c2];
  } else if (bid < 19200) {
    int r = bid - 12800;
    int yt = r % 20, x = r / 20;
    int yy = tid >> 4, c = tid & 15;
    float2* tiles = (float2*)shmem;  // [16][17]
    size_t si_ = (size_t)(x * NX + yt * 16 + yy) * NC + c;
    tiles[yy * 17 + c] = make_float2(sr[si_], si[si_]);
    __syncthreads();
    int c2 = tid >> 4, yy2 = tid & 15;
    float2 v = tiles[yy2 * 17 + c2];
    float sg = (yy2 & 1) ? -1.f : 1.f;  // (-1)^ny pre-sign
    sT[((size_t)(c2 * NX + x)) * NX + yt * 16 + yy2] =
        __floats2half2_rn(v.x * sg, v.y * sg);
  } else if (bid < 22400) {
    int r = bid - 19200;
    int nyt = r % 10, nx = r / 10;
    float* buf = (float*)shmem;  // [1600]
    size_t base = (size_t)(nx * NX + nyt * 32) * (2 * NT);
    for (int f = tid; f < 1600; f += 256) buf[f] = fl[base + f];
    __syncthreads();
    for (int f = tid; f < 1600; f += 256) {
      int t = f / 64;
      int k = f % 64;
      int nyl = k >> 1, d = k & 1;
      size_t di = ((size_t)(t * NX + nx) * NX + nyt * 32 + nyl) * 2 + d;
      ((float*)fs)[di] = buf[(nyl * 2 + d) * NT + t];
    }
  } else {
    int idx = (bid - 22400) * 256 + tid;  // 51200 float4
    ((float4*)out_f)[idx] = make_float4(0.f, 0.f, 0.f, 0.f);
  }
}

// Pass 1: x-axis IFFT for coil chunk [c0, c0+G). Writes tmp[cg][t][ky][nx]
// fp16, pre-signed by (-1)^nx * (-1)^ky.
__global__ __launch_bounds__(256) void pass1_k(
    const float2* __restrict__ kT, const unsigned int* __restrict__ mp,
    __half2* __restrict__ tmp, int c0) {
  int y = blockIdx.x, cg = blockIdx.y, c = c0 + cg;
  int tid = threadIdx.x, lane = tid & 63, w = tid >> 6;
  v2f v[5];
  unsigned int mb[5];
  size_t rowbase = ((size_t)c * NX + y) * NX;
#pragma unroll
  for (int q = 0; q < 5; ++q) {
    int x = 5 * lane + q;
    float2 kv = kT[rowbase + x];
    float sg = ((lane + q) & 1) ? -INV320 : INV320;  // (-1)^x / 320
    v[q].x = kv.x * sg;
    v[q].y = kv.y * sg;
    mb[q] = mp[rowbase + x];
  }
  Tw tw;
  make_tw(lane, tw);
  int r6 = rev6(lane);
  float osg = ((lane & 32) ? -1.f : 1.f) * ((y & 1) ? -1.f : 1.f);
  for (int t = w; t < NT; t += 4) {
    v2f z[5];
#pragma unroll
    for (int q = 0; q < 5; ++q) {
      float m = ((mb[q] >> t) & 1u) ? 1.f : 0.f;
      z[q] = v[q] * m;
    }
    fft320p(z, tw);
    __half2* dst = tmp + ((size_t)(cg * NT + t) * NX + y) * NX;
#pragma unroll
    for (int k2 = 0; k2 < 5; ++k2)
      dst[r6 + 64 * k2] = __floats2half2_rn(z[k2].x * osg, z[k2].y * osg);
  }
}

// Pass 2: y-axis IFFT + conj(smaps) combine -> im_aux[t][nx][ny] fp16.
// 256 threads = 4 waves; block = (nx-tile of 4, t); wave j owns nx.
__global__ __launch_bounds__(256) void pass2_k(
    const __half2* __restrict__ tmp, const __half2* __restrict__ sT,
    __half2* __restrict__ im_aux, int c0, int G, int first) {
  int bx = blockIdx.x, t = blockIdx.y;
  int nxt_ = (bx >> 3) + 10 * (bx & 7);  // bijective on [0,80)
  int tid = threadIdx.x, lane = tid & 63, j = tid >> 6;
  int nx = nxt_ * 4 + j;
  int k1 = rev6(lane);
  Tw tw;
  make_tw(lane, tw);
  __shared__ __half2 tile[2][NX][5];  // 12.8 KB
  v2f acc[5] = {{0, 0}, {0, 0}, {0, 0}, {0, 0}, {0, 0}};

  int off[5], lw[5];
#pragma unroll
  for (int q = 0; q < 5; ++q) {
    int f = tid + q * 256;
    off[q] = (f >> 2) * NX + (f & 3);
    lw[q] = (f >> 2) * 5 + (f & 3);
  }
  const size_t pstride = (size_t)NT * NX * NX;
  const __half2* sbase = tmp + (size_t)t * NX * NX + nxt_ * 4;
  __half2* lds = &tile[0][0][0];

  __half2 nb[5];
#pragma unroll
  for (int q = 0; q < 5; ++q) nb[q] = sbase[off[q]];

  for (int cg = 0; cg < G; ++cg) {
    __half2 cb[5];
#pragma unroll
    for (int q = 0; q < 5; ++q) cb[q] = nb[q];
    if (cg + 1 < G) {
      const __half2* s = sbase + (size_t)(cg + 1) * pstride;
#pragma unroll
      for (int q = 0; q < 5; ++q) nb[q] = s[off[q]];  // in flight across iter
    }
    __half2* buf = lds + (cg & 1) * (NX * 5);
#pragma unroll
    for (int q = 0; q < 5; ++q) buf[lw[q]] = cb[q];
    const __half2* srow = sT + ((size_t)(c0 + cg) * NX + nx) * NX;
    __half2 smh[5];
#pragma unroll
    for (int k2 = 0; k2 < 5; ++k2) smh[k2] = srow[k1 + 64 * k2];
    __syncthreads();
    v2f z[5];
#pragma unroll
    for (int q = 0; q < 5; ++q) {
      float2 v = __half22float2(buf[(5 * lane + q) * 5 + j]);
      z[q].x = v.x;  // signs pre-folded in pass1
      z[q].y = v.y;
    }
    fft320p(z, tw);
#pragma unroll
    for (int k2 = 0; k2 < 5; ++k2) {
      float2 sm = __half22float2(smh[k2]);
      v2f zc = {z[k2].y, -z[k2].x};  // conj-MAC helper
      acc[k2] += sm.x * z[k2] + sm.y * zc;
    }
  }
  __half2* dst = im_aux + ((size_t)t * NX + nx) * NX;
#pragma unroll
  for (int k2 = 0; k2 < 5; ++k2) {
    int ny = k1 + 64 * k2;
    v2f nv = acc[k2];  // (-1)^ny folded into sT
    if (!first) {
      float2 old = __half22float2(dst[ny]);
      nv.x += old.x;
      nv.y += old.y;
    }
    dst[ny] = __floats2half2_rn(nv.x, nv.y);
  }
}

// Scatter: block (band b, seg, frame t). LDS-privatized 32-row band of
// __half2 (re,im) cells; taps via ds_pk_add_f16 (4 lane-atomics/element).
__global__ __launch_bounds__(1024) void scatter_k(
    const __half2* __restrict__ im, const float2* __restrict__ fs,
    __half2* __restrict__ out_p, float* __restrict__ out_f, int nseg) {
  int b = blockIdx.x, seg = blockIdx.y, t = blockIdx.z;
  int r0 = b * BR;
  int tid = threadIdx.x, lane = tid & 63, w = tid >> 6;
  __shared__ __half2 acc[BR * NX];  // 40 KB
  const __half2 h2z = __floats2half2_rn(0.f, 0.f);
  for (int i = tid; i < BR * NX; i += 1024) acc[i] = h2z;
  __syncthreads();
  int lo = max(r0 - WH, 0), hi = min(r0 + BR + WH, NX);
  int stride = 16 * nseg;
  for (int nx = lo + seg * 16 + w; nx < hi; nx += stride) {
    bool own = (nx >= r0) && (nx < r0 + BR);
    const __half2* imrow = im + ((size_t)t * NX + nx) * NX;
    const float2* frow = fs + ((size_t)t * NX + nx) * NX;
#pragma unroll
    for (int q = 0; q < 5; ++q) {
      int ny = lane + 64 * q;
      float2 v = __half22float2(imrow[ny]);
      float2 fl = frow[ny];
      float px = fminf(fmaxf((float)nx + fl.x, 0.f), 319.f);
      float py = fminf(fmaxf((float)ny + fl.y, 0.f), 319.f);
      int x0 = (int)floorf(px), y0 = (int)floorf(py);
      int x1 = min(x0 + 1, NX - 1), y1 = min(y0 + 1, NX - 1);
      float wx = px - (float)x0, wy = py - (float)y0;
      float w00 = (1.f - wx) * (1.f - wy), w01 = (1.f - wx) * wy;
      float w10 = wx * (1.f - wy), w11 = wx * wy;
#pragma unroll
      for (int half = 0; half < 2; ++half) {
        int r = half ? x1 : x0;
        float wa = half ? w10 : w00;
        float wb = half ? w11 : w01;
        if (r >= r0 && r < r0 + BR) {
          unsafeAtomicAdd(&acc[(r - r0) * NX + y0],
                          __floats2half2_rn(wa * v.x, wa * v.y));
          unsafeAtomicAdd(&acc[(r - r0) * NX + y1],
                          __floats2half2_rn(wb * v.x, wb * v.y));
        } else if (own) {
          int rb = (r / BR) * BR;
          if (nx < rb - WH || nx >= rb + BR + WH) {  // no band reads nx
            unsafeAtomicAdd(&out_f[((size_t)r * NX + y0) * 2], wa * v.x);
            unsafeAtomicAdd(&out_f[((size_t)r * NX + y0) * 2 + 1], wa * v.y);
            unsafeAtomicAdd(&out_f[((size_t)r * NX + y1) * 2], wb * v.x);
            unsafeAtomicAdd(&out_f[((size_t)r * NX + y1) * 2 + 1], wb * v.y);
          }
        }
      }
    }
  }
  __syncthreads();
  __half2* dst = out_p + (size_t)(seg * NT + t) * NX * NX + (size_t)r0 * NX;
  for (int i = tid; i < BR * NX; i += 1024) dst[i] = acc[i];
}

// out = out_f + sum_{seg,t} out_p (half2 slices)
__global__ __launch_bounds__(256) void reduce_k(
    const __half2* __restrict__ out_p, const float* __restrict__ out_f,
    float* __restrict__ out, int nslice) {
  const int n = NX * NX;  // 102400 cells
  int i = blockIdx.x * 256 + threadIdx.x;
  if (i >= n) return;
  float2 s = ((const float2*)out_f)[i];
  for (int k = 0; k < nslice; ++k) {
    float2 v = __half22float2(out_p[(size_t)k * n + i]);
    s.x += v.x;
    s.y += v.y;
  }
  ((float2*)out)[i] = s;
}

extern "C" void kernel_launch(void* const* d_in, const int* in_sizes, int n_in,
                              void* d_out, int out_size, void* d_ws,
                              size_t ws_size, hipStream_t stream) {
  const float* kr = (const float*)d_in[0];
  const float* ki = (const float*)d_in[1];
  const float* mask = (const float*)d_in[2];
  const float* sr = (const float*)d_in[3];
  const float* si = (const float*)d_in[4];
  const float* fl = (const float*)d_in[5];
  float* out = (float*)d_out;

  const size_t tmp1 = (size_t)NT * NX * NX * 4;      // fp16 complex, per coil
  const size_t kT_b = (size_t)NC * NX * NX * 8;
  const size_t sT_b = (size_t)NC * NX * NX * 4;      // half2
  const size_t fs_b = (size_t)NT * NX * NX * 8;
  const size_t mp_b = (size_t)NC * NX * NX * 4;
  const size_t ia_b = (size_t)NT * NX * NX * 4;      // half2
  const size_t of_b = (size_t)NX * NX * 8;
  const size_t op1 = (size_t)NT * NX * NX * 4;       // half2, per segment

  int NSEG = 2, G = 16;
  for (;;) {
    size_t fixed = kT_b + sT_b + fs_b + mp_b + ia_b + of_b + NSEG * op1;
    if (ws_size >= fixed + (size_t)G * tmp1) break;
    if (G > 1) { G >>= 1; continue; }
    if (NSEG > 1) { NSEG >>= 1; G = 16; continue; }
    break;  // minimal config; assume it fits
  }

  char* w = (char*)d_ws;
  __half2* tmp = (__half2*)w;    w += (size_t)G * tmp1;
  float2* kT = (float2*)w;       w += kT_b;
  __half2* sT = (__half2*)w;     w += sT_b;
  float2* fs = (float2*)w;       w += fs_b;
  __half2* im_aux = (__half2*)w; w += ia_b;
  __half2* out_p = (__half2*)w;  w += (size_t)NSEG * op1;
  float* out_f = (float*)w;      w += of_b;
  unsigned int* mp = (unsigned int*)w;

  prep_k<<<22600, 256, 0, stream>>>(mask, kr, ki, sr, si, fl, mp, kT, sT, fs,
                                    out_f);

  for (int c0 = 0; c0 < NC; c0 += G) {
    pass1_k<<<dim3(NX, G), 256, 0, stream>>>(kT, mp, tmp, c0);
    pass2_k<<<dim3(80, NT), 256, 0, stream>>>(tmp, sT, im_aux, c0, G,
                                              c0 == 0 ? 1 : 0);
  }
  scatter_k<<<dim3(NX / BR, NSEG, NT), 1024, 0, stream>>>(im_aux, fs, out_p,
                                                          out_f, NSEG);
  reduce_k<<<400, 256, 0, stream>>>(out_p, out_f, out, NSEG * NT);
}

// Round 14
// 275.330 us; speedup vs baseline: 1.5582x; 1.0222x over previous
//
#include <hip/hip_runtime.h>
#include <hip/hip_fp16.h>

// MRI adjoint: masked centered 2D IFFT per (coil,frame) -> conj(smaps) combine
// -> bilinear warp-adjoint scatter -> sum over frames. Nx=Ny=320, Nc=16, Nt=25.
//
// FFT: 320 = 5*64; one wave per transform. Selection-free butterfly
// z = cmul(o + sgn*z, w) with lane-resident twiddles; radix-5 twiddles folded
// into the (identity-twiddle) m=1 stage. ds_swizzle (m<=16) / shfl_xor (m=32).
// Centered-transform signs folded into pass1 output & pre-signed smaps.
// tmp fp16 half2 [c][t][ky][nx]; smaps/im_aux fp16.
// prep (round-14): mask phase loads float4 (1KB/wave-instr vs 256B dword --
// rounds 11-13 all ~100us regardless of pack style => stream-limited) and
// blocks are y-major so consecutive blocks read adjacent 1600B chunks
// (sequential streams, not 512KB-strided chunks). Flow loads float2.
// Scatter: LDS __half2 accumulator + ds_pk_add_f16 taps (LDS atomics are
// ~lane-serialized; halving lane-atomics was round-10's win).

#define NX 320
#define NT 25
#define NC 16
#define BR 32
#define WH 16
static const float INV320 = 1.0f / 320.0f;

typedef float v2f __attribute__((ext_vector_type(2)));

__device__ __forceinline__ int rev6(int l) {
  return ((l & 1) << 5) | ((l & 2) << 3) | ((l & 4) << 1) |
         ((l & 8) >> 1) | ((l & 16) >> 3) | ((l & 32) >> 5);
}

// Lane-resident twiddle state. Stages st=0..4 (m=32..2): sg=bot?-1:+1,
// (cst,sst)=bot?(c,s):(1,0). Stage m=1: sg5 plus folded radix-5 twiddles.
struct Tw {
  float cst[5], sst[5], sg[5];
  float sg5;
  float c5[5], s5[5];
};

__device__ __forceinline__ void make_tw(int lane, Tw& tw) {
#pragma unroll
  for (int st = 0; st < 5; ++st) {
    int m = 32 >> st;
    bool bot = (lane & m) != 0;
    int j = lane & (m - 1);
    float ang = 3.14159265358979323846f * (float)j / (float)m;
    float s, c;
    __sincosf(ang, &s, &c);
    tw.sg[st] = bot ? -1.f : 1.f;
    tw.cst[st] = bot ? c : 1.f;
    tw.sst[st] = bot ? s : 0.f;
  }
  tw.sg5 = (lane & 1) ? -1.f : 1.f;
  int k1 = rev6(lane);
  float b = (6.283185307179586f / 320.0f) * (float)k1;
  float s1, c1;
  __sincosf(b, &s1, &c1);
  tw.c5[0] = 1.f;
  tw.s5[0] = 0.f;
  tw.c5[1] = c1;
  tw.s5[1] = s1;
  tw.c5[2] = c1 * c1 - s1 * s1;
  tw.s5[2] = 2.f * c1 * s1;
  tw.c5[3] = tw.c5[2] * c1 - tw.s5[2] * s1;
  tw.s5[3] = tw.c5[2] * s1 + tw.s5[2] * c1;
  tw.c5[4] = tw.c5[2] * tw.c5[2] - tw.s5[2] * tw.s5[2];
  tw.s5[4] = 2.f * tw.c5[2] * tw.s5[2];
}

template <int M>
__device__ __forceinline__ float lxor(float x) {
  if constexpr (M == 32) {
    return __shfl_xor(x, 32);
  } else {
    constexpr int pat = (M << 10) | 0x1F;  // BitMode: xor=M, and=0x1F
    return __int_as_float(__builtin_amdgcn_ds_swizzle(__float_as_int(x), pat));
  }
}

// (z.x + i z.y) * (c + i s)
__device__ __forceinline__ v2f cmul(v2f z, float c, float s) {
  v2f sw = {-z.y, z.x};
  return c * z + s * sw;
}

template <int M>
__device__ __forceinline__ void bstage(v2f z[5], float sg, float c, float s) {
#pragma unroll
  for (int q = 0; q < 5; ++q) {
    v2f o;
    o.x = lxor<M>(z[q].x);
    o.y = lxor<M>(z[q].y);
    v2f t = o + sg * z[q];
    z[q] = cmul(t, c, s);  // top lanes: (c,s)=(1,0) -> identity
  }
}

// Unnormalized inverse 320-pt DFT: lane l enters with x[5l+q] in z[q];
// exits with X[rev6(l) + 64*q].
__device__ __forceinline__ void fft320p(v2f z[5], const Tw& tw) {
  bstage<32>(z, tw.sg[0], tw.cst[0], tw.sst[0]);
  bstage<16>(z, tw.sg[1], tw.cst[1], tw.sst[1]);
  bstage<8>(z, tw.sg[2], tw.cst[2], tw.sst[2]);
  bstage<4>(z, tw.sg[3], tw.cst[3], tw.sst[3]);
  bstage<2>(z, tw.sg[4], tw.cst[4], tw.sst[4]);
  {
    v2f o;
    o.x = lxor<1>(z[0].x);
    o.y = lxor<1>(z[0].y);
    z[0] = o + tw.sg5 * z[0];  // c5[0]=1: no cmul
#pragma unroll
    for (int q = 1; q < 5; ++q) {
      o.x = lxor<1>(z[q].x);
      o.y = lxor<1>(z[q].y);
      v2f t = o + tw.sg5 * z[q];
      z[q] = cmul(t, tw.c5[q], tw.s5[q]);
    }
  }
  v2f t0 = z[0], t1 = z[1], t2 = z[2], t3 = z[3], t4 = z[4];
  const float C1 = 0.30901699437494742f, S1 = 0.95105651629515357f;
  const float C2 = -0.80901699437494742f, S2 = 0.58778525229247312f;
  v2f a1 = t1 + t4, b1 = t1 - t4;
  v2f a2 = t2 + t3, b2 = t2 - t3;
  z[0] = t0 + a1 + a2;
  v2f p = t0 + C1 * a1 + C2 * a2;
  v2f q_ = S1 * b1 + S2 * b2;
  v2f r = t0 + C2 * a1 + C1 * a2;
  v2f u = S2 * b1 - S1 * b2;
  v2f qi = {-q_.y, q_.x};
  v2f ui = {-u.y, u.x};
  z[1] = p + qi;
  z[4] = p - qi;
  z[2] = r + ui;
  z[3] = r - ui;
}

// Merged pre-pass: role-switched on blockIdx.x. ONE overlaid LDS buffer.
//  [0,6400)      mask [x][y][c][t] -> bit-packed mp[c][y][x] (float4, y-major)
//  [6400,12800)  kspace [x][y][c] -> kT[c][y][x] float2
//  [12800,19200) smaps [x][y][c] -> sT[c][x][y] half2, pre-signed by (-1)^y
//  [19200,22400) flow [nx][ny][2][t] -> fs[t][nx][ny] float2 (float2 loads)
//  [22400,22600) zero out_f
__global__ __launch_bounds__(256) void prep_k(
    const float* __restrict__ mask, const float* __restrict__ kr,
    const float* __restrict__ ki, const float* __restrict__ sr,
    const float* __restrict__ si, const float* __restrict__ fl,
    unsigned int* __restrict__ mp, float2* __restrict__ kT,
    __half2* __restrict__ sT, float2* __restrict__ fs,
    float* __restrict__ out_f) {
  __shared__ __align__(16) char shmem[7552];  // overlaid by all phases
  int bid = blockIdx.x, tid = threadIdx.x;
  if (bid < 6400) {
    // y-major: consecutive blocks read adjacent 1600B chunks (16 seq streams)
    int xt = bid / 320, y = bid % 320;
    int w = tid >> 6, lane = tid & 63;
    float4* stage4 = (float4*)shmem;                      // [4][100]
    float* stage = (float*)shmem;
    unsigned int* tileu = (unsigned int*)(shmem + 6400);  // [16][17]
#pragma unroll
    for (int k = 0; k < 4; ++k) {
      int xx = w * 4 + k;
      const float4* src =
          (const float4*)(mask + ((size_t)((xt * 16 + xx) * NX) + y) * (NC * NT));
      float4* dst4 = stage4 + w * 100;
      if (lane < 50) {
        dst4[lane] = src[lane];           // 1KB/wave-instr
        dst4[lane + 50] = src[lane + 50];
      }
      if (lane < 16) {
        const float* row = stage + w * 400 + lane * NT;
        unsigned int bits = 0;
#pragma unroll
        for (int t = 0; t < NT; ++t) bits |= (row[t] != 0.f) ? (1u << t) : 0u;
        tileu[xx * 17 + lane] = bits;
      }
    }
    __syncthreads();
    int c2 = tid >> 4, xx2 = tid & 15;
    mp[((size_t)(c2 * NX + y)) * NX + xt * 16 + xx2] = tileu[xx2 * 17 + c2];
  } else if (bid < 12800) {
    int r = bid - 6400;
    int xt = r % 20, y = r / 20;
    int xx = tid >> 4, c = tid & 15;
    float2* tilef = (float2*)shmem;  // [16][17]
    size_t si_ = (size_t)((xt * 16 + xx) * NX + y) * NC + c;
    tilef[xx * 17 + c] = make_float2(kr[si_], ki[si_]);
    __syncthreads();
    int c2 = tid >> 4, xx2 = tid & 15;
    kT[((size_t)(c2 * NX + y)) * NX + xt * 16 + xx2] = tilef[xx2 * 17 + c2];
  } else if (bid < 19200) {
    int r = bid - 12800;
    int yt = r % 20, x = r / 20;
    int yy = tid >> 4, c = tid & 15;
    float2* tiles = (float2*)shmem;  // [16][17]
    size_t si_ = (size_t)(x * NX + yt * 16 + yy) * NC + c;
    tiles[yy * 17 + c] = make_float2(sr[si_], si[si_]);
    __syncthreads();
    int c2 = tid >> 4, yy2 = tid & 15;
    float2 v = tiles[yy2 * 17 + c2];
    float sg = (yy2 & 1) ? -1.f : 1.f;  // (-1)^ny pre-sign
    sT[((size_t)(c2 * NX + x)) * NX + yt * 16 + yy2] =
        __floats2half2_rn(v.x * sg, v.y * sg);
  } else if (bid < 22400) {
    int r = bid - 19200;
    int nyt = r % 10, nx = r / 10;
    float* buf = (float*)shmem;  // [1600]
    size_t base = (size_t)(nx * NX + nyt * 32) * (2 * NT);
    const float2* src2 = (const float2*)(fl + base);  // 8B-aligned
    float2* buf2 = (float2*)shmem;
    for (int f = tid; f < 800; f += 256) buf2[f] = src2[f];
    __syncthreads();
    for (int f = tid; f < 1600; f += 256) {
      int t = f / 64;
      int k = f % 64;
      int nyl = k >> 1, d = k & 1;
      size_t di = ((size_t)(t * NX + nx) * NX + nyt * 32 + nyl) * 2 + d;
      ((float*)fs)[di] = buf[(nyl * 2 + d) * NT + t];
    }
  } else {
    int idx = (bid - 22400) * 256 + tid;  // 51200 float4
    ((float4*)out_f)[idx] = make_float4(0.f, 0.f, 0.f, 0.f);
  }
}

// Pass 1: x-axis IFFT for coil chunk [c0, c0+G). Writes tmp[cg][t][ky][nx]
// fp16, pre-signed by (-1)^nx * (-1)^ky.
__global__ __launch_bounds__(256) void pass1_k(
    const float2* __restrict__ kT, const unsigned int* __restrict__ mp,
    __half2* __restrict__ tmp, int c0) {
  int y = blockIdx.x, cg = blockIdx.y, c = c0 + cg;
  int tid = threadIdx.x, lane = tid & 63, w = tid >> 6;
  v2f v[5];
  unsigned int mb[5];
  size_t rowbase = ((size_t)c * NX + y) * NX;
#pragma unroll
  for (int q = 0; q < 5; ++q) {
    int x = 5 * lane + q;
    float2 kv = kT[rowbase + x];
    float sg = ((lane + q) & 1) ? -INV320 : INV320;  // (-1)^x / 320
    v[q].x = kv.x * sg;
    v[q].y = kv.y * sg;
    mb[q] = mp[rowbase + x];
  }
  Tw tw;
  make_tw(lane, tw);
  int r6 = rev6(lane);
  float osg = ((lane & 32) ? -1.f : 1.f) * ((y & 1) ? -1.f : 1.f);
  for (int t = w; t < NT; t += 4) {
    v2f z[5];
#pragma unroll
    for (int q = 0; q < 5; ++q) {
      float m = ((mb[q] >> t) & 1u) ? 1.f : 0.f;
      z[q] = v[q] * m;
    }
    fft320p(z, tw);
    __half2* dst = tmp + ((size_t)(cg * NT + t) * NX + y) * NX;
#pragma unroll
    for (int k2 = 0; k2 < 5; ++k2)
      dst[r6 + 64 * k2] = __floats2half2_rn(z[k2].x * osg, z[k2].y * osg);
  }
}

// Pass 2: y-axis IFFT + conj(smaps) combine -> im_aux[t][nx][ny] fp16.
// 256 threads = 4 waves; block = (nx-tile of 4, t); wave j owns nx.
__global__ __launch_bounds__(256) void pass2_k(
    const __half2* __restrict__ tmp, const __half2* __restrict__ sT,
    __half2* __restrict__ im_aux, int c0, int G, int first) {
  int bx = blockIdx.x, t = blockIdx.y;
  int nxt_ = (bx >> 3) + 10 * (bx & 7);  // bijective on [0,80)
  int tid = threadIdx.x, lane = tid & 63, j = tid >> 6;
  int nx = nxt_ * 4 + j;
  int k1 = rev6(lane);
  Tw tw;
  make_tw(lane, tw);
  __shared__ __half2 tile[2][NX][5];  // 12.8 KB
  v2f acc[5] = {{0, 0}, {0, 0}, {0, 0}, {0, 0}, {0, 0}};

  int off[5], lw[5];
#pragma unroll
  for (int q = 0; q < 5; ++q) {
    int f = tid + q * 256;
    off[q] = (f >> 2) * NX + (f & 3);
    lw[q] = (f >> 2) * 5 + (f & 3);
  }
  const size_t pstride = (size_t)NT * NX * NX;
  const __half2* sbase = tmp + (size_t)t * NX * NX + nxt_ * 4;
  __half2* lds = &tile[0][0][0];

  __half2 nb[5];
#pragma unroll
  for (int q = 0; q < 5; ++q) nb[q] = sbase[off[q]];

  for (int cg = 0; cg < G; ++cg) {
    __half2 cb[5];
#pragma unroll
    for (int q = 0; q < 5; ++q) cb[q] = nb[q];
    if (cg + 1 < G) {
      const __half2* s = sbase + (size_t)(cg + 1) * pstride;
#pragma unroll
      for (int q = 0; q < 5; ++q) nb[q] = s[off[q]];  // in flight across iter
    }
    __half2* buf = lds + (cg & 1) * (NX * 5);
#pragma unroll
    for (int q = 0; q < 5; ++q) buf[lw[q]] = cb[q];
    const __half2* srow = sT + ((size_t)(c0 + cg) * NX + nx) * NX;
    __half2 smh[5];
#pragma unroll
    for (int k2 = 0; k2 < 5; ++k2) smh[k2] = srow[k1 + 64 * k2];
    __syncthreads();
    v2f z[5];
#pragma unroll
    for (int q = 0; q < 5; ++q) {
      float2 v = __half22float2(buf[(5 * lane + q) * 5 + j]);
      z[q].x = v.x;  // signs pre-folded in pass1
      z[q].y = v.y;
    }
    fft320p(z, tw);
#pragma unroll
    for (int k2 = 0; k2 < 5; ++k2) {
      float2 sm = __half22float2(smh[k2]);
      v2f zc = {z[k2].y, -z[k2].x};  // conj-MAC helper
      acc[k2] += sm.x * z[k2] + sm.y * zc;
    }
  }
  __half2* dst = im_aux + ((size_t)t * NX + nx) * NX;
#pragma unroll
  for (int k2 = 0; k2 < 5; ++k2) {
    int ny = k1 + 64 * k2;
    v2f nv = acc[k2];  // (-1)^ny folded into sT
    if (!first) {
      float2 old = __half22float2(dst[ny]);
      nv.x += old.x;
      nv.y += old.y;
    }
    dst[ny] = __floats2half2_rn(nv.x, nv.y);
  }
}

// Scatter: block (band b, seg, frame t). LDS-privatized 32-row band of
// __half2 (re,im) cells; taps via ds_pk_add_f16 (4 lane-atomics/element).
__global__ __launch_bounds__(1024) void scatter_k(
    const __half2* __restrict__ im, const float2* __restrict__ fs,
    __half2* __restrict__ out_p, float* __restrict__ out_f, int nseg) {
  int b = blockIdx.x, seg = blockIdx.y, t = blockIdx.z;
  int r0 = b * BR;
  int tid = threadIdx.x, lane = tid & 63, w = tid >> 6;
  __shared__ __half2 acc[BR * NX];  // 40 KB
  const __half2 h2z = __floats2half2_rn(0.f, 0.f);
  for (int i = tid; i < BR * NX; i += 1024) acc[i] = h2z;
  __syncthreads();
  int lo = max(r0 - WH, 0), hi = min(r0 + BR + WH, NX);
  int stride = 16 * nseg;
  for (int nx = lo + seg * 16 + w; nx < hi; nx += stride) {
    bool own = (nx >= r0) && (nx < r0 + BR);
    const __half2* imrow = im + ((size_t)t * NX + nx) * NX;
    const float2* frow = fs + ((size_t)t * NX + nx) * NX;
#pragma unroll
    for (int q = 0; q < 5; ++q) {
      int ny = lane + 64 * q;
      float2 v = __half22float2(imrow[ny]);
      float2 fl = frow[ny];
      float px = fminf(fmaxf((float)nx + fl.x, 0.f), 319.f);
      float py = fminf(fmaxf((float)ny + fl.y, 0.f), 319.f);
      int x0 = (int)floorf(px), y0 = (int)floorf(py);
      int x1 = min(x0 + 1, NX - 1), y1 = min(y0 + 1, NX - 1);
      float wx = px - (float)x0, wy = py - (float)y0;
      float w00 = (1.f - wx) * (1.f - wy), w01 = (1.f - wx) * wy;
      float w10 = wx * (1.f - wy), w11 = wx * wy;
#pragma unroll
      for (int half = 0; half < 2; ++half) {
        int r = half ? x1 : x0;
        float wa = half ? w10 : w00;
        float wb = half ? w11 : w01;
        if (r >= r0 && r < r0 + BR) {
          unsafeAtomicAdd(&acc[(r - r0) * NX + y0],
                          __floats2half2_rn(wa * v.x, wa * v.y));
          unsafeAtomicAdd(&acc[(r - r0) * NX + y1],
                          __floats2half2_rn(wb * v.x, wb * v.y));
        } else if (own) {
          int rb = (r / BR) * BR;
          if (nx < rb - WH || nx >= rb + BR + WH) {  // no band reads nx
            unsafeAtomicAdd(&out_f[((size_t)r * NX + y0) * 2], wa * v.x);
            unsafeAtomicAdd(&out_f[((size_t)r * NX + y0) * 2 + 1], wa * v.y);
            unsafeAtomicAdd(&out_f[((size_t)r * NX + y1) * 2], wb * v.x);
            unsafeAtomicAdd(&out_f[((size_t)r * NX + y1) * 2 + 1], wb * v.y);
          }
        }
      }
    }
  }
  __syncthreads();
  __half2* dst = out_p + (size_t)(seg * NT + t) * NX * NX + (size_t)r0 * NX;
  for (int i = tid; i < BR * NX; i += 1024) dst[i] = acc[i];
}

// out = out_f + sum_{seg,t} out_p (half2 slices)
__global__ __launch_bounds__(256) void reduce_k(
    const __half2* __restrict__ out_p, const float* __restrict__ out_f,
    float* __restrict__ out, int nslice) {
  const int n = NX * NX;  // 102400 cells
  int i = blockIdx.x * 256 + threadIdx.x;
  if (i >= n) return;
  float2 s = ((const float2*)out_f)[i];
  for (int k = 0; k < nslice; ++k) {
    float2 v = __half22float2(out_p[(size_t)k * n + i]);
    s.x += v.x;
    s.y += v.y;
  }
  ((float2*)out)[i] = s;
}

extern "C" void kernel_launch(void* const* d_in, const int* in_sizes, int n_in,
                              void* d_out, int out_size, void* d_ws,
                              size_t ws_size, hipStream_t stream) {
  const float* kr = (const float*)d_in[0];
  const float* ki = (const float*)d_in[1];
  const float* mask = (const float*)d_in[2];
  const float* sr = (const float*)d_in[3];
  const float* si = (const float*)d_in[4];
  const float* fl = (const float*)d_in[5];
  float* out = (float*)d_out;

  const size_t tmp1 = (size_t)NT * NX * NX * 4;      // fp16 complex, per coil
  const size_t kT_b = (size_t)NC * NX * NX * 8;
  const size_t sT_b = (size_t)NC * NX * NX * 4;      // half2
  const size_t fs_b = (size_t)NT * NX * NX * 8;
  const size_t mp_b = (size_t)NC * NX * NX * 4;
  const size_t ia_b = (size_t)NT * NX * NX * 4;      // half2
  const size_t of_b = (size_t)NX * NX * 8;
  const size_t op1 = (size_t)NT * NX * NX * 4;       // half2, per segment

  int NSEG = 2, G = 16;
  for (;;) {
    size_t fixed = kT_b + sT_b + fs_b + mp_b + ia_b + of_b + NSEG * op1;
    if (ws_size >= fixed + (size_t)G * tmp1) break;
    if (G > 1) { G >>= 1; continue; }
    if (NSEG > 1) { NSEG >>= 1; G = 16; continue; }
    break;  // minimal config; assume it fits
  }

  char* w = (char*)d_ws;
  __half2* tmp = (__half2*)w;    w += (size_t)G * tmp1;
  float2* kT = (float2*)w;       w += kT_b;
  __half2* sT = (__half2*)w;     w += sT_b;
  float2* fs = (float2*)w;       w += fs_b;
  __half2* im_aux = (__half2*)w; w += ia_b;
  __half2* out_p = (__half2*)w;  w += (size_t)NSEG * op1;
  float* out_f = (float*)w;      w += of_b;
  unsigned int* mp = (unsigned int*)w;

  prep_k<<<22600, 256, 0, stream>>>(mask, kr, ki, sr, si, fl, mp, kT, sT, fs,
                                    out_f);

  for (int c0 = 0; c0 < NC; c0 += G) {
    pass1_k<<<dim3(NX, G), 256, 0, stream>>>(kT, mp, tmp, c0);
    pass2_k<<<dim3(80, NT), 256, 0, stream>>>(tmp, sT, im_aux, c0, G,
                                              c0 == 0 ? 1 : 0);
  }
  scatter_k<<<dim3(NX / BR, NSEG, NT), 1024, 0, stream>>>(im_aux, fs, out_p,
                                                          out_f, NSEG);
  reduce_k<<<400, 256, 0, stream>>>(out_p, out_f, out, NSEG * NT);
}

// Round 15
// 272.833 us; speedup vs baseline: 1.5725x; 1.0092x over previous
//
#include <hip/hip_runtime.h>
#include <hip/hip_fp16.h>

// MRI adjoint: masked centered 2D IFFT per (coil,frame) -> conj(smaps) combine
// -> bilinear warp-adjoint scatter -> sum over frames. Nx=Ny=320, Nc=16, Nt=25.
//
// FFT: 320 = 5*64; one wave per transform. Selection-free butterfly
// z = cmul(o + sgn*z, w) with lane-resident twiddles; radix-5 twiddles folded
// into the (identity-twiddle) m=1 stage.
// Cross-lane (round-15): m=1,2 via DPP quad_perm (VALU, zero DS);
// m=4,8,16 via immediate ds_swizzle; m=32 via shfl_xor. Round-14 showed the
// FFT passes DS-pipe-bound (~60 cross-lane DS ops/FFT saturate LDS while
// VALU sits at 59%) -- this moves 1/3 of the DS ops to the idle VALU pipe.
// Centered-transform signs folded into pass1 output & pre-signed smaps.
// tmp fp16 half2 [c][t][ky][nx]; smaps/im_aux fp16.
// prep: float4 y-major mask streams (round-14), one overlaid LDS buffer.
// Scatter: LDS __half2 accumulator + ds_pk_add_f16 taps (LDS atomics are
// ~lane-serialized; halving lane-atomics was round-10's win).

#define NX 320
#define NT 25
#define NC 16
#define BR 32
#define WH 16
static const float INV320 = 1.0f / 320.0f;

typedef float v2f __attribute__((ext_vector_type(2)));

__device__ __forceinline__ int rev6(int l) {
  return ((l & 1) << 5) | ((l & 2) << 3) | ((l & 4) << 1) |
         ((l & 8) >> 1) | ((l & 16) >> 3) | ((l & 32) >> 5);
}

// Lane-resident twiddle state. Stages st=0..4 (m=32..2): sg=bot?-1:+1,
// (cst,sst)=bot?(c,s):(1,0). Stage m=1: sg5 plus folded radix-5 twiddles.
struct Tw {
  float cst[5], sst[5], sg[5];
  float sg5;
  float c5[5], s5[5];
};

__device__ __forceinline__ void make_tw(int lane, Tw& tw) {
#pragma unroll
  for (int st = 0; st < 5; ++st) {
    int m = 32 >> st;
    bool bot = (lane & m) != 0;
    int j = lane & (m - 1);
    float ang = 3.14159265358979323846f * (float)j / (float)m;
    float s, c;
    __sincosf(ang, &s, &c);
    tw.sg[st] = bot ? -1.f : 1.f;
    tw.cst[st] = bot ? c : 1.f;
    tw.sst[st] = bot ? s : 0.f;
  }
  tw.sg5 = (lane & 1) ? -1.f : 1.f;
  int k1 = rev6(lane);
  float b = (6.283185307179586f / 320.0f) * (float)k1;
  float s1, c1;
  __sincosf(b, &s1, &c1);
  tw.c5[0] = 1.f;
  tw.s5[0] = 0.f;
  tw.c5[1] = c1;
  tw.s5[1] = s1;
  tw.c5[2] = c1 * c1 - s1 * s1;
  tw.s5[2] = 2.f * c1 * s1;
  tw.c5[3] = tw.c5[2] * c1 - tw.s5[2] * s1;
  tw.s5[3] = tw.c5[2] * s1 + tw.s5[2] * c1;
  tw.c5[4] = tw.c5[2] * tw.c5[2] - tw.s5[2] * tw.s5[2];
  tw.s5[4] = 2.f * tw.c5[2] * tw.s5[2];
}

// Cross-lane xor exchange. m=1,2: DPP quad_perm (VALU pipe, standard
// butterfly controls 0xB1 = [1,0,3,2], 0x4E = [2,3,0,1]). m=4,8,16:
// immediate ds_swizzle. m=32: shfl_xor (ds_bpermute).
template <int M>
__device__ __forceinline__ float lxor(float x) {
  if constexpr (M == 1) {
    return __int_as_float(
        __builtin_amdgcn_mov_dpp(__float_as_int(x), 0xB1, 0xF, 0xF, true));
  } else if constexpr (M == 2) {
    return __int_as_float(
        __builtin_amdgcn_mov_dpp(__float_as_int(x), 0x4E, 0xF, 0xF, true));
  } else if constexpr (M == 32) {
    return __shfl_xor(x, 32);
  } else {
    constexpr int pat = (M << 10) | 0x1F;  // BitMode: xor=M, and=0x1F
    return __int_as_float(__builtin_amdgcn_ds_swizzle(__float_as_int(x), pat));
  }
}

// (z.x + i z.y) * (c + i s)
__device__ __forceinline__ v2f cmul(v2f z, float c, float s) {
  v2f sw = {-z.y, z.x};
  return c * z + s * sw;
}

template <int M>
__device__ __forceinline__ void bstage(v2f z[5], float sg, float c, float s) {
#pragma unroll
  for (int q = 0; q < 5; ++q) {
    v2f o;
    o.x = lxor<M>(z[q].x);
    o.y = lxor<M>(z[q].y);
    v2f t = o + sg * z[q];
    z[q] = cmul(t, c, s);  // top lanes: (c,s)=(1,0) -> identity
  }
}

// Unnormalized inverse 320-pt DFT: lane l enters with x[5l+q] in z[q];
// exits with X[rev6(l) + 64*q].
__device__ __forceinline__ void fft320p(v2f z[5], const Tw& tw) {
  bstage<32>(z, tw.sg[0], tw.cst[0], tw.sst[0]);
  bstage<16>(z, tw.sg[1], tw.cst[1], tw.sst[1]);
  bstage<8>(z, tw.sg[2], tw.cst[2], tw.sst[2]);
  bstage<4>(z, tw.sg[3], tw.cst[3], tw.sst[3]);
  bstage<2>(z, tw.sg[4], tw.cst[4], tw.sst[4]);
  {
    v2f o;
    o.x = lxor<1>(z[0].x);
    o.y = lxor<1>(z[0].y);
    z[0] = o + tw.sg5 * z[0];  // c5[0]=1: no cmul
#pragma unroll
    for (int q = 1; q < 5; ++q) {
      o.x = lxor<1>(z[q].x);
      o.y = lxor<1>(z[q].y);
      v2f t = o + tw.sg5 * z[q];
      z[q] = cmul(t, tw.c5[q], tw.s5[q]);
    }
  }
  v2f t0 = z[0], t1 = z[1], t2 = z[2], t3 = z[3], t4 = z[4];
  const float C1 = 0.30901699437494742f, S1 = 0.95105651629515357f;
  const float C2 = -0.80901699437494742f, S2 = 0.58778525229247312f;
  v2f a1 = t1 + t4, b1 = t1 - t4;
  v2f a2 = t2 + t3, b2 = t2 - t3;
  z[0] = t0 + a1 + a2;
  v2f p = t0 + C1 * a1 + C2 * a2;
  v2f q_ = S1 * b1 + S2 * b2;
  v2f r = t0 + C2 * a1 + C1 * a2;
  v2f u = S2 * b1 - S1 * b2;
  v2f qi = {-q_.y, q_.x};
  v2f ui = {-u.y, u.x};
  z[1] = p + qi;
  z[4] = p - qi;
  z[2] = r + ui;
  z[3] = r - ui;
}

// Merged pre-pass: role-switched on blockIdx.x. ONE overlaid LDS buffer.
//  [0,6400)      mask [x][y][c][t] -> bit-packed mp[c][y][x] (float4, y-major)
//  [6400,12800)  kspace [x][y][c] -> kT[c][y][x] float2
//  [12800,19200) smaps [x][y][c] -> sT[c][x][y] half2, pre-signed by (-1)^y
//  [19200,22400) flow [nx][ny][2][t] -> fs[t][nx][ny] float2 (float2 loads)
//  [22400,22600) zero out_f
__global__ __launch_bounds__(256) void prep_k(
    const float* __restrict__ mask, const float* __restrict__ kr,
    const float* __restrict__ ki, const float* __restrict__ sr,
    const float* __restrict__ si, const float* __restrict__ fl,
    unsigned int* __restrict__ mp, float2* __restrict__ kT,
    __half2* __restrict__ sT, float2* __restrict__ fs,
    float* __restrict__ out_f) {
  __shared__ __align__(16) char shmem[7552];  // overlaid by all phases
  int bid = blockIdx.x, tid = threadIdx.x;
  if (bid < 6400) {
    // y-major: consecutive blocks read adjacent 1600B chunks (16 seq streams)
    int xt = bid / 320, y = bid % 320;
    int w = tid >> 6, lane = tid & 63;
    float4* stage4 = (float4*)shmem;                      // [4][100]
    float* stage = (float*)shmem;
    unsigned int* tileu = (unsigned int*)(shmem + 6400);  // [16][17]
#pragma unroll
    for (int k = 0; k < 4; ++k) {
      int xx = w * 4 + k;
      const float4* src =
          (const float4*)(mask + ((size_t)((xt * 16 + xx) * NX) + y) * (NC * NT));
      float4* dst4 = stage4 + w * 100;
      if (lane < 50) {
        dst4[lane] = src[lane];           // 1KB/wave-instr
        dst4[lane + 50] = src[lane + 50];
      }
      if (lane < 16) {
        const float* row = stage + w * 400 + lane * NT;
        unsigned int bits = 0;
#pragma unroll
        for (int t = 0; t < NT; ++t) bits |= (row[t] != 0.f) ? (1u << t) : 0u;
        tileu[xx * 17 + lane] = bits;
      }
    }
    __syncthreads();
    int c2 = tid >> 4, xx2 = tid & 15;
    mp[((size_t)(c2 * NX + y)) * NX + xt * 16 + xx2] = tileu[xx2 * 17 + c2];
  } else if (bid < 12800) {
    int r = bid - 6400;
    int xt = r % 20, y = r / 20;
    int xx = tid >> 4, c = tid & 15;
    float2* tilef = (float2*)shmem;  // [16][17]
    size_t si_ = (size_t)((xt * 16 + xx) * NX + y) * NC + c;
    tilef[xx * 17 + c] = make_float2(kr[si_], ki[si_]);
    __syncthreads();
    int c2 = tid >> 4, xx2 = tid & 15;
    kT[((size_t)(c2 * NX + y)) * NX + xt * 16 + xx2] = tilef[xx2 * 17 + c2];
  } else if (bid < 19200) {
    int r = bid - 12800;
    int yt = r % 20, x = r / 20;
    int yy = tid >> 4, c = tid & 15;
    float2* tiles = (float2*)shmem;  // [16][17]
    size_t si_ = (size_t)(x * NX + yt * 16 + yy) * NC + c;
    tiles[yy * 17 + c] = make_float2(sr[si_], si[si_]);
    __syncthreads();
    int c2 = tid >> 4, yy2 = tid & 15;
    float2 v = tiles[yy2 * 17 + c2];
    float sg = (yy2 & 1) ? -1.f : 1.f;  // (-1)^ny pre-sign
    sT[((size_t)(c2 * NX + x)) * NX + yt * 16 + yy2] =
        __floats2half2_rn(v.x * sg, v.y * sg);
  } else if (bid < 22400) {
    int r = bid - 19200;
    int nyt = r % 10, nx = r / 10;
    float* buf = (float*)shmem;  // [1600]
    size_t base = (size_t)(nx * NX + nyt * 32) * (2 * NT);
    const float2* src2 = (const float2*)(fl + base);  // 8B-aligned
    float2* buf2 = (float2*)shmem;
    for (int f = tid; f < 800; f += 256) buf2[f] = src2[f];
    __syncthreads();
    for (int f = tid; f < 1600; f += 256) {
      int t = f / 64;
      int k = f % 64;
      int nyl = k >> 1, d = k & 1;
      size_t di = ((size_t)(t * NX + nx) * NX + nyt * 32 + nyl) * 2 + d;
      ((float*)fs)[di] = buf[(nyl * 2 + d) * NT + t];
    }
  } else {
    int idx = (bid - 22400) * 256 + tid;  // 51200 float4
    ((float4*)out_f)[idx] = make_float4(0.f, 0.f, 0.f, 0.f);
  }
}

// Pass 1: x-axis IFFT for coil chunk [c0, c0+G). Writes tmp[cg][t][ky][nx]
// fp16, pre-signed by (-1)^nx * (-1)^ky.
__global__ __launch_bounds__(256) void pass1_k(
    const float2* __restrict__ kT, const unsigned int* __restrict__ mp,
    __half2* __restrict__ tmp, int c0) {
  int y = blockIdx.x, cg = blockIdx.y, c = c0 + cg;
  int tid = threadIdx.x, lane = tid & 63, w = tid >> 6;
  v2f v[5];
  unsigned int mb[5];
  size_t rowbase = ((size_t)c * NX + y) * NX;
#pragma unroll
  for (int q = 0; q < 5; ++q) {
    int x = 5 * lane + q;
    float2 kv = kT[rowbase + x];
    float sg = ((lane + q) & 1) ? -INV320 : INV320;  // (-1)^x / 320
    v[q].x = kv.x * sg;
    v[q].y = kv.y * sg;
    mb[q] = mp[rowbase + x];
  }
  Tw tw;
  make_tw(lane, tw);
  int r6 = rev6(lane);
  float osg = ((lane & 32) ? -1.f : 1.f) * ((y & 1) ? -1.f : 1.f);
  for (int t = w; t < NT; t += 4) {
    v2f z[5];
#pragma unroll
    for (int q = 0; q < 5; ++q) {
      float m = ((mb[q] >> t) & 1u) ? 1.f : 0.f;
      z[q] = v[q] * m;
    }
    fft320p(z, tw);
    __half2* dst = tmp + ((size_t)(cg * NT + t) * NX + y) * NX;
#pragma unroll
    for (int k2 = 0; k2 < 5; ++k2)
      dst[r6 + 64 * k2] = __floats2half2_rn(z[k2].x * osg, z[k2].y * osg);
  }
}

// Pass 2: y-axis IFFT + conj(smaps) combine -> im_aux[t][nx][ny] fp16.
// 256 threads = 4 waves; block = (nx-tile of 4, t); wave j owns nx.
__global__ __launch_bounds__(256) void pass2_k(
    const __half2* __restrict__ tmp, const __half2* __restrict__ sT,
    __half2* __restrict__ im_aux, int c0, int G, int first) {
  int bx = blockIdx.x, t = blockIdx.y;
  int nxt_ = (bx >> 3) + 10 * (bx & 7);  // bijective on [0,80)
  int tid = threadIdx.x, lane = tid & 63, j = tid >> 6;
  int nx = nxt_ * 4 + j;
  int k1 = rev6(lane);
  Tw tw;
  make_tw(lane, tw);
  __shared__ __half2 tile[2][NX][5];  // 12.8 KB
  v2f acc[5] = {{0, 0}, {0, 0}, {0, 0}, {0, 0}, {0, 0}};

  int off[5], lw[5];
#pragma unroll
  for (int q = 0; q < 5; ++q) {
    int f = tid + q * 256;
    off[q] = (f >> 2) * NX + (f & 3);
    lw[q] = (f >> 2) * 5 + (f & 3);
  }
  const size_t pstride = (size_t)NT * NX * NX;
  const __half2* sbase = tmp + (size_t)t * NX * NX + nxt_ * 4;
  __half2* lds = &tile[0][0][0];

  __half2 nb[5];
#pragma unroll
  for (int q = 0; q < 5; ++q) nb[q] = sbase[off[q]];

  for (int cg = 0; cg < G; ++cg) {
    __half2 cb[5];
#pragma unroll
    for (int q = 0; q < 5; ++q) cb[q] = nb[q];
    if (cg + 1 < G) {
      const __half2* s = sbase + (size_t)(cg + 1) * pstride;
#pragma unroll
      for (int q = 0; q < 5; ++q) nb[q] = s[off[q]];  // in flight across iter
    }
    __half2* buf = lds + (cg & 1) * (NX * 5);
#pragma unroll
    for (int q = 0; q < 5; ++q) buf[lw[q]] = cb[q];
    const __half2* srow = sT + ((size_t)(c0 + cg) * NX + nx) * NX;
    __half2 smh[5];
#pragma unroll
    for (int k2 = 0; k2 < 5; ++k2) smh[k2] = srow[k1 + 64 * k2];
    __syncthreads();
    v2f z[5];
#pragma unroll
    for (int q = 0; q < 5; ++q) {
      float2 v = __half22float2(buf[(5 * lane + q) * 5 + j]);
      z[q].x = v.x;  // signs pre-folded in pass1
      z[q].y = v.y;
    }
    fft320p(z, tw);
#pragma unroll
    for (int k2 = 0; k2 < 5; ++k2) {
      float2 sm = __half22float2(smh[k2]);
      v2f zc = {z[k2].y, -z[k2].x};  // conj-MAC helper
      acc[k2] += sm.x * z[k2] + sm.y * zc;
    }
  }
  __half2* dst = im_aux + ((size_t)t * NX + nx) * NX;
#pragma unroll
  for (int k2 = 0; k2 < 5; ++k2) {
    int ny = k1 + 64 * k2;
    v2f nv = acc[k2];  // (-1)^ny folded into sT
    if (!first) {
      float2 old = __half22float2(dst[ny]);
      nv.x += old.x;
      nv.y += old.y;
    }
    dst[ny] = __floats2half2_rn(nv.x, nv.y);
  }
}

// Scatter: block (band b, seg, frame t). LDS-privatized 32-row band of
// __half2 (re,im) cells; taps via ds_pk_add_f16 (4 lane-atomics/element).
__global__ __launch_bounds__(1024) void scatter_k(
    const __half2* __restrict__ im, const float2* __restrict__ fs,
    __half2* __restrict__ out_p, float* __restrict__ out_f, int nseg) {
  int b = blockIdx.x, seg = blockIdx.y, t = blockIdx.z;
  int r0 = b * BR;
  int tid = threadIdx.x, lane = tid & 63, w = tid >> 6;
  __shared__ __half2 acc[BR * NX];  // 40 KB
  const __half2 h2z = __floats2half2_rn(0.f, 0.f);
  for (int i = tid; i < BR * NX; i += 1024) acc[i] = h2z;
  __syncthreads();
  int lo = max(r0 - WH, 0), hi = min(r0 + BR + WH, NX);
  int stride = 16 * nseg;
  for (int nx = lo + seg * 16 + w; nx < hi; nx += stride) {
    bool own = (nx >= r0) && (nx < r0 + BR);
    const __half2* imrow = im + ((size_t)t * NX + nx) * NX;
    const float2* frow = fs + ((size_t)t * NX + nx) * NX;
#pragma unroll
    for (int q = 0; q < 5; ++q) {
      int ny = lane + 64 * q;
      float2 v = __half22float2(imrow[ny]);
      float2 fl = frow[ny];
      float px = fminf(fmaxf((float)nx + fl.x, 0.f), 319.f);
      float py = fminf(fmaxf((float)ny + fl.y, 0.f), 319.f);
      int x0 = (int)floorf(px), y0 = (int)floorf(py);
      int x1 = min(x0 + 1, NX - 1), y1 = min(y0 + 1, NX - 1);
      float wx = px - (float)x0, wy = py - (float)y0;
      float w00 = (1.f - wx) * (1.f - wy), w01 = (1.f - wx) * wy;
      float w10 = wx * (1.f - wy), w11 = wx * wy;
#pragma unroll
      for (int half = 0; half < 2; ++half) {
        int r = half ? x1 : x0;
        float wa = half ? w10 : w00;
        float wb = half ? w11 : w01;
        if (r >= r0 && r < r0 + BR) {
          unsafeAtomicAdd(&acc[(r - r0) * NX + y0],
                          __floats2half2_rn(wa * v.x, wa * v.y));
          unsafeAtomicAdd(&acc[(r - r0) * NX + y1],
                          __floats2half2_rn(wb * v.x, wb * v.y));
        } else if (own) {
          int rb = (r / BR) * BR;
          if (nx < rb - WH || nx >= rb + BR + WH) {  // no band reads nx
            unsafeAtomicAdd(&out_f[((size_t)r * NX + y0) * 2], wa * v.x);
            unsafeAtomicAdd(&out_f[((size_t)r * NX + y0) * 2 + 1], wa * v.y);
            unsafeAtomicAdd(&out_f[((size_t)r * NX + y1) * 2], wb * v.x);
            unsafeAtomicAdd(&out_f[((size_t)r * NX + y1) * 2 + 1], wb * v.y);
          }
        }
      }
    }
  }
  __syncthreads();
  __half2* dst = out_p + (size_t)(seg * NT + t) * NX * NX + (size_t)r0 * NX;
  for (int i = tid; i < BR * NX; i += 1024) dst[i] = acc[i];
}

// out = out_f + sum_{seg,t} out_p (half2 slices)
__global__ __launch_bounds__(256) void reduce_k(
    const __half2* __restrict__ out_p, const float* __restrict__ out_f,
    float* __restrict__ out, int nslice) {
  const int n = NX * NX;  // 102400 cells
  int i = blockIdx.x * 256 + threadIdx.x;
  if (i >= n) return;
  float2 s = ((const float2*)out_f)[i];
  for (int k = 0; k < nslice; ++k) {
    float2 v = __half22float2(out_p[(size_t)k * n + i]);
    s.x += v.x;
    s.y += v.y;
  }
  ((float2*)out)[i] = s;
}

extern "C" void kernel_launch(void* const* d_in, const int* in_sizes, int n_in,
                              void* d_out, int out_size, void* d_ws,
                              size_t ws_size, hipStream_t stream) {
  const float* kr = (const float*)d_in[0];
  const float* ki = (const float*)d_in[1];
  const float* mask = (const float*)d_in[2];
  const float* sr = (const float*)d_in[3];
  const float* si = (const float*)d_in[4];
  const float* fl = (const float*)d_in[5];
  float* out = (float*)d_out;

  const size_t tmp1 = (size_t)NT * NX * NX * 4;      // fp16 complex, per coil
  const size_t kT_b = (size_t)NC * NX * NX * 8;
  const size_t sT_b = (size_t)NC * NX * NX * 4;      // half2
  const size_t fs_b = (size_t)NT * NX * NX * 8;
  const size_t mp_b = (size_t)NC * NX * NX * 4;
  const size_t ia_b = (size_t)NT * NX * NX * 4;      // half2
  const size_t of_b = (size_t)NX * NX * 8;
  const size_t op1 = (size_t)NT * NX * NX * 4;       // half2, per segment

  int NSEG = 2, G = 16;
  for (;;) {
    size_t fixed = kT_b + sT_b + fs_b + mp_b + ia_b + of_b + NSEG * op1;
    if (ws_size >= fixed + (size_t)G * tmp1) break;
    if (G > 1) { G >>= 1; continue; }
    if (NSEG > 1) { NSEG >>= 1; G = 16; continue; }
    break;  // minimal config; assume it fits
  }

  char* w = (char*)d_ws;
  __half2* tmp = (__half2*)w;    w += (size_t)G * tmp1;
  float2* kT = (float2*)w;       w += kT_b;
  __half2* sT = (__half2*)w;     w += sT_b;
  float2* fs = (float2*)w;       w += fs_b;
  __half2* im_aux = (__half2*)w; w += ia_b;
  __half2* out_p = (__half2*)w;  w += (size_t)NSEG * op1;
  float* out_f = (float*)w;      w += of_b;
  unsigned int* mp = (unsigned int*)w;

  prep_k<<<22600, 256, 0, stream>>>(mask, kr, ki, sr, si, fl, mp, kT, sT, fs,
                                    out_f);

  for (int c0 = 0; c0 < NC; c0 += G) {
    pass1_k<<<dim3(NX, G), 256, 0, stream>>>(kT, mp, tmp, c0);
    pass2_k<<<dim3(80, NT), 256, 0, stream>>>(tmp, sT, im_aux, c0, G,
                                              c0 == 0 ? 1 : 0);
  }
  scatter_k<<<dim3(NX / BR, NSEG, NT), 1024, 0, stream>>>(im_aux, fs, out_p,
                                                          out_f, NSEG);
  reduce_k<<<400, 256, 0, stream>>>(out_p, out_f, out, NSEG * NT);
}